// Round 14
// baseline (1239.685 us; speedup 1.0000x reference)
//
#include <hip/hip_runtime.h>
#include <cstdint>
#include <cstddef>

#define NEG_INF (-3.402823466e38f)
typedef unsigned short u16;
typedef unsigned int u32;

typedef short s16x8 __attribute__((ext_vector_type(8)));
typedef __bf16 bf16x8_t __attribute__((ext_vector_type(8)));
typedef float f32x4 __attribute__((ext_vector_type(4)));

__device__ __forceinline__ f32x4 mfma_bf16(s16x8 a, s16x8 b, f32x4 c){
    return __builtin_amdgcn_mfma_f32_16x16x32_bf16(
        __builtin_bit_cast(bf16x8_t, a), __builtin_bit_cast(bf16x8_t, b), c, 0, 0, 0);
}
__device__ __forceinline__ float b2f(u16 u){ return __uint_as_float(((u32)u) << 16); }
__device__ __forceinline__ u16 f2bu(float f){           // RNE fp32 -> bf16 bits
    u32 u = __float_as_uint(f);
    return (u16)((u + 0x7fffu + ((u >> 16) & 1u)) >> 16);
}
// async global->LDS, 16B/lane; LDS dest = wave-uniform base + lane*16 (m97 pattern)
__device__ __forceinline__ void gload16(const u16* __restrict__ g, u16* l){
    __builtin_amdgcn_global_load_lds(
        (const __attribute__((address_space(1))) u32*)g,
        (__attribute__((address_space(3))) u32*)l, 16, 0, 0);
}

// ---------------- top-k helpers (JAX lax.top_k stable: val desc, idx asc on ties) ----
__device__ __forceinline__ bool tk_gt(float v, int i, float w, int j){
    return (v > w) || (v == w && i < j);
}
__device__ __forceinline__ void tk_insert(float v, int id, float tv[3], int ti[3]){
    if (!tk_gt(v, id, tv[2], ti[2])) return;
    if (tk_gt(v, id, tv[1], ti[1])) {
        tv[2]=tv[1]; ti[2]=ti[1];
        if (tk_gt(v, id, tv[0], ti[0])) { tv[1]=tv[0]; ti[1]=ti[0]; tv[0]=v; ti[0]=id; }
        else { tv[1]=v; ti[1]=id; }
    } else { tv[2]=v; ti[2]=id; }
}
__device__ __forceinline__ void tk_insert8(float v, int id, float tv[8], int ti[8]){
    if (!tk_gt(v, id, tv[7], ti[7])) return;
    tv[7]=v; ti[7]=id;
#pragma unroll
    for (int e=7;e>0;e--){
        if (tk_gt(tv[e], ti[e], tv[e-1], ti[e-1])){
            float fv=tv[e]; tv[e]=tv[e-1]; tv[e-1]=fv;
            int   fi=ti[e]; ti[e]=ti[e-1]; ti[e-1]=fi;
        }
    }
}

// ---------------- conversion pre-passes --------------------------------------------
__global__ void cvt_hilo(const float* __restrict__ in, u16* __restrict__ hi,
                         u16* __restrict__ lo, int n4)
{
    int i = blockIdx.x * 256 + threadIdx.x;
    if (i >= n4) return;
    float4 v = ((const float4*)in)[i];
    u16 h[4], l[4];
    float f[4] = {v.x, v.y, v.z, v.w};
#pragma unroll
    for (int j=0;j<4;j++){
        u16 hb = f2bu(f[j]);
        h[j] = hb;
        l[j] = f2bu(f[j] - b2f(hb));
    }
    *(ushort4*)&hi[i*4] = *(ushort4*)h;
    *(ushort4*)&lo[i*4] = *(ushort4*)l;
}

// im2col + bf16-split of x for one half (4608 patch rows), coalesced writes.
__global__ void xpb_build(const float* __restrict__ x, int base,
                          u16* __restrict__ xh, u16* __restrict__ xl)
{
    int gid = blockIdx.x * 256 + threadIdx.x;          // 7,372,800 threads
    int n = gid / 1600;
    int kq = (gid - n*1600) * 4;
    int ng = n + base;
    int pi = ng / 96, pj = ng - pi*96;
    u16 h[4], l[4];
#pragma unroll
    for (int e=0;e<4;e++){
        int k = kq + e;
        int c = k / 25, rem = k - c*25, r = rem / 5, jj = rem - r*5;
        float v = x[(size_t)c*230400 + (size_t)(pi*5+r)*480 + pj*5 + jj];
        u16 hb = f2bu(v);
        h[e] = hb;
        l[e] = f2bu(v - b2f(hb));
    }
    *(ushort4*)&xh[(size_t)n*6400 + kq] = *(ushort4*)h;
    *(ushort4*)&xl[(size_t)n*6400 + kq] = *(ushort4*)l;
}

// sum 4 K-split partials + bias + relu -> emb1 rows (one half = 294912 float4)
__global__ void conv_reduce2(const float* __restrict__ p, const float* __restrict__ bias,
                             float* __restrict__ o)
{
    int i = blockIdx.x * 256 + threadIdx.x;
    const float4* p4 = (const float4*)p;
    float4 s = p4[i];
#pragma unroll
    for (int j=1;j<4;j++){
        float4 v = p4[i + (size_t)j*294912];
        s.x += v.x; s.y += v.y; s.z += v.z; s.w += v.w;
    }
    float4 bb = ((const float4*)bias)[i & 63];
    float4 r;
    r.x = fmaxf(s.x+bb.x, 0.f);
    r.y = fmaxf(s.y+bb.y, 0.f);
    r.z = fmaxf(s.z+bb.z, 0.f);
    r.w = fmaxf(s.w+bb.w, 0.f);
    ((float4*)o)[i] = r;
}

// ---------------- generic fp32 GEMM (fc2, fc3) -------------------------------------
template<int ACT>
__global__ __launch_bounds__(256)
void gemm_f32(const float* __restrict__ A1, int ldA1, int K1,
              const float* __restrict__ A2, int ldA2,
              const float* __restrict__ B, const float* __restrict__ bias,
              const float* __restrict__ add,
              float* __restrict__ C, int M, int N, int K)
{
    __shared__ __align__(16) float As[16][128];
    __shared__ __align__(16) float Bs[16][64];
    const int mb = blockIdx.x * 128, nb = blockIdx.y * 64;
    const int tid = threadIdx.x;
    const int tn = tid & 15, tm = tid >> 4;
    float acc[8][4];
#pragma unroll
    for (int i=0;i<8;i++){
#pragma unroll
        for (int j=0;j<4;j++) acc[i][j]=0.f;
    }
    const int am = tid >> 2;
    const int ak = (tid & 3) * 4;
    const int bk = tid >> 4;
    const int bn = (tid & 15) * 4;

    for (int k0 = 0; k0 < K; k0 += 16) {
        int kg = k0 + ak;
#pragma unroll
        for (int half = 0; half < 2; ++half) {
            int ml = am + half*64;
            int m = mb + ml;
            float4 v;
            if (kg < K1) v = *(const float4*)(A1 + (size_t)m*ldA1 + kg);
            else         v = *(const float4*)(A2 + (size_t)m*ldA2 + (kg - K1));
            As[ak+0][ml] = v.x; As[ak+1][ml] = v.y; As[ak+2][ml] = v.z; As[ak+3][ml] = v.w;
        }
        {
            float4 v = *(const float4*)(B + (size_t)(k0+bk)*N + nb + bn);
            *(float4*)&Bs[bk][bn] = v;
        }
        __syncthreads();
#pragma unroll
        for (int kk=0;kk<16;kk++){
            float a[8], b[4];
            *(float4*)&a[0] = *(const float4*)&As[kk][tm*8];
            *(float4*)&a[4] = *(const float4*)&As[kk][tm*8+4];
            *(float4*)&b[0] = *(const float4*)&Bs[kk][tn*4];
#pragma unroll
            for (int i=0;i<8;i++){
#pragma unroll
                for (int j=0;j<4;j++) acc[i][j] += a[i]*b[j];
            }
        }
        __syncthreads();
    }
#pragma unroll
    for (int i=0;i<8;i++){
        int m = mb + tm*8 + i;
        float ov[4];
#pragma unroll
        for (int j=0;j<4;j++){
            int n = nb + tn*4 + j;
            float v = acc[i][j] + bias[n];
            if (ACT == 1) v = v > 0.f ? v : 0.f;
            if (add) v += add[(size_t)m*N + n];
            ov[j] = v;
        }
        *(float4*)(C + (size_t)m*N + nb + tn*4) = *(float4*)ov;
    }
}

// fp32 [K][N] row-major -> bf16 out[N][K]
__global__ __launch_bounds__(256)
void transpose_cvt(const float* __restrict__ in, int K, int N, u16* __restrict__ out)
{
    __shared__ float t[32][33];
    const int kb = blockIdx.x * 32, nb = blockIdx.y * 32;
    const int tx = threadIdx.x & 31, ty = threadIdx.x >> 5;   // 32 x 8
#pragma unroll
    for (int r=0;r<4;r++)
        t[ty + r*8][tx] = in[(size_t)(kb + ty + r*8)*N + nb + tx];
    __syncthreads();
#pragma unroll
    for (int r=0;r<4;r++)
        out[(size_t)(nb + ty + r*8)*K + kb + tx] = f2bu(t[tx][ty + r*8]);
}

// ---------------- bf16 MFMA NT GEMM core: C[M][N] = A[M][K] @ B[N][K]^T ------------
// 128x128 tile, BK=32, 256 thr (4 waves as 2x2 of 64x64); global_load_lds staging
// into linear LDS [128][32]. SPLIT: (hi,lo) 3-term. EPI 0: bf16 store via LDS-bounce
// coalesced uint4 (R14). EPI 1: symmetric top-3 candidates. EPI 2: conv K-split f32
// partials via LDS-bounce float4 (R14).
template<bool SPLIT, int EPI>
__device__ __forceinline__
void mm_core(const u16* __restrict__ Ah, const u16* __restrict__ Al, int lda,
             const u16* __restrict__ Bh, const u16* __restrict__ Bl, int ldb,
             const float* __restrict__ bias0, const float* __restrict__ bias1, int nHalf,
             void* __restrict__ Cout, int ldc, int K,
             float* __restrict__ pval, int* __restrict__ pidx)
{
    if constexpr (EPI == 1) {
        if (blockIdx.y < blockIdx.x) return;    // upper-triangle blocks only
    }
    constexpr int TSZ = 128 * 32;
    __shared__ u16 smem[(SPLIT ? 4 : 2) * TSZ];
    u16* AsH = smem;
    u16* BsH = smem + TSZ;
    u16* AsL = SPLIT ? smem + 2*TSZ : nullptr;
    u16* BsL = SPLIT ? smem + 3*TSZ : nullptr;

    const int tid = threadIdx.x;
    const int w = tid >> 6, ln = tid & 63;
    const int wr = w >> 1, wc = w & 1;
    const int fr = ln & 15, fq = ln >> 4;
    const int mb = blockIdx.x * 128, nb = blockIdx.y * 128;
    const int skk = (ln & 3) * 8;        // staging: k element offset
    const int srow = ln >> 2;            // staging: row within 16-row group (implicit via dest)

    int kbeg = 0;
    if constexpr (EPI == 2) kbeg = blockIdx.z * K;
    const int kend = kbeg + K;

    f32x4 acc[4][4];
#pragma unroll
    for (int i=0;i<4;i++)
#pragma unroll
        for (int j=0;j<4;j++) acc[i][j] = (f32x4){0.f,0.f,0.f,0.f};

    for (int k0 = kbeg; k0 < kend; k0 += 32) {
#pragma unroll
        for (int t=0;t<2;t++){
            int rbase = w*32 + t*16;
            int r = rbase + srow;
            size_t goA = (size_t)(mb + r)*lda + k0 + skk;
            size_t goB = (size_t)(nb + r)*ldb + k0 + skk;
            gload16(Ah + goA, AsH + rbase*32);
            gload16(Bh + goB, BsH + rbase*32);
            if constexpr (SPLIT){
                gload16(Al + goA, AsL + rbase*32);
                gload16(Bl + goB, BsL + rbase*32);
            }
        }
        __syncthreads();
        s16x8 ah[4], bh[4], al[4], bl[4];
#pragma unroll
        for (int mi=0;mi<4;mi++){
            int ro = (wr*64 + mi*16 + fr)*32 + fq*8;
            ah[mi] = *(const s16x8*)&AsH[ro];
            if constexpr (SPLIT) al[mi] = *(const s16x8*)&AsL[ro];
        }
#pragma unroll
        for (int nj=0;nj<4;nj++){
            int ro = (wc*64 + nj*16 + fr)*32 + fq*8;
            bh[nj] = *(const s16x8*)&BsH[ro];
            if constexpr (SPLIT) bl[nj] = *(const s16x8*)&BsL[ro];
        }
#pragma unroll
        for (int mi=0;mi<4;mi++)
#pragma unroll
            for (int nj=0;nj<4;nj++){
                acc[mi][nj] = mfma_bf16(ah[mi], bh[nj], acc[mi][nj]);
                if constexpr (SPLIT){
                    acc[mi][nj] = mfma_bf16(ah[mi], bl[nj], acc[mi][nj]);
                    acc[mi][nj] = mfma_bf16(al[mi], bh[nj], acc[mi][nj]);
                }
            }
        __syncthreads();
    }

    if constexpr (EPI == 0) {
        // LDS-bounce: 4 chunks of 32 rows x 128 cols bf16, pad 136 u16/row (16B-aligned,
        // fq rotates banks). Then coalesced uint4 stores (16B/lane).
        u16* ldsc = smem;                 // 32*136*2 = 8704B <= 16KB staging region
#pragma unroll
        for (int chunk=0; chunk<4; ++chunk){
            __syncthreads();
            if (wr == (chunk>>1)){
                int mi0 = (chunk&1)*2;
#pragma unroll
                for (int m2=0;m2<2;m2++){
                    int mi = mi0 + m2;
#pragma unroll
                    for (int nj=0;nj<4;nj++)
#pragma unroll
                    for (int t=0;t<4;t++){
                        int lr = m2*16 + fq*4 + t;
                        int lc = wc*64 + nj*16 + fr;
                        int col = nb + lc;
                        float v = acc[mi][nj][t];
                        if (bias0) v += (col < nHalf) ? bias0[col] : bias1[col - nHalf];
                        ldsc[lr*136 + lc] = f2bu(v);
                    }
                }
            }
            __syncthreads();
            int c0 = chunk*32;
#pragma unroll
            for (int q=0;q<2;q++){
                int e = q*256 + tid;      // 0..511 ; 32 rows x 16 uint4
                int lr = e >> 4, c16 = e & 15;
                *(uint4*)((u16*)Cout + (size_t)(mb + c0 + lr)*ldc + nb + c16*8)
                    = *(const uint4*)&ldsc[lr*136 + c16*8];
            }
        }
    } else if constexpr (EPI == 2) {
        // LDS-bounce: 8 chunks of 16 rows x 128 cols f32, pad 132 f32/row.
        float* ldsf = (float*)smem;       // 16*132*4 = 8448B <= 32KB (SPLIT)
#pragma unroll
        for (int chunk=0; chunk<8; ++chunk){
            __syncthreads();
            if (wr == (chunk>>2)){
                int mi = chunk & 3;
#pragma unroll
                for (int nj=0;nj<4;nj++)
#pragma unroll
                for (int t=0;t<4;t++){
                    int lr = fq*4 + t;
                    int lc = wc*64 + nj*16 + fr;
                    ldsf[lr*132 + lc] = acc[mi][nj][t];
                }
            }
            __syncthreads();
            int c0 = chunk*16;
#pragma unroll
            for (int q=0;q<2;q++){
                int e = q*256 + tid;      // 0..511 ; 16 rows x 32 float4
                int lr = e >> 5, c4 = e & 31;
                *(float4*)((float*)Cout + ((size_t)blockIdx.z*4608 + mb + c0 + lr)*256 + nb + c4*4)
                    = *(const float4*)&ldsf[lr*132 + c4*4];
            }
        }
    } else {
        // row side: per row, top-3 over this block's 64 cols (wc half)
        const int cbR = blockIdx.y * 2 + wc;
#pragma unroll
        for (int mi=0;mi<4;mi++)
#pragma unroll
            for (int t=0;t<4;t++){
                int row = mb + wr*64 + mi*16 + fq*4 + t;
                float tv[3] = {NEG_INF, NEG_INF, NEG_INF};
                int   ti[3] = {0x7fffffff, 0x7fffffff, 0x7fffffff};
#pragma unroll
                for (int nj=0;nj<4;nj++)
                    tk_insert(acc[mi][nj][t], nb + wc*64 + nj*16 + fr, tv, ti);
#pragma unroll
                for (int off=1; off<16; off<<=1){      // reduce across fr lanes
                    float ov[3]; int oi[3];
#pragma unroll
                    for (int e=0;e<3;e++){ ov[e]=__shfl_xor(tv[e],off); oi[e]=__shfl_xor(ti[e],off); }
#pragma unroll
                    for (int e=0;e<3;e++) tk_insert(ov[e], oi[e], tv, ti);
                }
                if (fr == 0){
#pragma unroll
                    for (int e=0;e<3;e++){
                        pval[(size_t)row*432 + cbR*3 + e] = tv[e];
                        pidx[(size_t)row*432 + cbR*3 + e] = ti[e];
                    }
                }
            }
        // col side: per col, top-3 over this block's 64 rows (wr half); skip diagonal
        if (blockIdx.x != blockIdx.y) {
            const int cbC = blockIdx.x * 2 + wr;
#pragma unroll
            for (int nj=0;nj<4;nj++){
                int col = nb + wc*64 + nj*16 + fr;
                float tv[3] = {NEG_INF, NEG_INF, NEG_INF};
                int   ti[3] = {0x7fffffff, 0x7fffffff, 0x7fffffff};
#pragma unroll
                for (int mi=0;mi<4;mi++)
#pragma unroll
                    for (int t=0;t<4;t++)
                        tk_insert(acc[mi][nj][t], mb + wr*64 + mi*16 + fq*4 + t, tv, ti);
#pragma unroll
                for (int off=16; off<64; off<<=1){     // reduce across fq lanes
                    float ov[3]; int oi[3];
#pragma unroll
                    for (int e=0;e<3;e++){ ov[e]=__shfl_xor(tv[e],off); oi[e]=__shfl_xor(ti[e],off); }
#pragma unroll
                    for (int e=0;e<3;e++) tk_insert(ov[e], oi[e], tv, ti);
                }
                if (fq == 0){
#pragma unroll
                    for (int e=0;e<3;e++){
                        pval[(size_t)col*432 + cbC*3 + e] = tv[e];
                        pidx[(size_t)col*432 + cbC*3 + e] = ti[e];
                    }
                }
            }
        }
    }
}

// named instantiations (distinct rocprof rows)
__global__ __launch_bounds__(256)
void mm_proj(const u16* Ah, int lda, const u16* Bh, int ldb,
             const float* bias0, const float* bias1, int nHalf,
             void* Cout, int ldc, int K)
{
    mm_core<false,0>(Ah, nullptr, lda, Bh, nullptr, ldb, bias0, bias1, nHalf,
                     Cout, ldc, K, nullptr, nullptr);
}
__global__ __launch_bounds__(256)
void mm_adj(const u16* Ah, int lda, float* pval, int* pidx)
{
    mm_core<false,1>(Ah, nullptr, lda, Ah, nullptr, lda, nullptr, nullptr, 0,
                     nullptr, 0, 256, pval, pidx);
}
__global__ __launch_bounds__(256)
void mm_conv(const u16* Ah, const u16* Al, int lda, const u16* Bh, const u16* Bl, int ldb,
             float* Cout, int K)
{
    mm_core<true,2>(Ah, Al, lda, Bh, Bl, ldb, nullptr, nullptr, 0,
                    Cout, 256, K, nullptr, nullptr);
}

// merge 432 partial entries per row -> approx top-8, ONE WAVE PER ROW.
__global__ __launch_bounds__(256)
void adj_merge8(const float* __restrict__ pvals, const int* __restrict__ pidx,
                int* __restrict__ c8i)
{
    int row = blockIdx.x * 4 + (threadIdx.x >> 6);
    int ln = threadIdx.x & 63;
    float tv[8]; int ti[8];
#pragma unroll
    for (int e=0;e<8;e++){ tv[e]=NEG_INF; ti[e]=0x7fffffff; }
    for (int t = ln; t < 432; t += 64)
        tk_insert8(pvals[(size_t)row*432 + t], pidx[(size_t)row*432 + t], tv, ti);
#pragma unroll
    for (int off=1; off<64; off<<=1){
        float ov[8]; int oi[8];
#pragma unroll
        for (int e=0;e<8;e++){ ov[e]=__shfl_xor(tv[e],off); oi[e]=__shfl_xor(ti[e],off); }
#pragma unroll
        for (int e=0;e<8;e++) tk_insert8(ov[e], oi[e], tv, ti);
    }
    if (ln == 0){
#pragma unroll
        for (int e=0;e<8;e++) c8i[row*8+e] = ti[e];
    }
}

// exact fp32 rescore of 8 candidates per row, final top-3 (lax.top_k semantics).
__global__ __launch_bounds__(256)
void rescore_select(const float* __restrict__ emb, const int* __restrict__ c8i,
                    float* __restrict__ vals, int* __restrict__ idx)
{
    int gid = blockIdx.x * 256 + threadIdx.x;
    int row = gid >> 6;
    int ln = threadIdx.x & 63;
    float a[4];
    *(float4*)a = *(const float4*)(emb + (size_t)row*256 + ln*4);
    float sc[8];
#pragma unroll
    for (int c=0;c<8;c++){
        int cand = c8i[row*8+c];
        float4 b = *(const float4*)(emb + (size_t)cand*256 + ln*4);
        float p = a[0]*b.x + a[1]*b.y + a[2]*b.z + a[3]*b.w;
#pragma unroll
        for (int off=1; off<64; off<<=1) p += __shfl_xor(p, off);
        sc[c] = p;
    }
    if (ln == 0){
        float tv[3]={NEG_INF,NEG_INF,NEG_INF};
        int   ti[3]={0x7fffffff,0x7fffffff,0x7fffffff};
#pragma unroll
        for (int c=0;c<8;c++) tk_insert(sc[c], c8i[row*8+c], tv, ti);
#pragma unroll
        for (int e=0;e<3;e++){ vals[row*3+e]=tv[e]; idx[row*3+e]=ti[e]; }
    }
}

// ---------------- GATv2 softmax + aggregate + bias + ELU, bf16 inputs --------------
template<int H, int TPH, bool SPATIAL, bool OUTBF>
__global__ __launch_bounds__(H*TPH)
void gat_agg(const u16* __restrict__ xlxr, int ldx, int xrOff,
             const float* __restrict__ att, const float* __restrict__ bias,
             const float* __restrict__ vals, const int* __restrict__ idx,
             void* __restrict__ outp, int ldo)
{
    constexpr int D = 256;
    constexpr int DPT = D / TPH;
    const int n = blockIdx.x;
    const int tid = threadIdx.x;
    const int h = tid / TPH;
    const int l = tid % TPH;
    const int d0 = l * DPT;

    int srcs[4]; bool valid[4];
#pragma unroll
    for (int s=0;s<4;s++){ srcs[s]=n; valid[s]=(s==3); }
    if constexpr (SPATIAL) {
        int pi = n / 96, pj = n - (n/96)*96;
        int cand[4]; int nc=0;
        if (pi > 0)  cand[nc++] = n - 96;
        if (pj > 0)  cand[nc++] = n - 1;
        if (pj < 95) cand[nc++] = n + 1;
        if (pi < 95) cand[nc++] = n + 96;
        int s0 = cand[0], s1 = cand[1];
        if (s0 > n){ srcs[0]=s0; valid[0]=true; }
        if (s1 > n){ srcs[1]=s1; valid[1]=true; }
    } else {
#pragma unroll
        for (int t=0;t<3;t++){
            int s = idx[n*3+t];
            float v = vals[n*3+t];
            if (s > n && v != 0.0f){ srcs[t]=s; valid[t]=true; }
        }
    }

    float xrv[DPT], attv[DPT];
#pragma unroll
    for (int q=0;q<DPT/4;q++){
        ushort4 u = *(const ushort4*)(xlxr + (size_t)n*ldx + xrOff + h*D + d0 + q*4);
        xrv[q*4+0]=b2f(u.x); xrv[q*4+1]=b2f(u.y); xrv[q*4+2]=b2f(u.z); xrv[q*4+3]=b2f(u.w);
        *(float4*)&attv[q*4] = *(const float4*)(att + h*D + d0 + q*4);
    }

    float xs[4][DPT];
    float sc[4];
#pragma unroll
    for (int s=0;s<4;s++){
#pragma unroll
        for (int q=0;q<DPT/4;q++){
            ushort4 u = *(const ushort4*)(xlxr + (size_t)srcs[s]*ldx + h*D + d0 + q*4);
            xs[s][q*4+0]=b2f(u.x); xs[s][q*4+1]=b2f(u.y); xs[s][q*4+2]=b2f(u.z); xs[s][q*4+3]=b2f(u.w);
        }
        float p = 0.f;
#pragma unroll
        for (int d=0;d<DPT;d++){
            float e = xs[s][d] + xrv[d];
            e = (e > 0.f) ? e : 0.2f*e;
            p += attv[d]*e;
        }
#pragma unroll
        for (int off=1; off<TPH; off<<=1) p += __shfl_xor(p, off);
        sc[s] = p;
    }
    float m = NEG_INF;
#pragma unroll
    for (int s=0;s<4;s++) if (valid[s]) m = fmaxf(m, sc[s]);
    float al[4]; float denom = 0.f;
#pragma unroll
    for (int s=0;s<4;s++){ al[s] = valid[s] ? expf(sc[s]-m) : 0.f; denom += al[s]; }
    float inv = 1.f / denom;

    float o[DPT];
#pragma unroll
    for (int d=0;d<DPT;d++){
        float acc = al[0]*xs[0][d] + al[1]*xs[1][d] + al[2]*xs[2][d] + al[3]*xs[3][d];
        acc = acc*inv + bias[h*D + d0 + d];
        o[d] = (acc > 0.f) ? acc : (expf(acc) - 1.f);
    }
    if constexpr (OUTBF) {
        u16 ov[DPT];
#pragma unroll
        for (int d=0;d<DPT;d++) ov[d] = f2bu(o[d]);
#pragma unroll
        for (int q=0;q<DPT/8;q++)
            *(uint4*)((u16*)outp + (size_t)n*ldo + h*D + d0 + q*8) = *(uint4*)&ov[q*8];
        if constexpr (DPT < 8)
            *(uint2*)((u16*)outp + (size_t)n*ldo + h*D + d0) = *(uint2*)ov;
    } else {
#pragma unroll
        for (int q=0;q<DPT/4;q++)
            *(float4*)((float*)outp + (size_t)n*ldo + h*D + d0 + q*4) = *(float4*)&o[q*4];
    }
}

// ---------------------------------------------------------------------------
extern "C" void kernel_launch(void* const* d_in, const int* in_sizes, int n_in,
                              void* d_out, int out_size, void* d_ws, size_t ws_size,
                              hipStream_t stream)
{
    (void)in_sizes; (void)n_in;
    const float* x      = (const float*)d_in[0];
    const float* conv_w = (const float*)d_in[1];
    const float* conv_b = (const float*)d_in[2];
    const float* fc2_w  = (const float*)d_in[3];
    const float* fc2_b  = (const float*)d_in[4];
    const float* fc3_w  = (const float*)d_in[5];
    const float* fc3_b  = (const float*)d_in[6];
    const float* g_wl[4]   = {(const float*)d_in[7],  (const float*)d_in[13], (const float*)d_in[19], (const float*)d_in[25]};
    const float* g_bl[4]   = {(const float*)d_in[8],  (const float*)d_in[14], (const float*)d_in[20], (const float*)d_in[26]};
    const float* g_wr[4]   = {(const float*)d_in[9],  (const float*)d_in[15], (const float*)d_in[21], (const float*)d_in[27]};
    const float* g_br[4]   = {(const float*)d_in[10], (const float*)d_in[16], (const float*)d_in[22], (const float*)d_in[28]};
    const float* g_att[4]  = {(const float*)d_in[11], (const float*)d_in[17], (const float*)d_in[23], (const float*)d_in[29]};
    const float* g_bias[4] = {(const float*)d_in[12], (const float*)d_in[18], (const float*)d_in[24], (const float*)d_in[30]};

    float* ws = (float*)d_ws;
    size_t off = 0;
    float* emb1  = ws + off; off += 2359296;                  // [9216][256] f32 (persists)
    size_t emb_off = off;
    float* emb   = ws + off; off += 2359296;
    u16*   emb_h = (u16*)(ws + off); off += 1179648;          // [9216][256] bf16
    u16*   emb_l = (u16*)(ws + off); off += 1179648;
    u16*   Wt[4];
    Wt[0] = (u16*)(ws + off); off += 524288;                  // [4096][256] bf16
    Wt[1] = (u16*)(ws + off); off += 524288;                  // [512][2048] bf16
    Wt[2] = (u16*)(ws + off); off += 524288;
    Wt[3] = (u16*)(ws + off); off += 524288;
    float* apv  = ws + off; off += 3981312;                   // [9216][144][3]
    int*   api  = (int*)(ws + off); off += 3981312;
    int*   c8i  = (int*)(ws + off); off += 73728;             // [9216][8]
    float* vals = ws + off; off += 27648;
    int*   idx  = (int*)(ws + off); off += 27648;
    float* h2   = ws + off; off += 2359296;
    float* h4   = ws + off; off += 2359296;
    u16*   xlxr = (u16*)(ws + off); off += 18874368;          // [9216][4096] u16
    u16*   hbig = (u16*)(ws + off); off += 9437184;           // [9216][2048] u16
    u16*   WbH  = (u16*)(ws + off); off += 851968;            // [256][6400] bf16 (conv W split)
    u16*   WbL  = (u16*)(ws + off); off += 851968;
    // conv-phase scratch, aliased onto post-conv region starting at emb
    u16*   xp_h = (u16*)(ws + emb_off);                          // [4608][6400] u16
    u16*   xp_l = (u16*)(ws + emb_off + 14745600);
    float* cpart = ws + emb_off + 29491200;                      // [4][4608][256] f32
    size_t need = off * sizeof(float);
    if (ws_size < need) {
        hipMemsetAsync(d_out, 0, (size_t)out_size*sizeof(float), stream);
        return;
    }
    float* out = (float*)d_out;

    // conv1 = bf16-split-3-term NT GEMM over im2col'd x (two row-halves, K-split x4).
    cvt_hilo<<<1600,256,0,stream>>>(conv_w, WbH, WbL, 409600);
    for (int half = 0; half < 2; ++half) {
        xpb_build<<<28800,256,0,stream>>>(x, half*4608, xp_h, xp_l);
        mm_conv<<<dim3(36,2,4),256,0,stream>>>(xp_h, xp_l, 6400, WbH, WbL, 6400, cpart, 1600);
        conv_reduce2<<<1152,256,0,stream>>>(cpart, conv_b, emb1 + (size_t)half*4608*256);
    }
    // fc2 fp32 -> emb (exact; feeds graph + rescore)
    gemm_f32<1><<<dim3(72,4),256,0,stream>>>(emb1,256,256, emb1,256, fc2_w, fc2_b, nullptr, emb, 9216,256,256);

    // conversions: emb -> hi/lo ; weights -> transposed bf16 (wl rows 0..N-1, wr rows N..2N-1)
    cvt_hilo<<<2304,256,0,stream>>>(emb, emb_h, emb_l, 589824);
    transpose_cvt<<<dim3(8,64),256,0,stream>>>(g_wl[0], 256, 2048, Wt[0]);
    transpose_cvt<<<dim3(8,64),256,0,stream>>>(g_wr[0], 256, 2048, Wt[0] + (size_t)2048*256);
    transpose_cvt<<<dim3(64,8),256,0,stream>>>(g_wl[1], 2048, 256, Wt[1]);
    transpose_cvt<<<dim3(64,8),256,0,stream>>>(g_wr[1], 2048, 256, Wt[1] + (size_t)256*2048);
    transpose_cvt<<<dim3(8,64),256,0,stream>>>(g_wl[2], 256, 2048, Wt[2]);
    transpose_cvt<<<dim3(8,64),256,0,stream>>>(g_wr[2], 256, 2048, Wt[2] + (size_t)2048*256);
    transpose_cvt<<<dim3(64,8),256,0,stream>>>(g_wl[3], 2048, 256, Wt[3]);
    transpose_cvt<<<dim3(64,8),256,0,stream>>>(g_wr[3], 2048, 256, Wt[3] + (size_t)256*2048);

    // similarity kNN: 1-term bf16 symmetric candidates -> wave-parallel top-8 merge
    // -> exact fp32 rescore -> top-3.
    mm_adj<<<dim3(72,72),256,0,stream>>>(emb_h, 256, apv, api);
    adj_merge8<<<2304,256,0,stream>>>(apv, api, c8i);
    rescore_select<<<2304,256,0,stream>>>(emb, c8i, vals, idx);

    // g1 (H=8, similarity graph)
    mm_proj<<<dim3(72,32),256,0,stream>>>(emb_h, 256, Wt[0], 256, g_bl[0], g_br[0], 2048,
                                          xlxr, 4096, 256);
    gat_agg<8,32,false,true><<<9216,256,0,stream>>>(xlxr, 4096, 2048, g_att[0], g_bias[0], vals, idx, hbig, 2048);
    // g2 (H=1)
    mm_proj<<<dim3(72,4),256,0,stream>>>(hbig, 2048, Wt[1], 2048, g_bl[1], g_br[1], 256,
                                         xlxr, 512, 2048);
    gat_agg<1,64,false,false><<<9216,64,0,stream>>>(xlxr, 512, 256, g_att[1], g_bias[1], vals, idx, h2, 256);
    // g3 (H=8, spatial graph)
    mm_proj<<<dim3(72,32),256,0,stream>>>(emb_h, 256, Wt[2], 256, g_bl[2], g_br[2], 2048,
                                          xlxr, 4096, 256);
    gat_agg<8,32,true,true><<<9216,256,0,stream>>>(xlxr, 4096, 2048, g_att[2], g_bias[2], nullptr, nullptr, hbig, 2048);
    // g4 (H=1)
    mm_proj<<<dim3(72,4),256,0,stream>>>(hbig, 2048, Wt[3], 2048, g_bl[3], g_br[3], 256,
                                         xlxr, 512, 2048);
    gat_agg<1,64,true,false><<<9216,64,0,stream>>>(xlxr, 512, 256, g_att[3], g_bias[3], nullptr, nullptr, h4, 256);

    // fc3 on concat(h2,h4) + relu + residual(h4) -> out
    gemm_f32<1><<<dim3(72,4),256,0,stream>>>(h2,256,256, h4,256, fc3_w, fc3_b, h4, out, 9216,256,512);
}

// Round 15
// 1115.240 us; speedup vs baseline: 1.1116x; 1.1116x over previous
//
#include <hip/hip_runtime.h>
#include <cstdint>
#include <cstddef>

#define NEG_INF (-3.402823466e38f)
typedef unsigned short u16;
typedef unsigned int u32;

typedef short s16x8 __attribute__((ext_vector_type(8)));
typedef __bf16 bf16x8_t __attribute__((ext_vector_type(8)));
typedef float f32x4 __attribute__((ext_vector_type(4)));

__device__ __forceinline__ f32x4 mfma_bf16(s16x8 a, s16x8 b, f32x4 c){
    return __builtin_amdgcn_mfma_f32_16x16x32_bf16(
        __builtin_bit_cast(bf16x8_t, a), __builtin_bit_cast(bf16x8_t, b), c, 0, 0, 0);
}
__device__ __forceinline__ float b2f(u16 u){ return __uint_as_float(((u32)u) << 16); }
__device__ __forceinline__ u16 f2bu(float f){           // RNE fp32 -> bf16 bits
    u32 u = __float_as_uint(f);
    return (u16)((u + 0x7fffu + ((u >> 16) & 1u)) >> 16);
}
// async global->LDS, 16B/lane; LDS dest = wave-uniform base + lane*16 (m97 pattern)
__device__ __forceinline__ void gload16(const u16* __restrict__ g, u16* l){
    __builtin_amdgcn_global_load_lds(
        (const __attribute__((address_space(1))) u32*)g,
        (__attribute__((address_space(3))) u32*)l, 16, 0, 0);
}

// ---------------- top-k helpers (JAX lax.top_k stable: val desc, idx asc on ties) ----
__device__ __forceinline__ bool tk_gt(float v, int i, float w, int j){
    return (v > w) || (v == w && i < j);
}
__device__ __forceinline__ void tk_insert(float v, int id, float tv[3], int ti[3]){
    if (!tk_gt(v, id, tv[2], ti[2])) return;
    if (tk_gt(v, id, tv[1], ti[1])) {
        tv[2]=tv[1]; ti[2]=ti[1];
        if (tk_gt(v, id, tv[0], ti[0])) { tv[1]=tv[0]; ti[1]=ti[0]; tv[0]=v; ti[0]=id; }
        else { tv[1]=v; ti[1]=id; }
    } else { tv[2]=v; ti[2]=id; }
}
__device__ __forceinline__ void tk_insert8(float v, int id, float tv[8], int ti[8]){
    if (!tk_gt(v, id, tv[7], ti[7])) return;
    tv[7]=v; ti[7]=id;
#pragma unroll
    for (int e=7;e>0;e--){
        if (tk_gt(tv[e], ti[e], tv[e-1], ti[e-1])){
            float fv=tv[e]; tv[e]=tv[e-1]; tv[e-1]=fv;
            int   fi=ti[e]; ti[e]=ti[e-1]; ti[e-1]=fi;
        }
    }
}

// ---------------- conversion pre-passes --------------------------------------------
__global__ void cvt_hilo(const float* __restrict__ in, u16* __restrict__ hi,
                         u16* __restrict__ lo, int n4)
{
    int i = blockIdx.x * 256 + threadIdx.x;
    if (i >= n4) return;
    float4 v = ((const float4*)in)[i];
    u16 h[4], l[4];
    float f[4] = {v.x, v.y, v.z, v.w};
#pragma unroll
    for (int j=0;j<4;j++){
        u16 hb = f2bu(f[j]);
        h[j] = hb;
        l[j] = f2bu(f[j] - b2f(hb));
    }
    *(ushort4*)&hi[i*4] = *(ushort4*)h;
    *(ushort4*)&lo[i*4] = *(ushort4*)l;
}

// im2col + bf16-split of x for one half (4608 patch rows), coalesced writes.
__global__ void xpb_build(const float* __restrict__ x, int base,
                          u16* __restrict__ xh, u16* __restrict__ xl)
{
    int gid = blockIdx.x * 256 + threadIdx.x;          // 7,372,800 threads
    int n = gid / 1600;
    int kq = (gid - n*1600) * 4;
    int ng = n + base;
    int pi = ng / 96, pj = ng - pi*96;
    u16 h[4], l[4];
#pragma unroll
    for (int e=0;e<4;e++){
        int k = kq + e;
        int c = k / 25, rem = k - c*25, r = rem / 5, jj = rem - r*5;
        float v = x[(size_t)c*230400 + (size_t)(pi*5+r)*480 + pj*5 + jj];
        u16 hb = f2bu(v);
        h[e] = hb;
        l[e] = f2bu(v - b2f(hb));
    }
    *(ushort4*)&xh[(size_t)n*6400 + kq] = *(ushort4*)h;
    *(ushort4*)&xl[(size_t)n*6400 + kq] = *(ushort4*)l;
}

// sum 4 K-split partials + bias + relu -> emb1 rows (one half = 294912 float4)
__global__ void conv_reduce2(const float* __restrict__ p, const float* __restrict__ bias,
                             float* __restrict__ o)
{
    int i = blockIdx.x * 256 + threadIdx.x;
    const float4* p4 = (const float4*)p;
    float4 s = p4[i];
#pragma unroll
    for (int j=1;j<4;j++){
        float4 v = p4[i + (size_t)j*294912];
        s.x += v.x; s.y += v.y; s.z += v.z; s.w += v.w;
    }
    float4 bb = ((const float4*)bias)[i & 63];
    float4 r;
    r.x = fmaxf(s.x+bb.x, 0.f);
    r.y = fmaxf(s.y+bb.y, 0.f);
    r.z = fmaxf(s.z+bb.z, 0.f);
    r.w = fmaxf(s.w+bb.w, 0.f);
    ((float4*)o)[i] = r;
}

// ---------------- generic fp32 GEMM (fc2, fc3) -------------------------------------
template<int ACT>
__global__ __launch_bounds__(256)
void gemm_f32(const float* __restrict__ A1, int ldA1, int K1,
              const float* __restrict__ A2, int ldA2,
              const float* __restrict__ B, const float* __restrict__ bias,
              const float* __restrict__ add,
              float* __restrict__ C, int M, int N, int K)
{
    __shared__ __align__(16) float As[16][128];
    __shared__ __align__(16) float Bs[16][64];
    const int mb = blockIdx.x * 128, nb = blockIdx.y * 64;
    const int tid = threadIdx.x;
    const int tn = tid & 15, tm = tid >> 4;
    float acc[8][4];
#pragma unroll
    for (int i=0;i<8;i++){
#pragma unroll
        for (int j=0;j<4;j++) acc[i][j]=0.f;
    }
    const int am = tid >> 2;
    const int ak = (tid & 3) * 4;
    const int bk = tid >> 4;
    const int bn = (tid & 15) * 4;

    for (int k0 = 0; k0 < K; k0 += 16) {
        int kg = k0 + ak;
#pragma unroll
        for (int half = 0; half < 2; ++half) {
            int ml = am + half*64;
            int m = mb + ml;
            float4 v;
            if (kg < K1) v = *(const float4*)(A1 + (size_t)m*ldA1 + kg);
            else         v = *(const float4*)(A2 + (size_t)m*ldA2 + (kg - K1));
            As[ak+0][ml] = v.x; As[ak+1][ml] = v.y; As[ak+2][ml] = v.z; As[ak+3][ml] = v.w;
        }
        {
            float4 v = *(const float4*)(B + (size_t)(k0+bk)*N + nb + bn);
            *(float4*)&Bs[bk][bn] = v;
        }
        __syncthreads();
#pragma unroll
        for (int kk=0;kk<16;kk++){
            float a[8], b[4];
            *(float4*)&a[0] = *(const float4*)&As[kk][tm*8];
            *(float4*)&a[4] = *(const float4*)&As[kk][tm*8+4];
            *(float4*)&b[0] = *(const float4*)&Bs[kk][tn*4];
#pragma unroll
            for (int i=0;i<8;i++){
#pragma unroll
                for (int j=0;j<4;j++) acc[i][j] += a[i]*b[j];
            }
        }
        __syncthreads();
    }
#pragma unroll
    for (int i=0;i<8;i++){
        int m = mb + tm*8 + i;
        float ov[4];
#pragma unroll
        for (int j=0;j<4;j++){
            int n = nb + tn*4 + j;
            float v = acc[i][j] + bias[n];
            if (ACT == 1) v = v > 0.f ? v : 0.f;
            if (add) v += add[(size_t)m*N + n];
            ov[j] = v;
        }
        *(float4*)(C + (size_t)m*N + nb + tn*4) = *(float4*)ov;
    }
}

// fp32 [K][N] row-major -> bf16 out[N][K]
__global__ __launch_bounds__(256)
void transpose_cvt(const float* __restrict__ in, int K, int N, u16* __restrict__ out)
{
    __shared__ float t[32][33];
    const int kb = blockIdx.x * 32, nb = blockIdx.y * 32;
    const int tx = threadIdx.x & 31, ty = threadIdx.x >> 5;   // 32 x 8
#pragma unroll
    for (int r=0;r<4;r++)
        t[ty + r*8][tx] = in[(size_t)(kb + ty + r*8)*N + nb + tx];
    __syncthreads();
#pragma unroll
    for (int r=0;r<4;r++)
        out[(size_t)(nb + ty + r*8)*K + kb + tx] = f2bu(t[tx][ty + r*8]);
}

// ---------------- bf16 MFMA NT GEMM core: C[M][N] = A[M][K] @ B[N][K]^T ------------
// 128x128 tile, BK=32, 256 thr (4 waves as 2x2 of 64x64); global_load_lds staging
// into linear LDS [128][32]. SPLIT: (hi,lo) 3-term. EPI 0: bf16 store via LDS-bounce
// coalesced uint4. EPI 1 (R15): SWAPPED-operand top-3 candidates — A-operand is the
// adj COLUMN tile, B-operand the adj ROW tile, so each lane owns 4 adj-rows (nj,fr)
// with 16 lane-local c-values (mi,t); 16 local inserts + 2-step fq-butterfly give the
// exact top-3 per (row, 64-c window). Full grid (no triangle). EPI 2: conv K-split.
template<bool SPLIT, int EPI>
__device__ __forceinline__
void mm_core(const u16* __restrict__ Ah, const u16* __restrict__ Al, int lda,
             const u16* __restrict__ Bh, const u16* __restrict__ Bl, int ldb,
             const float* __restrict__ bias0, const float* __restrict__ bias1, int nHalf,
             void* __restrict__ Cout, int ldc, int K,
             float* __restrict__ pval, int* __restrict__ pidx)
{
    constexpr int TSZ = 128 * 32;
    __shared__ u16 smem[(SPLIT ? 4 : 2) * TSZ];
    u16* AsH = smem;
    u16* BsH = smem + TSZ;
    u16* AsL = SPLIT ? smem + 2*TSZ : nullptr;
    u16* BsL = SPLIT ? smem + 3*TSZ : nullptr;

    const int tid = threadIdx.x;
    const int w = tid >> 6, ln = tid & 63;
    const int wr = w >> 1, wc = w & 1;
    const int fr = ln & 15, fq = ln >> 4;
    const int mb = blockIdx.x * 128, nb = blockIdx.y * 128;
    const int skk = (ln & 3) * 8;        // staging: k element offset
    const int srow = ln >> 2;            // staging: row within 16-row group

    int kbeg = 0;
    if constexpr (EPI == 2) kbeg = blockIdx.z * K;
    const int kend = kbeg + K;

    f32x4 acc[4][4];
#pragma unroll
    for (int i=0;i<4;i++)
#pragma unroll
        for (int j=0;j<4;j++) acc[i][j] = (f32x4){0.f,0.f,0.f,0.f};

    for (int k0 = kbeg; k0 < kend; k0 += 32) {
#pragma unroll
        for (int t=0;t<2;t++){
            int rbase = w*32 + t*16;
            int r = rbase + srow;
            size_t goA = (size_t)(mb + r)*lda + k0 + skk;
            size_t goB = (size_t)(nb + r)*ldb + k0 + skk;
            gload16(Ah + goA, AsH + rbase*32);
            gload16(Bh + goB, BsH + rbase*32);
            if constexpr (SPLIT){
                gload16(Al + goA, AsL + rbase*32);
                gload16(Bl + goB, BsL + rbase*32);
            }
        }
        __syncthreads();
        s16x8 ah[4], bh[4], al[4], bl[4];
#pragma unroll
        for (int mi=0;mi<4;mi++){
            int ro = (wr*64 + mi*16 + fr)*32 + fq*8;
            ah[mi] = *(const s16x8*)&AsH[ro];
            if constexpr (SPLIT) al[mi] = *(const s16x8*)&AsL[ro];
        }
#pragma unroll
        for (int nj=0;nj<4;nj++){
            int ro = (wc*64 + nj*16 + fr)*32 + fq*8;
            bh[nj] = *(const s16x8*)&BsH[ro];
            if constexpr (SPLIT) bl[nj] = *(const s16x8*)&BsL[ro];
        }
#pragma unroll
        for (int mi=0;mi<4;mi++)
#pragma unroll
            for (int nj=0;nj<4;nj++){
                acc[mi][nj] = mfma_bf16(ah[mi], bh[nj], acc[mi][nj]);
                if constexpr (SPLIT){
                    acc[mi][nj] = mfma_bf16(ah[mi], bl[nj], acc[mi][nj]);
                    acc[mi][nj] = mfma_bf16(al[mi], bh[nj], acc[mi][nj]);
                }
            }
        __syncthreads();
    }

    if constexpr (EPI == 0) {
        // LDS-bounce: 4 chunks of 32 rows x 128 cols bf16, pad 136 u16/row; then
        // coalesced uint4 stores (16B/lane).
        u16* ldsc = smem;
#pragma unroll
        for (int chunk=0; chunk<4; ++chunk){
            __syncthreads();
            if (wr == (chunk>>1)){
                int mi0 = (chunk&1)*2;
#pragma unroll
                for (int m2=0;m2<2;m2++){
                    int mi = mi0 + m2;
#pragma unroll
                    for (int nj=0;nj<4;nj++)
#pragma unroll
                    for (int t=0;t<4;t++){
                        int lr = m2*16 + fq*4 + t;
                        int lc = wc*64 + nj*16 + fr;
                        int col = nb + lc;
                        float v = acc[mi][nj][t];
                        if (bias0) v += (col < nHalf) ? bias0[col] : bias1[col - nHalf];
                        ldsc[lr*136 + lc] = f2bu(v);
                    }
                }
            }
            __syncthreads();
            int c0 = chunk*32;
#pragma unroll
            for (int q=0;q<2;q++){
                int e = q*256 + tid;
                int lr = e >> 4, c16 = e & 15;
                *(uint4*)((u16*)Cout + (size_t)(mb + c0 + lr)*ldc + nb + c16*8)
                    = *(const uint4*)&ldsc[lr*136 + c16*8];
            }
        }
    } else if constexpr (EPI == 2) {
        // LDS-bounce: 8 chunks of 16 rows x 128 cols f32, pad 132 f32/row.
        float* ldsf = (float*)smem;
#pragma unroll
        for (int chunk=0; chunk<8; ++chunk){
            __syncthreads();
            if (wr == (chunk>>2)){
                int mi = chunk & 3;
#pragma unroll
                for (int nj=0;nj<4;nj++)
#pragma unroll
                for (int t=0;t<4;t++){
                    int lr = fq*4 + t;
                    int lc = wc*64 + nj*16 + fr;
                    ldsf[lr*132 + lc] = acc[mi][nj][t];
                }
            }
            __syncthreads();
            int c0 = chunk*16;
#pragma unroll
            for (int q=0;q<2;q++){
                int e = q*256 + tid;
                int lr = e >> 5, c4 = e & 31;
                *(float4*)((float*)Cout + ((size_t)blockIdx.z*4608 + mb + c0 + lr)*256 + nb + c4*4)
                    = *(const float4*)&ldsf[lr*132 + c4*4];
            }
        }
    } else {
        // R15 swapped-selection epilogue. adj row = B-side (nb + wc*64 + nj*16 + fr),
        // c = A-side (mb + wr*64 + mi*16 + fq*4 + t). 16 lane-local inserts per row,
        // then fq-butterfly (xor 16,32) -> exact top-3 of the 64-c window; fq==0 writes.
        const int cbR = blockIdx.x * 2 + wr;
#pragma unroll
        for (int nj=0;nj<4;nj++){
            int row = nb + wc*64 + nj*16 + fr;
            float tv[3] = {NEG_INF, NEG_INF, NEG_INF};
            int   ti[3] = {0x7fffffff, 0x7fffffff, 0x7fffffff};
#pragma unroll
            for (int mi=0;mi<4;mi++)
#pragma unroll
                for (int t=0;t<4;t++)
                    tk_insert(acc[mi][nj][t], mb + wr*64 + mi*16 + fq*4 + t, tv, ti);
#pragma unroll
            for (int off=16; off<64; off<<=1){
                float ov[3]; int oi[3];
#pragma unroll
                for (int e=0;e<3;e++){ ov[e]=__shfl_xor(tv[e],off); oi[e]=__shfl_xor(ti[e],off); }
#pragma unroll
                for (int e=0;e<3;e++) tk_insert(ov[e], oi[e], tv, ti);
            }
            if (fq == 0){
#pragma unroll
                for (int e=0;e<3;e++){
                    pval[(size_t)row*432 + cbR*3 + e] = tv[e];
                    pidx[(size_t)row*432 + cbR*3 + e] = ti[e];
                }
            }
        }
    }
}

// named instantiations (distinct rocprof rows)
__global__ __launch_bounds__(256)
void mm_proj(const u16* Ah, int lda, const u16* Bh, int ldb,
             const float* bias0, const float* bias1, int nHalf,
             void* Cout, int ldc, int K)
{
    mm_core<false,0>(Ah, nullptr, lda, Bh, nullptr, ldb, bias0, bias1, nHalf,
                     Cout, ldc, K, nullptr, nullptr);
}
__global__ __launch_bounds__(256)
void mm_adj(const u16* Ah, int lda, float* pval, int* pidx)
{
    mm_core<false,1>(Ah, nullptr, lda, Ah, nullptr, lda, nullptr, nullptr, 0,
                     nullptr, 0, 256, pval, pidx);
}
__global__ __launch_bounds__(256)
void mm_conv(const u16* Ah, const u16* Al, int lda, const u16* Bh, const u16* Bl, int ldb,
             float* Cout, int K)
{
    mm_core<true,2>(Ah, Al, lda, Bh, Bl, ldb, nullptr, nullptr, 0,
                    Cout, 256, K, nullptr, nullptr);
}

// merge 432 partial entries per row -> approx top-8, ONE WAVE PER ROW.
__global__ __launch_bounds__(256)
void adj_merge8(const float* __restrict__ pvals, const int* __restrict__ pidx,
                int* __restrict__ c8i)
{
    int row = blockIdx.x * 4 + (threadIdx.x >> 6);
    int ln = threadIdx.x & 63;
    float tv[8]; int ti[8];
#pragma unroll
    for (int e=0;e<8;e++){ tv[e]=NEG_INF; ti[e]=0x7fffffff; }
    for (int t = ln; t < 432; t += 64)
        tk_insert8(pvals[(size_t)row*432 + t], pidx[(size_t)row*432 + t], tv, ti);
#pragma unroll
    for (int off=1; off<64; off<<=1){
        float ov[8]; int oi[8];
#pragma unroll
        for (int e=0;e<8;e++){ ov[e]=__shfl_xor(tv[e],off); oi[e]=__shfl_xor(ti[e],off); }
#pragma unroll
        for (int e=0;e<8;e++) tk_insert8(ov[e], oi[e], tv, ti);
    }
    if (ln == 0){
#pragma unroll
        for (int e=0;e<8;e++) c8i[row*8+e] = ti[e];
    }
}

// exact fp32 rescore of 8 candidates per row, final top-3 (lax.top_k semantics).
__global__ __launch_bounds__(256)
void rescore_select(const float* __restrict__ emb, const int* __restrict__ c8i,
                    float* __restrict__ vals, int* __restrict__ idx)
{
    int gid = blockIdx.x * 256 + threadIdx.x;
    int row = gid >> 6;
    int ln = threadIdx.x & 63;
    float a[4];
    *(float4*)a = *(const float4*)(emb + (size_t)row*256 + ln*4);
    float sc[8];
#pragma unroll
    for (int c=0;c<8;c++){
        int cand = c8i[row*8+c];
        float4 b = *(const float4*)(emb + (size_t)cand*256 + ln*4);
        float p = a[0]*b.x + a[1]*b.y + a[2]*b.z + a[3]*b.w;
#pragma unroll
        for (int off=1; off<64; off<<=1) p += __shfl_xor(p, off);
        sc[c] = p;
    }
    if (ln == 0){
        float tv[3]={NEG_INF,NEG_INF,NEG_INF};
        int   ti[3]={0x7fffffff,0x7fffffff,0x7fffffff};
#pragma unroll
        for (int c=0;c<8;c++) tk_insert(sc[c], c8i[row*8+c], tv, ti);
#pragma unroll
        for (int e=0;e<3;e++){ vals[row*3+e]=tv[e]; idx[row*3+e]=ti[e]; }
    }
}

// ---------------- GATv2 softmax + aggregate + bias + ELU, bf16 inputs --------------
template<int H, int TPH, bool SPATIAL, bool OUTBF>
__global__ __launch_bounds__(H*TPH)
void gat_agg(const u16* __restrict__ xlxr, int ldx, int xrOff,
             const float* __restrict__ att, const float* __restrict__ bias,
             const float* __restrict__ vals, const int* __restrict__ idx,
             void* __restrict__ outp, int ldo)
{
    constexpr int D = 256;
    constexpr int DPT = D / TPH;
    const int n = blockIdx.x;
    const int tid = threadIdx.x;
    const int h = tid / TPH;
    const int l = tid % TPH;
    const int d0 = l * DPT;

    int srcs[4]; bool valid[4];
#pragma unroll
    for (int s=0;s<4;s++){ srcs[s]=n; valid[s]=(s==3); }
    if constexpr (SPATIAL) {
        int pi = n / 96, pj = n - (n/96)*96;
        int cand[4]; int nc=0;
        if (pi > 0)  cand[nc++] = n - 96;
        if (pj > 0)  cand[nc++] = n - 1;
        if (pj < 95) cand[nc++] = n + 1;
        if (pi < 95) cand[nc++] = n + 96;
        int s0 = cand[0], s1 = cand[1];
        if (s0 > n){ srcs[0]=s0; valid[0]=true; }
        if (s1 > n){ srcs[1]=s1; valid[1]=true; }
    } else {
#pragma unroll
        for (int t=0;t<3;t++){
            int s = idx[n*3+t];
            float v = vals[n*3+t];
            if (s > n && v != 0.0f){ srcs[t]=s; valid[t]=true; }
        }
    }

    float xrv[DPT], attv[DPT];
#pragma unroll
    for (int q=0;q<DPT/4;q++){
        ushort4 u = *(const ushort4*)(xlxr + (size_t)n*ldx + xrOff + h*D + d0 + q*4);
        xrv[q*4+0]=b2f(u.x); xrv[q*4+1]=b2f(u.y); xrv[q*4+2]=b2f(u.z); xrv[q*4+3]=b2f(u.w);
        *(float4*)&attv[q*4] = *(const float4*)(att + h*D + d0 + q*4);
    }

    float xs[4][DPT];
    float sc[4];
#pragma unroll
    for (int s=0;s<4;s++){
#pragma unroll
        for (int q=0;q<DPT/4;q++){
            ushort4 u = *(const ushort4*)(xlxr + (size_t)srcs[s]*ldx + h*D + d0 + q*4);
            xs[s][q*4+0]=b2f(u.x); xs[s][q*4+1]=b2f(u.y); xs[s][q*4+2]=b2f(u.z); xs[s][q*4+3]=b2f(u.w);
        }
        float p = 0.f;
#pragma unroll
        for (int d=0;d<DPT;d++){
            float e = xs[s][d] + xrv[d];
            e = (e > 0.f) ? e : 0.2f*e;
            p += attv[d]*e;
        }
#pragma unroll
        for (int off=1; off<TPH; off<<=1) p += __shfl_xor(p, off);
        sc[s] = p;
    }
    float m = NEG_INF;
#pragma unroll
    for (int s=0;s<4;s++) if (valid[s]) m = fmaxf(m, sc[s]);
    float al[4]; float denom = 0.f;
#pragma unroll
    for (int s=0;s<4;s++){ al[s] = valid[s] ? expf(sc[s]-m) : 0.f; denom += al[s]; }
    float inv = 1.f / denom;

    float o[DPT];
#pragma unroll
    for (int d=0;d<DPT;d++){
        float acc = al[0]*xs[0][d] + al[1]*xs[1][d] + al[2]*xs[2][d] + al[3]*xs[3][d];
        acc = acc*inv + bias[h*D + d0 + d];
        o[d] = (acc > 0.f) ? acc : (expf(acc) - 1.f);
    }
    if constexpr (OUTBF) {
        u16 ov[DPT];
#pragma unroll
        for (int d=0;d<DPT;d++) ov[d] = f2bu(o[d]);
#pragma unroll
        for (int q=0;q<DPT/8;q++)
            *(uint4*)((u16*)outp + (size_t)n*ldo + h*D + d0 + q*8) = *(uint4*)&ov[q*8];
        if constexpr (DPT < 8)
            *(uint2*)((u16*)outp + (size_t)n*ldo + h*D + d0) = *(uint2*)ov;
    } else {
#pragma unroll
        for (int q=0;q<DPT/4;q++)
            *(float4*)((float*)outp + (size_t)n*ldo + h*D + d0 + q*4) = *(float4*)&o[q*4];
    }
}

// ---------------------------------------------------------------------------
extern "C" void kernel_launch(void* const* d_in, const int* in_sizes, int n_in,
                              void* d_out, int out_size, void* d_ws, size_t ws_size,
                              hipStream_t stream)
{
    (void)in_sizes; (void)n_in;
    const float* x      = (const float*)d_in[0];
    const float* conv_w = (const float*)d_in[1];
    const float* conv_b = (const float*)d_in[2];
    const float* fc2_w  = (const float*)d_in[3];
    const float* fc2_b  = (const float*)d_in[4];
    const float* fc3_w  = (const float*)d_in[5];
    const float* fc3_b  = (const float*)d_in[6];
    const float* g_wl[4]   = {(const float*)d_in[7],  (const float*)d_in[13], (const float*)d_in[19], (const float*)d_in[25]};
    const float* g_bl[4]   = {(const float*)d_in[8],  (const float*)d_in[14], (const float*)d_in[20], (const float*)d_in[26]};
    const float* g_wr[4]   = {(const float*)d_in[9],  (const float*)d_in[15], (const float*)d_in[21], (const float*)d_in[27]};
    const float* g_br[4]   = {(const float*)d_in[10], (const float*)d_in[16], (const float*)d_in[22], (const float*)d_in[28]};
    const float* g_att[4]  = {(const float*)d_in[11], (const float*)d_in[17], (const float*)d_in[23], (const float*)d_in[29]};
    const float* g_bias[4] = {(const float*)d_in[12], (const float*)d_in[18], (const float*)d_in[24], (const float*)d_in[30]};

    float* ws = (float*)d_ws;
    size_t off = 0;
    float* emb1  = ws + off; off += 2359296;                  // [9216][256] f32 (persists)
    size_t emb_off = off;
    float* emb   = ws + off; off += 2359296;
    u16*   emb_h = (u16*)(ws + off); off += 1179648;          // [9216][256] bf16
    u16*   emb_l = (u16*)(ws + off); off += 1179648;
    u16*   Wt[4];
    Wt[0] = (u16*)(ws + off); off += 524288;                  // [4096][256] bf16
    Wt[1] = (u16*)(ws + off); off += 524288;                  // [512][2048] bf16
    Wt[2] = (u16*)(ws + off); off += 524288;
    Wt[3] = (u16*)(ws + off); off += 524288;
    float* apv  = ws + off; off += 3981312;                   // [9216][144][3]
    int*   api  = (int*)(ws + off); off += 3981312;
    int*   c8i  = (int*)(ws + off); off += 73728;             // [9216][8]
    float* vals = ws + off; off += 27648;
    int*   idx  = (int*)(ws + off); off += 27648;
    float* h2   = ws + off; off += 2359296;
    float* h4   = ws + off; off += 2359296;
    u16*   xlxr = (u16*)(ws + off); off += 18874368;          // [9216][4096] u16
    u16*   hbig = (u16*)(ws + off); off += 9437184;           // [9216][2048] u16
    u16*   WbH  = (u16*)(ws + off); off += 851968;            // [256][6400] bf16 (conv W split)
    u16*   WbL  = (u16*)(ws + off); off += 851968;
    // conv-phase scratch, aliased onto post-conv region starting at emb
    u16*   xp_h = (u16*)(ws + emb_off);                          // [4608][6400] u16
    u16*   xp_l = (u16*)(ws + emb_off + 14745600);
    float* cpart = ws + emb_off + 29491200;                      // [4][4608][256] f32
    size_t need = off * sizeof(float);
    if (ws_size < need) {
        hipMemsetAsync(d_out, 0, (size_t)out_size*sizeof(float), stream);
        return;
    }
    float* out = (float*)d_out;

    // conv1 = bf16-split-3-term NT GEMM over im2col'd x (two row-halves, K-split x4).
    cvt_hilo<<<1600,256,0,stream>>>(conv_w, WbH, WbL, 409600);
    for (int half = 0; half < 2; ++half) {
        xpb_build<<<28800,256,0,stream>>>(x, half*4608, xp_h, xp_l);
        mm_conv<<<dim3(36,2,4),256,0,stream>>>(xp_h, xp_l, 6400, WbH, WbL, 6400, cpart, 1600);
        conv_reduce2<<<1152,256,0,stream>>>(cpart, conv_b, emb1 + (size_t)half*4608*256);
    }
    // fc2 fp32 -> emb (exact; feeds graph + rescore)
    gemm_f32<1><<<dim3(72,4),256,0,stream>>>(emb1,256,256, emb1,256, fc2_w, fc2_b, nullptr, emb, 9216,256,256);

    // conversions: emb -> hi/lo ; weights -> transposed bf16 (wl rows 0..N-1, wr rows N..2N-1)
    cvt_hilo<<<2304,256,0,stream>>>(emb, emb_h, emb_l, 589824);
    transpose_cvt<<<dim3(8,64),256,0,stream>>>(g_wl[0], 256, 2048, Wt[0]);
    transpose_cvt<<<dim3(8,64),256,0,stream>>>(g_wr[0], 256, 2048, Wt[0] + (size_t)2048*256);
    transpose_cvt<<<dim3(64,8),256,0,stream>>>(g_wl[1], 2048, 256, Wt[1]);
    transpose_cvt<<<dim3(64,8),256,0,stream>>>(g_wr[1], 2048, 256, Wt[1] + (size_t)256*2048);
    transpose_cvt<<<dim3(8,64),256,0,stream>>>(g_wl[2], 256, 2048, Wt[2]);
    transpose_cvt<<<dim3(8,64),256,0,stream>>>(g_wr[2], 256, 2048, Wt[2] + (size_t)2048*256);
    transpose_cvt<<<dim3(64,8),256,0,stream>>>(g_wl[3], 2048, 256, Wt[3]);
    transpose_cvt<<<dim3(64,8),256,0,stream>>>(g_wr[3], 2048, 256, Wt[3] + (size_t)256*2048);

    // similarity kNN: 1-term bf16 candidates (full grid, swapped-operand lane-local
    // selection) -> wave-parallel top-8 merge -> exact fp32 rescore -> top-3.
    mm_adj<<<dim3(72,72),256,0,stream>>>(emb_h, 256, apv, api);
    adj_merge8<<<2304,256,0,stream>>>(apv, api, c8i);
    rescore_select<<<2304,256,0,stream>>>(emb, c8i, vals, idx);

    // g1 (H=8, similarity graph)
    mm_proj<<<dim3(72,32),256,0,stream>>>(emb_h, 256, Wt[0], 256, g_bl[0], g_br[0], 2048,
                                          xlxr, 4096, 256);
    gat_agg<8,32,false,true><<<9216,256,0,stream>>>(xlxr, 4096, 2048, g_att[0], g_bias[0], vals, idx, hbig, 2048);
    // g2 (H=1)
    mm_proj<<<dim3(72,4),256,0,stream>>>(hbig, 2048, Wt[1], 2048, g_bl[1], g_br[1], 256,
                                         xlxr, 512, 2048);
    gat_agg<1,64,false,false><<<9216,64,0,stream>>>(xlxr, 512, 256, g_att[1], g_bias[1], vals, idx, h2, 256);
    // g3 (H=8, spatial graph)
    mm_proj<<<dim3(72,32),256,0,stream>>>(emb_h, 256, Wt[2], 256, g_bl[2], g_br[2], 2048,
                                          xlxr, 4096, 256);
    gat_agg<8,32,true,true><<<9216,256,0,stream>>>(xlxr, 4096, 2048, g_att[2], g_bias[2], nullptr, nullptr, hbig, 2048);
    // g4 (H=1)
    mm_proj<<<dim3(72,4),256,0,stream>>>(hbig, 2048, Wt[3], 2048, g_bl[3], g_br[3], 256,
                                         xlxr, 512, 2048);
    gat_agg<1,64,true,false><<<9216,64,0,stream>>>(xlxr, 512, 256, g_att[3], g_bias[3], nullptr, nullptr, h4, 256);

    // fc3 on concat(h2,h4) + relu + residual(h4) -> out
    gemm_f32<1><<<dim3(72,4),256,0,stream>>>(h2,256,256, h4,256, fc3_w, fc3_b, h4, out, 9216,256,512);
}

// Round 16
// 1007.356 us; speedup vs baseline: 1.2306x; 1.1071x over previous
//
#include <hip/hip_runtime.h>
#include <cstdint>
#include <cstddef>

#define NEG_INF (-3.402823466e38f)
typedef unsigned short u16;
typedef unsigned int u32;
typedef unsigned long long u64;

typedef short s16x8 __attribute__((ext_vector_type(8)));
typedef __bf16 bf16x8_t __attribute__((ext_vector_type(8)));
typedef float f32x4 __attribute__((ext_vector_type(4)));

__device__ __forceinline__ f32x4 mfma_bf16(s16x8 a, s16x8 b, f32x4 c){
    return __builtin_amdgcn_mfma_f32_16x16x32_bf16(
        __builtin_bit_cast(bf16x8_t, a), __builtin_bit_cast(bf16x8_t, b), c, 0, 0, 0);
}
__device__ __forceinline__ float b2f(u16 u){ return __uint_as_float(((u32)u) << 16); }
__device__ __forceinline__ u16 f2bu(float f){           // RNE fp32 -> bf16 bits
    u32 u = __float_as_uint(f);
    return (u16)((u + 0x7fffu + ((u >> 16) & 1u)) >> 16);
}
// async global->LDS, 16B/lane; LDS dest = wave-uniform base + lane*16 (m97 pattern)
__device__ __forceinline__ void gload16(const u16* __restrict__ g, u16* l){
    __builtin_amdgcn_global_load_lds(
        (const __attribute__((address_space(1))) u32*)g,
        (__attribute__((address_space(3))) u32*)l, 16, 0, 0);
}
// monotone (val desc, idx asc) <-> u64 key desc ; keys unique (idx unique), > 0
__device__ __forceinline__ u64 mkkey(float v, int id){
    u32 s = __float_as_uint(v);
    s ^= (u32)(((int)s >> 31)) | 0x80000000u;
    return ((u64)s << 32) | (u32)(~(u32)id);
}

// ---------------- top-k helpers (JAX lax.top_k stable: val desc, idx asc on ties) ----
__device__ __forceinline__ bool tk_gt(float v, int i, float w, int j){
    return (v > w) || (v == w && i < j);
}
__device__ __forceinline__ void tk_insert(float v, int id, float tv[3], int ti[3]){
    if (!tk_gt(v, id, tv[2], ti[2])) return;
    if (tk_gt(v, id, tv[1], ti[1])) {
        tv[2]=tv[1]; ti[2]=ti[1];
        if (tk_gt(v, id, tv[0], ti[0])) { tv[1]=tv[0]; ti[1]=ti[0]; tv[0]=v; ti[0]=id; }
        else { tv[1]=v; ti[1]=id; }
    } else { tv[2]=v; ti[2]=id; }
}

// ---------------- conversion pre-passes --------------------------------------------
__global__ void cvt_hilo(const float* __restrict__ in, u16* __restrict__ hi,
                         u16* __restrict__ lo, int n4)
{
    int i = blockIdx.x * 256 + threadIdx.x;
    if (i >= n4) return;
    float4 v = ((const float4*)in)[i];
    u16 h[4], l[4];
    float f[4] = {v.x, v.y, v.z, v.w};
#pragma unroll
    for (int j=0;j<4;j++){
        u16 hb = f2bu(f[j]);
        h[j] = hb;
        l[j] = f2bu(f[j] - b2f(hb));
    }
    *(ushort4*)&hi[i*4] = *(ushort4*)h;
    *(ushort4*)&lo[i*4] = *(ushort4*)l;
}

// im2col + bf16-split of x for one half (4608 patch rows), coalesced writes.
__global__ void xpb_build(const float* __restrict__ x, int base,
                          u16* __restrict__ xh, u16* __restrict__ xl)
{
    int gid = blockIdx.x * 256 + threadIdx.x;          // 7,372,800 threads
    int n = gid / 1600;
    int kq = (gid - n*1600) * 4;
    int ng = n + base;
    int pi = ng / 96, pj = ng - pi*96;
    u16 h[4], l[4];
#pragma unroll
    for (int e=0;e<4;e++){
        int k = kq + e;
        int c = k / 25, rem = k - c*25, r = rem / 5, jj = rem - r*5;
        float v = x[(size_t)c*230400 + (size_t)(pi*5+r)*480 + pj*5 + jj];
        u16 hb = f2bu(v);
        h[e] = hb;
        l[e] = f2bu(v - b2f(hb));
    }
    *(ushort4*)&xh[(size_t)n*6400 + kq] = *(ushort4*)h;
    *(ushort4*)&xl[(size_t)n*6400 + kq] = *(ushort4*)l;
}

// sum 4 K-split partials + bias + relu -> emb1 rows (one half = 294912 float4)
__global__ void conv_reduce2(const float* __restrict__ p, const float* __restrict__ bias,
                             float* __restrict__ o)
{
    int i = blockIdx.x * 256 + threadIdx.x;
    const float4* p4 = (const float4*)p;
    float4 s = p4[i];
#pragma unroll
    for (int j=1;j<4;j++){
        float4 v = p4[i + (size_t)j*294912];
        s.x += v.x; s.y += v.y; s.z += v.z; s.w += v.w;
    }
    float4 bb = ((const float4*)bias)[i & 63];
    float4 r;
    r.x = fmaxf(s.x+bb.x, 0.f);
    r.y = fmaxf(s.y+bb.y, 0.f);
    r.z = fmaxf(s.z+bb.z, 0.f);
    r.w = fmaxf(s.w+bb.w, 0.f);
    ((float4*)o)[i] = r;
}

// ---------------- generic fp32 GEMM (fc2, fc3) -------------------------------------
template<int ACT>
__global__ __launch_bounds__(256)
void gemm_f32(const float* __restrict__ A1, int ldA1, int K1,
              const float* __restrict__ A2, int ldA2,
              const float* __restrict__ B, const float* __restrict__ bias,
              const float* __restrict__ add,
              float* __restrict__ C, int M, int N, int K)
{
    __shared__ __align__(16) float As[16][128];
    __shared__ __align__(16) float Bs[16][64];
    const int mb = blockIdx.x * 128, nb = blockIdx.y * 64;
    const int tid = threadIdx.x;
    const int tn = tid & 15, tm = tid >> 4;
    float acc[8][4];
#pragma unroll
    for (int i=0;i<8;i++){
#pragma unroll
        for (int j=0;j<4;j++) acc[i][j]=0.f;
    }
    const int am = tid >> 2;
    const int ak = (tid & 3) * 4;
    const int bk = tid >> 4;
    const int bn = (tid & 15) * 4;

    for (int k0 = 0; k0 < K; k0 += 16) {
        int kg = k0 + ak;
#pragma unroll
        for (int half = 0; half < 2; ++half) {
            int ml = am + half*64;
            int m = mb + ml;
            float4 v;
            if (kg < K1) v = *(const float4*)(A1 + (size_t)m*ldA1 + kg);
            else         v = *(const float4*)(A2 + (size_t)m*ldA2 + (kg - K1));
            As[ak+0][ml] = v.x; As[ak+1][ml] = v.y; As[ak+2][ml] = v.z; As[ak+3][ml] = v.w;
        }
        {
            float4 v = *(const float4*)(B + (size_t)(k0+bk)*N + nb + bn);
            *(float4*)&Bs[bk][bn] = v;
        }
        __syncthreads();
#pragma unroll
        for (int kk=0;kk<16;kk++){
            float a[8], b[4];
            *(float4*)&a[0] = *(const float4*)&As[kk][tm*8];
            *(float4*)&a[4] = *(const float4*)&As[kk][tm*8+4];
            *(float4*)&b[0] = *(const float4*)&Bs[kk][tn*4];
#pragma unroll
            for (int i=0;i<8;i++){
#pragma unroll
                for (int j=0;j<4;j++) acc[i][j] += a[i]*b[j];
            }
        }
        __syncthreads();
    }
#pragma unroll
    for (int i=0;i<8;i++){
        int m = mb + tm*8 + i;
        float ov[4];
#pragma unroll
        for (int j=0;j<4;j++){
            int n = nb + tn*4 + j;
            float v = acc[i][j] + bias[n];
            if (ACT == 1) v = v > 0.f ? v : 0.f;
            if (add) v += add[(size_t)m*N + n];
            ov[j] = v;
        }
        *(float4*)(C + (size_t)m*N + nb + tn*4) = *(float4*)ov;
    }
}

// fp32 [K][N] row-major -> bf16 out[N][K]
__global__ __launch_bounds__(256)
void transpose_cvt(const float* __restrict__ in, int K, int N, u16* __restrict__ out)
{
    __shared__ float t[32][33];
    const int kb = blockIdx.x * 32, nb = blockIdx.y * 32;
    const int tx = threadIdx.x & 31, ty = threadIdx.x >> 5;   // 32 x 8
#pragma unroll
    for (int r=0;r<4;r++)
        t[ty + r*8][tx] = in[(size_t)(kb + ty + r*8)*N + nb + tx];
    __syncthreads();
#pragma unroll
    for (int r=0;r<4;r++)
        out[(size_t)(nb + ty + r*8)*K + kb + tx] = f2bu(t[tx][ty + r*8]);
}

// ---------------- bf16 MFMA NT GEMM core: C[M][N] = A[M][K] @ B[N][K]^T ------------
// 128x128 tile, BK=32, 256 thr (4 waves as 2x2 of 64x64); global_load_lds staging
// into linear LDS [128][32]. SPLIT: (hi,lo) 3-term. EPI 0: bf16 store via LDS-bounce
// coalesced uint4. EPI 1: swapped-operand top-3 candidates, written as packed u64
// keys (R16). EPI 2: conv K-split f32 partials via LDS-bounce float4.
template<bool SPLIT, int EPI>
__device__ __forceinline__
void mm_core(const u16* __restrict__ Ah, const u16* __restrict__ Al, int lda,
             const u16* __restrict__ Bh, const u16* __restrict__ Bl, int ldb,
             const float* __restrict__ bias0, const float* __restrict__ bias1, int nHalf,
             void* __restrict__ Cout, int ldc, int K,
             u64* __restrict__ apk)
{
    constexpr int TSZ = 128 * 32;
    __shared__ u16 smem[(SPLIT ? 4 : 2) * TSZ];
    u16* AsH = smem;
    u16* BsH = smem + TSZ;
    u16* AsL = SPLIT ? smem + 2*TSZ : nullptr;
    u16* BsL = SPLIT ? smem + 3*TSZ : nullptr;

    const int tid = threadIdx.x;
    const int w = tid >> 6, ln = tid & 63;
    const int wr = w >> 1, wc = w & 1;
    const int fr = ln & 15, fq = ln >> 4;
    const int mb = blockIdx.x * 128, nb = blockIdx.y * 128;
    const int skk = (ln & 3) * 8;        // staging: k element offset
    const int srow = ln >> 2;            // staging: row within 16-row group

    int kbeg = 0;
    if constexpr (EPI == 2) kbeg = blockIdx.z * K;
    const int kend = kbeg + K;

    f32x4 acc[4][4];
#pragma unroll
    for (int i=0;i<4;i++)
#pragma unroll
        for (int j=0;j<4;j++) acc[i][j] = (f32x4){0.f,0.f,0.f,0.f};

    for (int k0 = kbeg; k0 < kend; k0 += 32) {
#pragma unroll
        for (int t=0;t<2;t++){
            int rbase = w*32 + t*16;
            int r = rbase + srow;
            size_t goA = (size_t)(mb + r)*lda + k0 + skk;
            size_t goB = (size_t)(nb + r)*ldb + k0 + skk;
            gload16(Ah + goA, AsH + rbase*32);
            gload16(Bh + goB, BsH + rbase*32);
            if constexpr (SPLIT){
                gload16(Al + goA, AsL + rbase*32);
                gload16(Bl + goB, BsL + rbase*32);
            }
        }
        __syncthreads();
        s16x8 ah[4], bh[4], al[4], bl[4];
#pragma unroll
        for (int mi=0;mi<4;mi++){
            int ro = (wr*64 + mi*16 + fr)*32 + fq*8;
            ah[mi] = *(const s16x8*)&AsH[ro];
            if constexpr (SPLIT) al[mi] = *(const s16x8*)&AsL[ro];
        }
#pragma unroll
        for (int nj=0;nj<4;nj++){
            int ro = (wc*64 + nj*16 + fr)*32 + fq*8;
            bh[nj] = *(const s16x8*)&BsH[ro];
            if constexpr (SPLIT) bl[nj] = *(const s16x8*)&BsL[ro];
        }
#pragma unroll
        for (int mi=0;mi<4;mi++)
#pragma unroll
            for (int nj=0;nj<4;nj++){
                acc[mi][nj] = mfma_bf16(ah[mi], bh[nj], acc[mi][nj]);
                if constexpr (SPLIT){
                    acc[mi][nj] = mfma_bf16(ah[mi], bl[nj], acc[mi][nj]);
                    acc[mi][nj] = mfma_bf16(al[mi], bh[nj], acc[mi][nj]);
                }
            }
        __syncthreads();
    }

    if constexpr (EPI == 0) {
        u16* ldsc = smem;
#pragma unroll
        for (int chunk=0; chunk<4; ++chunk){
            __syncthreads();
            if (wr == (chunk>>1)){
                int mi0 = (chunk&1)*2;
#pragma unroll
                for (int m2=0;m2<2;m2++){
                    int mi = mi0 + m2;
#pragma unroll
                    for (int nj=0;nj<4;nj++)
#pragma unroll
                    for (int t=0;t<4;t++){
                        int lr = m2*16 + fq*4 + t;
                        int lc = wc*64 + nj*16 + fr;
                        int col = nb + lc;
                        float v = acc[mi][nj][t];
                        if (bias0) v += (col < nHalf) ? bias0[col] : bias1[col - nHalf];
                        ldsc[lr*136 + lc] = f2bu(v);
                    }
                }
            }
            __syncthreads();
            int c0 = chunk*32;
#pragma unroll
            for (int q=0;q<2;q++){
                int e = q*256 + tid;
                int lr = e >> 4, c16 = e & 15;
                *(uint4*)((u16*)Cout + (size_t)(mb + c0 + lr)*ldc + nb + c16*8)
                    = *(const uint4*)&ldsc[lr*136 + c16*8];
            }
        }
    } else if constexpr (EPI == 2) {
        float* ldsf = (float*)smem;
#pragma unroll
        for (int chunk=0; chunk<8; ++chunk){
            __syncthreads();
            if (wr == (chunk>>2)){
                int mi = chunk & 3;
#pragma unroll
                for (int nj=0;nj<4;nj++)
#pragma unroll
                for (int t=0;t<4;t++){
                    int lr = fq*4 + t;
                    int lc = wc*64 + nj*16 + fr;
                    ldsf[lr*132 + lc] = acc[mi][nj][t];
                }
            }
            __syncthreads();
            int c0 = chunk*16;
#pragma unroll
            for (int q=0;q<2;q++){
                int e = q*256 + tid;
                int lr = e >> 5, c4 = e & 31;
                *(float4*)((float*)Cout + ((size_t)blockIdx.z*4608 + mb + c0 + lr)*256 + nb + c4*4)
                    = *(const float4*)&ldsf[lr*132 + c4*4];
            }
        }
    } else {
        // swapped-selection: adj row = B-side (nb + wc*64 + nj*16 + fr); c = A-side.
        const int cbR = blockIdx.x * 2 + wr;
#pragma unroll
        for (int nj=0;nj<4;nj++){
            int row = nb + wc*64 + nj*16 + fr;
            float tv[3] = {NEG_INF, NEG_INF, NEG_INF};
            int   ti[3] = {0x7fffffff, 0x7fffffff, 0x7fffffff};
#pragma unroll
            for (int mi=0;mi<4;mi++)
#pragma unroll
                for (int t=0;t<4;t++)
                    tk_insert(acc[mi][nj][t], mb + wr*64 + mi*16 + fq*4 + t, tv, ti);
#pragma unroll
            for (int off=16; off<64; off<<=1){
                float ov[3]; int oi[3];
#pragma unroll
                for (int e=0;e<3;e++){ ov[e]=__shfl_xor(tv[e],off); oi[e]=__shfl_xor(ti[e],off); }
#pragma unroll
                for (int e=0;e<3;e++) tk_insert(ov[e], oi[e], tv, ti);
            }
            if (fq == 0){
#pragma unroll
                for (int e=0;e<3;e++)
                    apk[(size_t)row*432 + cbR*3 + e] = mkkey(tv[e], ti[e]);
            }
        }
    }
}

// named instantiations (distinct rocprof rows)
__global__ __launch_bounds__(256)
void mm_proj(const u16* Ah, int lda, const u16* Bh, int ldb,
             const float* bias0, const float* bias1, int nHalf,
             void* Cout, int ldc, int K)
{
    mm_core<false,0>(Ah, nullptr, lda, Bh, nullptr, ldb, bias0, bias1, nHalf,
                     Cout, ldc, K, nullptr);
}
__global__ __launch_bounds__(256)
void mm_adj(const u16* Ah, int lda, u64* apk)
{
    mm_core<false,1>(Ah, nullptr, lda, Ah, nullptr, lda, nullptr, nullptr, 0,
                     nullptr, 0, 256, apk);
}
__global__ __launch_bounds__(256)
void mm_conv(const u16* Ah, const u16* Al, int lda, const u16* Bh, const u16* Bl, int ldb,
             float* Cout, int K)
{
    mm_core<true,2>(Ah, Al, lda, Bh, Bl, ldb, nullptr, nullptr, 0,
                    Cout, 256, K, nullptr);
}

// R16 merge: 432 packed keys per row -> top-8, ONE WAVE PER ROW.
// Lane sorts its <=7 keys desc (16-CE network; pad 0 never wins), then 8 rounds of
// head-pop wave-max (u64 shfl butterfly). Key order == (val desc, idx asc): identical
// selection to the insertion-sort version.
__device__ __forceinline__ void ce_desc(u64& a, u64& b){
    u64 mx = a > b ? a : b; u64 mn = a > b ? b : a; a = mx; b = mn;
}
__global__ __launch_bounds__(256)
void adj_merge8(const u64* __restrict__ apk, int* __restrict__ c8i)
{
    int row = blockIdx.x * 4 + (threadIdx.x >> 6);
    int ln = threadIdx.x & 63;
    u64 k[7];
#pragma unroll
    for (int j=0;j<7;j++){
        int t = ln + 64*j;
        k[j] = (t < 432) ? apk[(size_t)row*432 + t] : 0ull;
    }
    // optimal 7-element sorting network (16 CEs), descending
    ce_desc(k[0],k[6]); ce_desc(k[2],k[3]); ce_desc(k[4],k[5]);
    ce_desc(k[0],k[2]); ce_desc(k[1],k[4]); ce_desc(k[3],k[6]);
    ce_desc(k[0],k[1]); ce_desc(k[2],k[5]); ce_desc(k[3],k[4]);
    ce_desc(k[1],k[2]); ce_desc(k[4],k[6]);
    ce_desc(k[2],k[3]); ce_desc(k[4],k[5]);
    ce_desc(k[1],k[2]); ce_desc(k[3],k[4]); ce_desc(k[5],k[6]);
#pragma unroll
    for (int r=0;r<8;r++){
        u64 m = k[0];
#pragma unroll
        for (int off=1; off<64; off<<=1){
            u64 o = __shfl_xor((unsigned long long)m, off);
            m = o > m ? o : m;
        }
        if (k[0] == m){               // unique keys -> exactly one winner pops
            k[0]=k[1]; k[1]=k[2]; k[2]=k[3]; k[3]=k[4]; k[4]=k[5]; k[5]=k[6]; k[6]=0ull;
        }
        if (ln == 0) c8i[row*8 + r] = (int)(~(u32)(m & 0xFFFFFFFFull));
    }
}

// exact fp32 rescore of 8 candidates per row, final top-3 (lax.top_k semantics).
__global__ __launch_bounds__(256)
void rescore_select(const float* __restrict__ emb, const int* __restrict__ c8i,
                    float* __restrict__ vals, int* __restrict__ idx)
{
    int gid = blockIdx.x * 256 + threadIdx.x;
    int row = gid >> 6;
    int ln = threadIdx.x & 63;
    float a[4];
    *(float4*)a = *(const float4*)(emb + (size_t)row*256 + ln*4);
    float sc[8];
#pragma unroll
    for (int c=0;c<8;c++){
        int cand = c8i[row*8+c];
        float4 b = *(const float4*)(emb + (size_t)cand*256 + ln*4);
        float p = a[0]*b.x + a[1]*b.y + a[2]*b.z + a[3]*b.w;
#pragma unroll
        for (int off=1; off<64; off<<=1) p += __shfl_xor(p, off);
        sc[c] = p;
    }
    if (ln == 0){
        float tv[3]={NEG_INF,NEG_INF,NEG_INF};
        int   ti[3]={0x7fffffff,0x7fffffff,0x7fffffff};
#pragma unroll
        for (int c=0;c<8;c++) tk_insert(sc[c], c8i[row*8+c], tv, ti);
#pragma unroll
        for (int e=0;e<3;e++){ vals[row*3+e]=tv[e]; idx[row*3+e]=ti[e]; }
    }
}

// ---------------- GATv2 softmax + aggregate + bias + ELU, bf16 inputs --------------
template<int H, int TPH, bool SPATIAL, bool OUTBF>
__global__ __launch_bounds__(H*TPH)
void gat_agg(const u16* __restrict__ xlxr, int ldx, int xrOff,
             const float* __restrict__ att, const float* __restrict__ bias,
             const float* __restrict__ vals, const int* __restrict__ idx,
             void* __restrict__ outp, int ldo)
{
    constexpr int D = 256;
    constexpr int DPT = D / TPH;
    const int n = blockIdx.x;
    const int tid = threadIdx.x;
    const int h = tid / TPH;
    const int l = tid % TPH;
    const int d0 = l * DPT;

    int srcs[4]; bool valid[4];
#pragma unroll
    for (int s=0;s<4;s++){ srcs[s]=n; valid[s]=(s==3); }
    if constexpr (SPATIAL) {
        int pi = n / 96, pj = n - (n/96)*96;
        int cand[4]; int nc=0;
        if (pi > 0)  cand[nc++] = n - 96;
        if (pj > 0)  cand[nc++] = n - 1;
        if (pj < 95) cand[nc++] = n + 1;
        if (pi < 95) cand[nc++] = n + 96;
        int s0 = cand[0], s1 = cand[1];
        if (s0 > n){ srcs[0]=s0; valid[0]=true; }
        if (s1 > n){ srcs[1]=s1; valid[1]=true; }
    } else {
#pragma unroll
        for (int t=0;t<3;t++){
            int s = idx[n*3+t];
            float v = vals[n*3+t];
            if (s > n && v != 0.0f){ srcs[t]=s; valid[t]=true; }
        }
    }

    float xrv[DPT], attv[DPT];
#pragma unroll
    for (int q=0;q<DPT/4;q++){
        ushort4 u = *(const ushort4*)(xlxr + (size_t)n*ldx + xrOff + h*D + d0 + q*4);
        xrv[q*4+0]=b2f(u.x); xrv[q*4+1]=b2f(u.y); xrv[q*4+2]=b2f(u.z); xrv[q*4+3]=b2f(u.w);
        *(float4*)&attv[q*4] = *(const float4*)(att + h*D + d0 + q*4);
    }

    float xs[4][DPT];
    float sc[4];
#pragma unroll
    for (int s=0;s<4;s++){
#pragma unroll
        for (int q=0;q<DPT/4;q++){
            ushort4 u = *(const ushort4*)(xlxr + (size_t)srcs[s]*ldx + h*D + d0 + q*4);
            xs[s][q*4+0]=b2f(u.x); xs[s][q*4+1]=b2f(u.y); xs[s][q*4+2]=b2f(u.z); xs[s][q*4+3]=b2f(u.w);
        }
        float p = 0.f;
#pragma unroll
        for (int d=0;d<DPT;d++){
            float e = xs[s][d] + xrv[d];
            e = (e > 0.f) ? e : 0.2f*e;
            p += attv[d]*e;
        }
#pragma unroll
        for (int off=1; off<TPH; off<<=1) p += __shfl_xor(p, off);
        sc[s] = p;
    }
    float m = NEG_INF;
#pragma unroll
    for (int s=0;s<4;s++) if (valid[s]) m = fmaxf(m, sc[s]);
    float al[4]; float denom = 0.f;
#pragma unroll
    for (int s=0;s<4;s++){ al[s] = valid[s] ? expf(sc[s]-m) : 0.f; denom += al[s]; }
    float inv = 1.f / denom;

    float o[DPT];
#pragma unroll
    for (int d=0;d<DPT;d++){
        float acc = al[0]*xs[0][d] + al[1]*xs[1][d] + al[2]*xs[2][d] + al[3]*xs[3][d];
        acc = acc*inv + bias[h*D + d0 + d];
        o[d] = (acc > 0.f) ? acc : (expf(acc) - 1.f);
    }
    if constexpr (OUTBF) {
        u16 ov[DPT];
#pragma unroll
        for (int d=0;d<DPT;d++) ov[d] = f2bu(o[d]);
#pragma unroll
        for (int q=0;q<DPT/8;q++)
            *(uint4*)((u16*)outp + (size_t)n*ldo + h*D + d0 + q*8) = *(uint4*)&ov[q*8];
        if constexpr (DPT < 8)
            *(uint2*)((u16*)outp + (size_t)n*ldo + h*D + d0) = *(uint2*)ov;
    } else {
#pragma unroll
        for (int q=0;q<DPT/4;q++)
            *(float4*)((float*)outp + (size_t)n*ldo + h*D + d0 + q*4) = *(float4*)&o[q*4];
    }
}

// ---------------------------------------------------------------------------
extern "C" void kernel_launch(void* const* d_in, const int* in_sizes, int n_in,
                              void* d_out, int out_size, void* d_ws, size_t ws_size,
                              hipStream_t stream)
{
    (void)in_sizes; (void)n_in;
    const float* x      = (const float*)d_in[0];
    const float* conv_w = (const float*)d_in[1];
    const float* conv_b = (const float*)d_in[2];
    const float* fc2_w  = (const float*)d_in[3];
    const float* fc2_b  = (const float*)d_in[4];
    const float* fc3_w  = (const float*)d_in[5];
    const float* fc3_b  = (const float*)d_in[6];
    const float* g_wl[4]   = {(const float*)d_in[7],  (const float*)d_in[13], (const float*)d_in[19], (const float*)d_in[25]};
    const float* g_bl[4]   = {(const float*)d_in[8],  (const float*)d_in[14], (const float*)d_in[20], (const float*)d_in[26]};
    const float* g_wr[4]   = {(const float*)d_in[9],  (const float*)d_in[15], (const float*)d_in[21], (const float*)d_in[27]};
    const float* g_br[4]   = {(const float*)d_in[10], (const float*)d_in[16], (const float*)d_in[22], (const float*)d_in[28]};
    const float* g_att[4]  = {(const float*)d_in[11], (const float*)d_in[17], (const float*)d_in[23], (const float*)d_in[29]};
    const float* g_bias[4] = {(const float*)d_in[12], (const float*)d_in[18], (const float*)d_in[24], (const float*)d_in[30]};

    float* ws = (float*)d_ws;
    size_t off = 0;
    float* emb1  = ws + off; off += 2359296;                  // [9216][256] f32 (persists)
    size_t emb_off = off;
    float* emb   = ws + off; off += 2359296;
    u16*   emb_h = (u16*)(ws + off); off += 1179648;          // [9216][256] bf16
    u16*   emb_l = (u16*)(ws + off); off += 1179648;
    u16*   Wt[4];
    Wt[0] = (u16*)(ws + off); off += 524288;                  // [4096][256] bf16
    Wt[1] = (u16*)(ws + off); off += 524288;                  // [512][2048] bf16
    Wt[2] = (u16*)(ws + off); off += 524288;
    Wt[3] = (u16*)(ws + off); off += 524288;
    u64*   apk  = (u64*)(ws + off); off += 7962624;           // [9216][432] u64 keys
    int*   c8i  = (int*)(ws + off); off += 73728;             // [9216][8]
    float* vals = ws + off; off += 27648;
    int*   idx  = (int*)(ws + off); off += 27648;
    float* h2   = ws + off; off += 2359296;
    float* h4   = ws + off; off += 2359296;
    u16*   xlxr = (u16*)(ws + off); off += 18874368;          // [9216][4096] u16
    u16*   hbig = (u16*)(ws + off); off += 9437184;           // [9216][2048] u16
    u16*   WbH  = (u16*)(ws + off); off += 851968;            // [256][6400] bf16 (conv W split)
    u16*   WbL  = (u16*)(ws + off); off += 851968;
    // conv-phase scratch, aliased onto post-conv region starting at emb
    u16*   xp_h = (u16*)(ws + emb_off);                          // [4608][6400] u16
    u16*   xp_l = (u16*)(ws + emb_off + 14745600);
    float* cpart = ws + emb_off + 29491200;                      // [4][4608][256] f32
    size_t need = off * sizeof(float);
    if (ws_size < need) {
        hipMemsetAsync(d_out, 0, (size_t)out_size*sizeof(float), stream);
        return;
    }
    float* out = (float*)d_out;

    // conv1 = bf16-split-3-term NT GEMM over im2col'd x (two row-halves, K-split x4).
    cvt_hilo<<<1600,256,0,stream>>>(conv_w, WbH, WbL, 409600);
    for (int half = 0; half < 2; ++half) {
        xpb_build<<<28800,256,0,stream>>>(x, half*4608, xp_h, xp_l);
        mm_conv<<<dim3(36,2,4),256,0,stream>>>(xp_h, xp_l, 6400, WbH, WbL, 6400, cpart, 1600);
        conv_reduce2<<<1152,256,0,stream>>>(cpart, conv_b, emb1 + (size_t)half*4608*256);
    }
    // fc2 fp32 -> emb (exact; feeds graph + rescore)
    gemm_f32<1><<<dim3(72,4),256,0,stream>>>(emb1,256,256, emb1,256, fc2_w, fc2_b, nullptr, emb, 9216,256,256);

    // conversions: emb -> hi/lo ; weights -> transposed bf16 (wl rows 0..N-1, wr rows N..2N-1)
    cvt_hilo<<<2304,256,0,stream>>>(emb, emb_h, emb_l, 589824);
    transpose_cvt<<<dim3(8,64),256,0,stream>>>(g_wl[0], 256, 2048, Wt[0]);
    transpose_cvt<<<dim3(8,64),256,0,stream>>>(g_wr[0], 256, 2048, Wt[0] + (size_t)2048*256);
    transpose_cvt<<<dim3(64,8),256,0,stream>>>(g_wl[1], 2048, 256, Wt[1]);
    transpose_cvt<<<dim3(64,8),256,0,stream>>>(g_wr[1], 2048, 256, Wt[1] + (size_t)256*2048);
    transpose_cvt<<<dim3(8,64),256,0,stream>>>(g_wl[2], 256, 2048, Wt[2]);
    transpose_cvt<<<dim3(8,64),256,0,stream>>>(g_wr[2], 256, 2048, Wt[2] + (size_t)2048*256);
    transpose_cvt<<<dim3(64,8),256,0,stream>>>(g_wl[3], 2048, 256, Wt[3]);
    transpose_cvt<<<dim3(64,8),256,0,stream>>>(g_wr[3], 2048, 256, Wt[3] + (size_t)256*2048);

    // similarity kNN: 1-term bf16 candidates (swapped-operand selection, packed keys)
    // -> packed-key wave-max merge -> exact fp32 rescore -> top-3.
    mm_adj<<<dim3(72,72),256,0,stream>>>(emb_h, 256, apk);
    adj_merge8<<<2304,256,0,stream>>>(apk, c8i);
    rescore_select<<<2304,256,0,stream>>>(emb, c8i, vals, idx);

    // g1 (H=8, similarity graph)
    mm_proj<<<dim3(72,32),256,0,stream>>>(emb_h, 256, Wt[0], 256, g_bl[0], g_br[0], 2048,
                                          xlxr, 4096, 256);
    gat_agg<8,32,false,true><<<9216,256,0,stream>>>(xlxr, 4096, 2048, g_att[0], g_bias[0], vals, idx, hbig, 2048);
    // g2 (H=1)
    mm_proj<<<dim3(72,4),256,0,stream>>>(hbig, 2048, Wt[1], 2048, g_bl[1], g_br[1], 256,
                                         xlxr, 512, 2048);
    gat_agg<1,64,false,false><<<9216,64,0,stream>>>(xlxr, 512, 256, g_att[1], g_bias[1], vals, idx, h2, 256);
    // g3 (H=8, spatial graph)
    mm_proj<<<dim3(72,32),256,0,stream>>>(emb_h, 256, Wt[2], 256, g_bl[2], g_br[2], 2048,
                                          xlxr, 4096, 256);
    gat_agg<8,32,true,true><<<9216,256,0,stream>>>(xlxr, 4096, 2048, g_att[2], g_bias[2], nullptr, nullptr, hbig, 2048);
    // g4 (H=1)
    mm_proj<<<dim3(72,4),256,0,stream>>>(hbig, 2048, Wt[3], 2048, g_bl[3], g_br[3], 256,
                                         xlxr, 512, 2048);
    gat_agg<1,64,true,false><<<9216,64,0,stream>>>(xlxr, 512, 256, g_att[3], g_bias[3], nullptr, nullptr, h4, 256);

    // fc3 on concat(h2,h4) + relu + residual(h4) -> out
    gemm_f32<1><<<dim3(72,4),256,0,stream>>>(h2,256,256, h4,256, fc3_w, fc3_b, h4, out, 9216,256,512);
}

// Round 17
// 862.178 us; speedup vs baseline: 1.4379x; 1.1684x over previous
//
#include <hip/hip_runtime.h>
#include <cstdint>
#include <cstddef>

#define NEG_INF (-3.402823466e38f)
typedef unsigned short u16;
typedef unsigned int u32;
typedef unsigned long long u64;

typedef short s16x8 __attribute__((ext_vector_type(8)));
typedef __bf16 bf16x8_t __attribute__((ext_vector_type(8)));
typedef float f32x4 __attribute__((ext_vector_type(4)));

__device__ __forceinline__ f32x4 mfma_bf16(s16x8 a, s16x8 b, f32x4 c){
    return __builtin_amdgcn_mfma_f32_16x16x32_bf16(
        __builtin_bit_cast(bf16x8_t, a), __builtin_bit_cast(bf16x8_t, b), c, 0, 0, 0);
}
__device__ __forceinline__ float b2f(u16 u){ return __uint_as_float(((u32)u) << 16); }
__device__ __forceinline__ u16 f2bu(float f){           // RNE fp32 -> bf16 bits
    u32 u = __float_as_uint(f);
    return (u16)((u + 0x7fffu + ((u >> 16) & 1u)) >> 16);
}
// async global->LDS, 16B/lane; LDS dest = wave-uniform base + lane*16 (m97 pattern)
__device__ __forceinline__ void gload16(const u16* __restrict__ g, u16* l){
    __builtin_amdgcn_global_load_lds(
        (const __attribute__((address_space(1))) u32*)g,
        (__attribute__((address_space(3))) u32*)l, 16, 0, 0);
}
// monotone (val desc, idx asc) <-> u64 key desc ; keys unique (idx unique), > 0
__device__ __forceinline__ u64 mkkey(float v, int id){
    u32 s = __float_as_uint(v);
    s ^= (u32)(((int)s >> 31)) | 0x80000000u;
    return ((u64)s << 32) | (u32)(~(u32)id);
}

// ---------------- top-k helpers (JAX lax.top_k stable: val desc, idx asc on ties) ----
__device__ __forceinline__ bool tk_gt(float v, int i, float w, int j){
    return (v > w) || (v == w && i < j);
}
__device__ __forceinline__ void tk_insert(float v, int id, float tv[3], int ti[3]){
    if (!tk_gt(v, id, tv[2], ti[2])) return;
    if (tk_gt(v, id, tv[1], ti[1])) {
        tv[2]=tv[1]; ti[2]=ti[1];
        if (tk_gt(v, id, tv[0], ti[0])) { tv[1]=tv[0]; ti[1]=ti[0]; tv[0]=v; ti[0]=id; }
        else { tv[1]=v; ti[1]=id; }
    } else { tv[2]=v; ti[2]=id; }
}

// ---------------- conversion pre-passes --------------------------------------------
__global__ void cvt_hilo(const float* __restrict__ in, u16* __restrict__ hi,
                         u16* __restrict__ lo, int n4)
{
    int i = blockIdx.x * 256 + threadIdx.x;
    if (i >= n4) return;
    float4 v = ((const float4*)in)[i];
    u16 h[4], l[4];
    float f[4] = {v.x, v.y, v.z, v.w};
#pragma unroll
    for (int j=0;j<4;j++){
        u16 hb = f2bu(f[j]);
        h[j] = hb;
        l[j] = f2bu(f[j] - b2f(hb));
    }
    *(ushort4*)&hi[i*4] = *(ushort4*)h;
    *(ushort4*)&lo[i*4] = *(ushort4*)l;
}

// R17: im2col + bf16-split, READ-COALESCED. One block per (channel c, patch-row pi):
// load x[c][pi*5..+5][0..480) as 600 aligned float4 (each x element fetched once),
// convert, scatter to LDS [96 pj][26 pad], then write 96 rows x 25 u16 contiguous.
__global__ __launch_bounds__(256)
void xpb_build(const float* __restrict__ x, int base,
               u16* __restrict__ xh, u16* __restrict__ xl)
{
    __shared__ u16 lh[96*26], ll[96*26];
    const int c = blockIdx.x / 48;
    const int piL = blockIdx.x - c*48;               // 0..47 within this half
    const int pi = (base/96) + piL;                  // global patch-row
    const int tid = threadIdx.x;

    for (int e = tid; e < 600; e += 256){            // r = e/120, col4 = e%120
        int r = e / 120, col4 = e - r*120;
        float4 v = *(const float4*)(x + (size_t)c*230400 + (size_t)(pi*5+r)*480 + col4*4);
        float f[4] = {v.x, v.y, v.z, v.w};
#pragma unroll
        for (int j=0;j<4;j++){
            int col = col4*4 + j;
            int pj = col / 5, jj = col - pj*5;
            u16 hb = f2bu(f[j]);
            int lo = pj*26 + r*5 + jj;
            lh[lo] = hb;
            ll[lo] = f2bu(f[j] - b2f(hb));
        }
    }
    __syncthreads();
    for (int e = tid; e < 2400; e += 256){           // nrow = e/25, kk = e%25
        int pj = e / 25, kk = e - pj*25;
        size_t go = (size_t)(piL*96 + pj)*6400 + c*25 + kk;
        xh[go] = lh[pj*26 + kk];
        xl[go] = ll[pj*26 + kk];
    }
}

// sum 4 K-split partials + bias + relu -> emb1 rows (one half = 294912 float4)
__global__ void conv_reduce2(const float* __restrict__ p, const float* __restrict__ bias,
                             float* __restrict__ o)
{
    int i = blockIdx.x * 256 + threadIdx.x;
    const float4* p4 = (const float4*)p;
    float4 s = p4[i];
#pragma unroll
    for (int j=1;j<4;j++){
        float4 v = p4[i + (size_t)j*294912];
        s.x += v.x; s.y += v.y; s.z += v.z; s.w += v.w;
    }
    float4 bb = ((const float4*)bias)[i & 63];
    float4 r;
    r.x = fmaxf(s.x+bb.x, 0.f);
    r.y = fmaxf(s.y+bb.y, 0.f);
    r.z = fmaxf(s.z+bb.z, 0.f);
    r.w = fmaxf(s.w+bb.w, 0.f);
    ((float4*)o)[i] = r;
}

// ---------------- generic fp32 GEMM (fc2, fc3) -------------------------------------
template<int ACT>
__global__ __launch_bounds__(256)
void gemm_f32(const float* __restrict__ A1, int ldA1, int K1,
              const float* __restrict__ A2, int ldA2,
              const float* __restrict__ B, const float* __restrict__ bias,
              const float* __restrict__ add,
              float* __restrict__ C, int M, int N, int K)
{
    __shared__ __align__(16) float As[16][128];
    __shared__ __align__(16) float Bs[16][64];
    const int mb = blockIdx.x * 128, nb = blockIdx.y * 64;
    const int tid = threadIdx.x;
    const int tn = tid & 15, tm = tid >> 4;
    float acc[8][4];
#pragma unroll
    for (int i=0;i<8;i++){
#pragma unroll
        for (int j=0;j<4;j++) acc[i][j]=0.f;
    }
    const int am = tid >> 2;
    const int ak = (tid & 3) * 4;
    const int bk = tid >> 4;
    const int bn = (tid & 15) * 4;

    for (int k0 = 0; k0 < K; k0 += 16) {
        int kg = k0 + ak;
#pragma unroll
        for (int half = 0; half < 2; ++half) {
            int ml = am + half*64;
            int m = mb + ml;
            float4 v;
            if (kg < K1) v = *(const float4*)(A1 + (size_t)m*ldA1 + kg);
            else         v = *(const float4*)(A2 + (size_t)m*ldA2 + (kg - K1));
            As[ak+0][ml] = v.x; As[ak+1][ml] = v.y; As[ak+2][ml] = v.z; As[ak+3][ml] = v.w;
        }
        {
            float4 v = *(const float4*)(B + (size_t)(k0+bk)*N + nb + bn);
            *(float4*)&Bs[bk][bn] = v;
        }
        __syncthreads();
#pragma unroll
        for (int kk=0;kk<16;kk++){
            float a[8], b[4];
            *(float4*)&a[0] = *(const float4*)&As[kk][tm*8];
            *(float4*)&a[4] = *(const float4*)&As[kk][tm*8+4];
            *(float4*)&b[0] = *(const float4*)&Bs[kk][tn*4];
#pragma unroll
            for (int i=0;i<8;i++){
#pragma unroll
                for (int j=0;j<4;j++) acc[i][j] += a[i]*b[j];
            }
        }
        __syncthreads();
    }
#pragma unroll
    for (int i=0;i<8;i++){
        int m = mb + tm*8 + i;
        float ov[4];
#pragma unroll
        for (int j=0;j<4;j++){
            int n = nb + tn*4 + j;
            float v = acc[i][j] + bias[n];
            if (ACT == 1) v = v > 0.f ? v : 0.f;
            if (add) v += add[(size_t)m*N + n];
            ov[j] = v;
        }
        *(float4*)(C + (size_t)m*N + nb + tn*4) = *(float4*)ov;
    }
}

// fp32 [K][N] row-major -> bf16 out[N][K]
__global__ __launch_bounds__(256)
void transpose_cvt(const float* __restrict__ in, int K, int N, u16* __restrict__ out)
{
    __shared__ float t[32][33];
    const int kb = blockIdx.x * 32, nb = blockIdx.y * 32;
    const int tx = threadIdx.x & 31, ty = threadIdx.x >> 5;   // 32 x 8
#pragma unroll
    for (int r=0;r<4;r++)
        t[ty + r*8][tx] = in[(size_t)(kb + ty + r*8)*N + nb + tx];
    __syncthreads();
#pragma unroll
    for (int r=0;r<4;r++)
        out[(size_t)(nb + ty + r*8)*K + kb + tx] = f2bu(t[tx][ty + r*8]);
}

// ---------------- bf16 MFMA NT GEMM core: C[M][N] = A[M][K] @ B[N][K]^T ------------
// 128x128 tile, BK=32, 256 thr (4 waves as 2x2 of 64x64); global_load_lds staging
// into linear LDS [128][32]. SPLIT: (hi,lo) 3-term. EPI 0: bf16 store via LDS-bounce
// coalesced uint4. EPI 1: swapped-operand top-3 candidates, packed u64 keys.
// EPI 2: conv K-split f32 partials via LDS-bounce float4.
template<bool SPLIT, int EPI>
__device__ __forceinline__
void mm_core(const u16* __restrict__ Ah, const u16* __restrict__ Al, int lda,
             const u16* __restrict__ Bh, const u16* __restrict__ Bl, int ldb,
             const float* __restrict__ bias0, const float* __restrict__ bias1, int nHalf,
             void* __restrict__ Cout, int ldc, int K,
             u64* __restrict__ apk)
{
    constexpr int TSZ = 128 * 32;
    __shared__ u16 smem[(SPLIT ? 4 : 2) * TSZ];
    u16* AsH = smem;
    u16* BsH = smem + TSZ;
    u16* AsL = SPLIT ? smem + 2*TSZ : nullptr;
    u16* BsL = SPLIT ? smem + 3*TSZ : nullptr;

    const int tid = threadIdx.x;
    const int w = tid >> 6, ln = tid & 63;
    const int wr = w >> 1, wc = w & 1;
    const int fr = ln & 15, fq = ln >> 4;
    const int mb = blockIdx.x * 128, nb = blockIdx.y * 128;
    const int skk = (ln & 3) * 8;        // staging: k element offset

    int kbeg = 0;
    if constexpr (EPI == 2) kbeg = blockIdx.z * K;
    const int kend = kbeg + K;

    f32x4 acc[4][4];
#pragma unroll
    for (int i=0;i<4;i++)
#pragma unroll
        for (int j=0;j<4;j++) acc[i][j] = (f32x4){0.f,0.f,0.f,0.f};

    for (int k0 = kbeg; k0 < kend; k0 += 32) {
#pragma unroll
        for (int t=0;t<2;t++){
            int rbase = w*32 + t*16;
            int r = rbase + (ln >> 2);
            size_t goA = (size_t)(mb + r)*lda + k0 + skk;
            size_t goB = (size_t)(nb + r)*ldb + k0 + skk;
            gload16(Ah + goA, AsH + rbase*32);
            gload16(Bh + goB, BsH + rbase*32);
            if constexpr (SPLIT){
                gload16(Al + goA, AsL + rbase*32);
                gload16(Bl + goB, BsL + rbase*32);
            }
        }
        __syncthreads();
        s16x8 ah[4], bh[4], al[4], bl[4];
#pragma unroll
        for (int mi=0;mi<4;mi++){
            int ro = (wr*64 + mi*16 + fr)*32 + fq*8;
            ah[mi] = *(const s16x8*)&AsH[ro];
            if constexpr (SPLIT) al[mi] = *(const s16x8*)&AsL[ro];
        }
#pragma unroll
        for (int nj=0;nj<4;nj++){
            int ro = (wc*64 + nj*16 + fr)*32 + fq*8;
            bh[nj] = *(const s16x8*)&BsH[ro];
            if constexpr (SPLIT) bl[nj] = *(const s16x8*)&BsL[ro];
        }
#pragma unroll
        for (int mi=0;mi<4;mi++)
#pragma unroll
            for (int nj=0;nj<4;nj++){
                acc[mi][nj] = mfma_bf16(ah[mi], bh[nj], acc[mi][nj]);
                if constexpr (SPLIT){
                    acc[mi][nj] = mfma_bf16(ah[mi], bl[nj], acc[mi][nj]);
                    acc[mi][nj] = mfma_bf16(al[mi], bh[nj], acc[mi][nj]);
                }
            }
        __syncthreads();
    }

    if constexpr (EPI == 0) {
        u16* ldsc = smem;
#pragma unroll
        for (int chunk=0; chunk<4; ++chunk){
            __syncthreads();
            if (wr == (chunk>>1)){
                int mi0 = (chunk&1)*2;
#pragma unroll
                for (int m2=0;m2<2;m2++){
                    int mi = mi0 + m2;
#pragma unroll
                    for (int nj=0;nj<4;nj++)
#pragma unroll
                    for (int t=0;t<4;t++){
                        int lr = m2*16 + fq*4 + t;
                        int lc = wc*64 + nj*16 + fr;
                        int col = nb + lc;
                        float v = acc[mi][nj][t];
                        if (bias0) v += (col < nHalf) ? bias0[col] : bias1[col - nHalf];
                        ldsc[lr*136 + lc] = f2bu(v);
                    }
                }
            }
            __syncthreads();
            int c0 = chunk*32;
#pragma unroll
            for (int q=0;q<2;q++){
                int e = q*256 + tid;
                int lr = e >> 4, c16 = e & 15;
                *(uint4*)((u16*)Cout + (size_t)(mb + c0 + lr)*ldc + nb + c16*8)
                    = *(const uint4*)&ldsc[lr*136 + c16*8];
            }
        }
    } else if constexpr (EPI == 2) {
        float* ldsf = (float*)smem;
#pragma unroll
        for (int chunk=0; chunk<8; ++chunk){
            __syncthreads();
            if (wr == (chunk>>2)){
                int mi = chunk & 3;
#pragma unroll
                for (int nj=0;nj<4;nj++)
#pragma unroll
                for (int t=0;t<4;t++){
                    int lr = fq*4 + t;
                    int lc = wc*64 + nj*16 + fr;
                    ldsf[lr*132 + lc] = acc[mi][nj][t];
                }
            }
            __syncthreads();
            int c0 = chunk*16;
#pragma unroll
            for (int q=0;q<2;q++){
                int e = q*256 + tid;
                int lr = e >> 5, c4 = e & 31;
                *(float4*)((float*)Cout + ((size_t)blockIdx.z*4608 + mb + c0 + lr)*256 + nb + c4*4)
                    = *(const float4*)&ldsf[lr*132 + c4*4];
            }
        }
    } else {
        // swapped-selection: adj row = B-side (nb + wc*64 + nj*16 + fr); c = A-side.
        const int cbR = blockIdx.x * 2 + wr;
#pragma unroll
        for (int nj=0;nj<4;nj++){
            int row = nb + wc*64 + nj*16 + fr;
            float tv[3] = {NEG_INF, NEG_INF, NEG_INF};
            int   ti[3] = {0x7fffffff, 0x7fffffff, 0x7fffffff};
#pragma unroll
            for (int mi=0;mi<4;mi++)
#pragma unroll
                for (int t=0;t<4;t++)
                    tk_insert(acc[mi][nj][t], mb + wr*64 + mi*16 + fq*4 + t, tv, ti);
#pragma unroll
            for (int off=16; off<64; off<<=1){
                float ov[3]; int oi[3];
#pragma unroll
                for (int e=0;e<3;e++){ ov[e]=__shfl_xor(tv[e],off); oi[e]=__shfl_xor(ti[e],off); }
#pragma unroll
                for (int e=0;e<3;e++) tk_insert(ov[e], oi[e], tv, ti);
            }
            if (fq == 0){
#pragma unroll
                for (int e=0;e<3;e++)
                    apk[(size_t)row*432 + cbR*3 + e] = mkkey(tv[e], ti[e]);
            }
        }
    }
}

// named instantiations (distinct rocprof rows)
__global__ __launch_bounds__(256)
void mm_proj(const u16* Ah, int lda, const u16* Bh, int ldb,
             const float* bias0, const float* bias1, int nHalf,
             void* Cout, int ldc, int K)
{
    mm_core<false,0>(Ah, nullptr, lda, Bh, nullptr, ldb, bias0, bias1, nHalf,
                     Cout, ldc, K, nullptr);
}
__global__ __launch_bounds__(256)
void mm_adj(const u16* Ah, int lda, u64* apk)
{
    mm_core<false,1>(Ah, nullptr, lda, Ah, nullptr, lda, nullptr, nullptr, 0,
                     nullptr, 0, 256, apk);
}
__global__ __launch_bounds__(256)
void mm_conv(const u16* Ah, const u16* Al, int lda, const u16* Bh, const u16* Bl, int ldb,
             float* Cout, int K)
{
    mm_core<true,2>(Ah, Al, lda, Bh, Bl, ldb, nullptr, nullptr, 0,
                    Cout, 256, K, nullptr);
}

// merge: 432 packed keys per row -> top-8, ONE WAVE PER ROW (sort-network + head-pop).
__device__ __forceinline__ void ce_desc(u64& a, u64& b){
    u64 mx = a > b ? a : b; u64 mn = a > b ? b : a; a = mx; b = mn;
}
__global__ __launch_bounds__(256)
void adj_merge8(const u64* __restrict__ apk, int* __restrict__ c8i)
{
    int row = blockIdx.x * 4 + (threadIdx.x >> 6);
    int ln = threadIdx.x & 63;
    u64 k[7];
#pragma unroll
    for (int j=0;j<7;j++){
        int t = ln + 64*j;
        k[j] = (t < 432) ? apk[(size_t)row*432 + t] : 0ull;
    }
    ce_desc(k[0],k[6]); ce_desc(k[2],k[3]); ce_desc(k[4],k[5]);
    ce_desc(k[0],k[2]); ce_desc(k[1],k[4]); ce_desc(k[3],k[6]);
    ce_desc(k[0],k[1]); ce_desc(k[2],k[5]); ce_desc(k[3],k[4]);
    ce_desc(k[1],k[2]); ce_desc(k[4],k[6]);
    ce_desc(k[2],k[3]); ce_desc(k[4],k[5]);
    ce_desc(k[1],k[2]); ce_desc(k[3],k[4]); ce_desc(k[5],k[6]);
#pragma unroll
    for (int r=0;r<8;r++){
        u64 m = k[0];
#pragma unroll
        for (int off=1; off<64; off<<=1){
            u64 o = __shfl_xor((unsigned long long)m, off);
            m = o > m ? o : m;
        }
        if (k[0] == m){
            k[0]=k[1]; k[1]=k[2]; k[2]=k[3]; k[3]=k[4]; k[4]=k[5]; k[5]=k[6]; k[6]=0ull;
        }
        if (ln == 0) c8i[row*8 + r] = (int)(~(u32)(m & 0xFFFFFFFFull));
    }
}

// exact fp32 rescore of 8 candidates per row, final top-3 (lax.top_k semantics).
__global__ __launch_bounds__(256)
void rescore_select(const float* __restrict__ emb, const int* __restrict__ c8i,
                    float* __restrict__ vals, int* __restrict__ idx)
{
    int gid = blockIdx.x * 256 + threadIdx.x;
    int row = gid >> 6;
    int ln = threadIdx.x & 63;
    float a[4];
    *(float4*)a = *(const float4*)(emb + (size_t)row*256 + ln*4);
    float sc[8];
#pragma unroll
    for (int c=0;c<8;c++){
        int cand = c8i[row*8+c];
        float4 b = *(const float4*)(emb + (size_t)cand*256 + ln*4);
        float p = a[0]*b.x + a[1]*b.y + a[2]*b.z + a[3]*b.w;
#pragma unroll
        for (int off=1; off<64; off<<=1) p += __shfl_xor(p, off);
        sc[c] = p;
    }
    if (ln == 0){
        float tv[3]={NEG_INF,NEG_INF,NEG_INF};
        int   ti[3]={0x7fffffff,0x7fffffff,0x7fffffff};
#pragma unroll
        for (int c=0;c<8;c++) tk_insert(sc[c], c8i[row*8+c], tv, ti);
#pragma unroll
        for (int e=0;e<3;e++){ vals[row*3+e]=tv[e]; idx[row*3+e]=ti[e]; }
    }
}

// ---------------- GATv2 softmax + aggregate + bias + ELU, bf16 inputs --------------
template<int H, int TPH, bool SPATIAL, bool OUTBF>
__global__ __launch_bounds__(H*TPH)
void gat_agg(const u16* __restrict__ xlxr, int ldx, int xrOff,
             const float* __restrict__ att, const float* __restrict__ bias,
             const float* __restrict__ vals, const int* __restrict__ idx,
             void* __restrict__ outp, int ldo)
{
    constexpr int D = 256;
    constexpr int DPT = D / TPH;
    const int n = blockIdx.x;
    const int tid = threadIdx.x;
    const int h = tid / TPH;
    const int l = tid % TPH;
    const int d0 = l * DPT;

    int srcs[4]; bool valid[4];
#pragma unroll
    for (int s=0;s<4;s++){ srcs[s]=n; valid[s]=(s==3); }
    if constexpr (SPATIAL) {
        int pi = n / 96, pj = n - (n/96)*96;
        int cand[4]; int nc=0;
        if (pi > 0)  cand[nc++] = n - 96;
        if (pj > 0)  cand[nc++] = n - 1;
        if (pj < 95) cand[nc++] = n + 1;
        if (pi < 95) cand[nc++] = n + 96;
        int s0 = cand[0], s1 = cand[1];
        if (s0 > n){ srcs[0]=s0; valid[0]=true; }
        if (s1 > n){ srcs[1]=s1; valid[1]=true; }
    } else {
#pragma unroll
        for (int t=0;t<3;t++){
            int s = idx[n*3+t];
            float v = vals[n*3+t];
            if (s > n && v != 0.0f){ srcs[t]=s; valid[t]=true; }
        }
    }

    float xrv[DPT], attv[DPT];
#pragma unroll
    for (int q=0;q<DPT/4;q++){
        ushort4 u = *(const ushort4*)(xlxr + (size_t)n*ldx + xrOff + h*D + d0 + q*4);
        xrv[q*4+0]=b2f(u.x); xrv[q*4+1]=b2f(u.y); xrv[q*4+2]=b2f(u.z); xrv[q*4+3]=b2f(u.w);
        *(float4*)&attv[q*4] = *(const float4*)(att + h*D + d0 + q*4);
    }

    float xs[4][DPT];
    float sc[4];
#pragma unroll
    for (int s=0;s<4;s++){
#pragma unroll
        for (int q=0;q<DPT/4;q++){
            ushort4 u = *(const ushort4*)(xlxr + (size_t)srcs[s]*ldx + h*D + d0 + q*4);
            xs[s][q*4+0]=b2f(u.x); xs[s][q*4+1]=b2f(u.y); xs[s][q*4+2]=b2f(u.z); xs[s][q*4+3]=b2f(u.w);
        }
        float p = 0.f;
#pragma unroll
        for (int d=0;d<DPT;d++){
            float e = xs[s][d] + xrv[d];
            e = (e > 0.f) ? e : 0.2f*e;
            p += attv[d]*e;
        }
#pragma unroll
        for (int off=1; off<TPH; off<<=1) p += __shfl_xor(p, off);
        sc[s] = p;
    }
    float m = NEG_INF;
#pragma unroll
    for (int s=0;s<4;s++) if (valid[s]) m = fmaxf(m, sc[s]);
    float al[4]; float denom = 0.f;
#pragma unroll
    for (int s=0;s<4;s++){ al[s] = valid[s] ? expf(sc[s]-m) : 0.f; denom += al[s]; }
    float inv = 1.f / denom;

    float o[DPT];
#pragma unroll
    for (int d=0;d<DPT;d++){
        float acc = al[0]*xs[0][d] + al[1]*xs[1][d] + al[2]*xs[2][d] + al[3]*xs[3][d];
        acc = acc*inv + bias[h*D + d0 + d];
        o[d] = (acc > 0.f) ? acc : (expf(acc) - 1.f);
    }
    if constexpr (OUTBF) {
        u16 ov[DPT];
#pragma unroll
        for (int d=0;d<DPT;d++) ov[d] = f2bu(o[d]);
#pragma unroll
        for (int q=0;q<DPT/8;q++)
            *(uint4*)((u16*)outp + (size_t)n*ldo + h*D + d0 + q*8) = *(uint4*)&ov[q*8];
        if constexpr (DPT < 8)
            *(uint2*)((u16*)outp + (size_t)n*ldo + h*D + d0) = *(uint2*)ov;
    } else {
#pragma unroll
        for (int q=0;q<DPT/4;q++)
            *(float4*)((float*)outp + (size_t)n*ldo + h*D + d0 + q*4) = *(float4*)&o[q*4];
    }
}

// ---------------------------------------------------------------------------
extern "C" void kernel_launch(void* const* d_in, const int* in_sizes, int n_in,
                              void* d_out, int out_size, void* d_ws, size_t ws_size,
                              hipStream_t stream)
{
    (void)in_sizes; (void)n_in;
    const float* x      = (const float*)d_in[0];
    const float* conv_w = (const float*)d_in[1];
    const float* conv_b = (const float*)d_in[2];
    const float* fc2_w  = (const float*)d_in[3];
    const float* fc2_b  = (const float*)d_in[4];
    const float* fc3_w  = (const float*)d_in[5];
    const float* fc3_b  = (const float*)d_in[6];
    const float* g_wl[4]   = {(const float*)d_in[7],  (const float*)d_in[13], (const float*)d_in[19], (const float*)d_in[25]};
    const float* g_bl[4]   = {(const float*)d_in[8],  (const float*)d_in[14], (const float*)d_in[20], (const float*)d_in[26]};
    const float* g_wr[4]   = {(const float*)d_in[9],  (const float*)d_in[15], (const float*)d_in[21], (const float*)d_in[27]};
    const float* g_br[4]   = {(const float*)d_in[10], (const float*)d_in[16], (const float*)d_in[22], (const float*)d_in[28]};
    const float* g_att[4]  = {(const float*)d_in[11], (const float*)d_in[17], (const float*)d_in[23], (const float*)d_in[29]};
    const float* g_bias[4] = {(const float*)d_in[12], (const float*)d_in[18], (const float*)d_in[24], (const float*)d_in[30]};

    float* ws = (float*)d_ws;
    size_t off = 0;
    float* emb1  = ws + off; off += 2359296;                  // [9216][256] f32 (persists)
    size_t emb_off = off;
    float* emb   = ws + off; off += 2359296;
    u16*   emb_h = (u16*)(ws + off); off += 1179648;          // [9216][256] bf16
    u16*   emb_l = (u16*)(ws + off); off += 1179648;
    u16*   Wt[4];
    Wt[0] = (u16*)(ws + off); off += 524288;                  // [4096][256] bf16
    Wt[1] = (u16*)(ws + off); off += 524288;                  // [512][2048] bf16
    Wt[2] = (u16*)(ws + off); off += 524288;
    Wt[3] = (u16*)(ws + off); off += 524288;
    u64*   apk  = (u64*)(ws + off); off += 7962624;           // [9216][432] u64 keys
    int*   c8i  = (int*)(ws + off); off += 73728;             // [9216][8]
    float* vals = ws + off; off += 27648;
    int*   idx  = (int*)(ws + off); off += 27648;
    float* h2   = ws + off; off += 2359296;
    float* h4   = ws + off; off += 2359296;
    u16*   xlxr = (u16*)(ws + off); off += 18874368;          // [9216][4096] u16
    u16*   hbig = (u16*)(ws + off); off += 9437184;           // [9216][2048] u16
    u16*   WbH  = (u16*)(ws + off); off += 851968;            // [256][6400] bf16 (conv W split)
    u16*   WbL  = (u16*)(ws + off); off += 851968;
    // conv-phase scratch, aliased onto post-conv region starting at emb
    u16*   xp_h = (u16*)(ws + emb_off);                          // [4608][6400] u16
    u16*   xp_l = (u16*)(ws + emb_off + 14745600);
    float* cpart = ws + emb_off + 29491200;                      // [4][4608][256] f32
    size_t need = off * sizeof(float);
    if (ws_size < need) {
        hipMemsetAsync(d_out, 0, (size_t)out_size*sizeof(float), stream);
        return;
    }
    float* out = (float*)d_out;

    // conv1 = bf16-split-3-term NT GEMM over im2col'd x (two row-halves, K-split x4).
    cvt_hilo<<<1600,256,0,stream>>>(conv_w, WbH, WbL, 409600);
    for (int half = 0; half < 2; ++half) {
        xpb_build<<<12288,256,0,stream>>>(x, half*4608, xp_h, xp_l);
        mm_conv<<<dim3(36,2,4),256,0,stream>>>(xp_h, xp_l, 6400, WbH, WbL, 6400, cpart, 1600);
        conv_reduce2<<<1152,256,0,stream>>>(cpart, conv_b, emb1 + (size_t)half*4608*256);
    }
    // fc2 fp32 -> emb (exact; feeds graph + rescore)
    gemm_f32<1><<<dim3(72,4),256,0,stream>>>(emb1,256,256, emb1,256, fc2_w, fc2_b, nullptr, emb, 9216,256,256);

    // conversions: emb -> hi/lo ; weights -> transposed bf16 (wl rows 0..N-1, wr rows N..2N-1)
    cvt_hilo<<<2304,256,0,stream>>>(emb, emb_h, emb_l, 589824);
    transpose_cvt<<<dim3(8,64),256,0,stream>>>(g_wl[0], 256, 2048, Wt[0]);
    transpose_cvt<<<dim3(8,64),256,0,stream>>>(g_wr[0], 256, 2048, Wt[0] + (size_t)2048*256);
    transpose_cvt<<<dim3(64,8),256,0,stream>>>(g_wl[1], 2048, 256, Wt[1]);
    transpose_cvt<<<dim3(64,8),256,0,stream>>>(g_wr[1], 2048, 256, Wt[1] + (size_t)256*2048);
    transpose_cvt<<<dim3(8,64),256,0,stream>>>(g_wl[2], 256, 2048, Wt[2]);
    transpose_cvt<<<dim3(8,64),256,0,stream>>>(g_wr[2], 256, 2048, Wt[2] + (size_t)2048*256);
    transpose_cvt<<<dim3(64,8),256,0,stream>>>(g_wl[3], 2048, 256, Wt[3]);
    transpose_cvt<<<dim3(64,8),256,0,stream>>>(g_wr[3], 2048, 256, Wt[3] + (size_t)256*2048);

    // similarity kNN: 1-term bf16 candidates (swapped-operand selection, packed keys)
    // -> packed-key wave-max merge -> exact fp32 rescore -> top-3.
    mm_adj<<<dim3(72,72),256,0,stream>>>(emb_h, 256, apk);
    adj_merge8<<<2304,256,0,stream>>>(apk, c8i);
    rescore_select<<<2304,256,0,stream>>>(emb, c8i, vals, idx);

    // g1 (H=8, similarity graph)
    mm_proj<<<dim3(72,32),256,0,stream>>>(emb_h, 256, Wt[0], 256, g_bl[0], g_br[0], 2048,
                                          xlxr, 4096, 256);
    gat_agg<8,32,false,true><<<9216,256,0,stream>>>(xlxr, 4096, 2048, g_att[0], g_bias[0], vals, idx, hbig, 2048);
    // g2 (H=1)
    mm_proj<<<dim3(72,4),256,0,stream>>>(hbig, 2048, Wt[1], 2048, g_bl[1], g_br[1], 256,
                                         xlxr, 512, 2048);
    gat_agg<1,64,false,false><<<9216,64,0,stream>>>(xlxr, 512, 256, g_att[1], g_bias[1], vals, idx, h2, 256);
    // g3 (H=8, spatial graph)
    mm_proj<<<dim3(72,32),256,0,stream>>>(emb_h, 256, Wt[2], 256, g_bl[2], g_br[2], 2048,
                                          xlxr, 4096, 256);
    gat_agg<8,32,true,true><<<9216,256,0,stream>>>(xlxr, 4096, 2048, g_att[2], g_bias[2], nullptr, nullptr, hbig, 2048);
    // g4 (H=1)
    mm_proj<<<dim3(72,4),256,0,stream>>>(hbig, 2048, Wt[3], 2048, g_bl[3], g_br[3], 256,
                                         xlxr, 512, 2048);
    gat_agg<1,64,true,false><<<9216,64,0,stream>>>(xlxr, 512, 256, g_att[3], g_bias[3], nullptr, nullptr, h4, 256);

    // fc3 on concat(h2,h4) + relu + residual(h4) -> out
    gemm_f32<1><<<dim3(72,4),256,0,stream>>>(h2,256,256, h4,256, fc3_w, fc3_b, h4, out, 9216,256,512);
}

// Round 18
// 810.834 us; speedup vs baseline: 1.5289x; 1.0633x over previous
//
#include <hip/hip_runtime.h>
#include <cstdint>
#include <cstddef>

#define NEG_INF (-3.402823466e38f)
typedef unsigned short u16;
typedef unsigned int u32;
typedef unsigned long long u64;

typedef short s16x8 __attribute__((ext_vector_type(8)));
typedef __bf16 bf16x8_t __attribute__((ext_vector_type(8)));
typedef float f32x4 __attribute__((ext_vector_type(4)));

__device__ __forceinline__ f32x4 mfma_bf16(s16x8 a, s16x8 b, f32x4 c){
    return __builtin_amdgcn_mfma_f32_16x16x32_bf16(
        __builtin_bit_cast(bf16x8_t, a), __builtin_bit_cast(bf16x8_t, b), c, 0, 0, 0);
}
__device__ __forceinline__ float b2f(u16 u){ return __uint_as_float(((u32)u) << 16); }
__device__ __forceinline__ u16 f2bu(float f){           // RNE fp32 -> bf16 bits
    u32 u = __float_as_uint(f);
    return (u16)((u + 0x7fffu + ((u >> 16) & 1u)) >> 16);
}
// async global->LDS, 16B/lane; LDS dest = wave-uniform base + lane*16 (m97 pattern)
__device__ __forceinline__ void gload16(const u16* __restrict__ g, u16* l){
    __builtin_amdgcn_global_load_lds(
        (const __attribute__((address_space(1))) u32*)g,
        (__attribute__((address_space(3))) u32*)l, 16, 0, 0);
}
// monotone (val desc, idx asc) <-> u64 key desc ; keys unique (idx unique), > 0
__device__ __forceinline__ u64 mkkey(float v, int id){
    u32 s = __float_as_uint(v);
    s ^= (u32)(((int)s >> 31)) | 0x80000000u;
    return ((u64)s << 32) | (u32)(~(u32)id);
}

// ---------------- top-k helpers (JAX lax.top_k stable: val desc, idx asc on ties) ----
__device__ __forceinline__ bool tk_gt(float v, int i, float w, int j){
    return (v > w) || (v == w && i < j);
}
__device__ __forceinline__ void tk_insert(float v, int id, float tv[3], int ti[3]){
    if (!tk_gt(v, id, tv[2], ti[2])) return;
    if (tk_gt(v, id, tv[1], ti[1])) {
        tv[2]=tv[1]; ti[2]=ti[1];
        if (tk_gt(v, id, tv[0], ti[0])) { tv[1]=tv[0]; ti[1]=ti[0]; tv[0]=v; ti[0]=id; }
        else { tv[1]=v; ti[1]=id; }
    } else { tv[2]=v; ti[2]=id; }
}

// ---------------- conversion pre-passes --------------------------------------------
__global__ void cvt_hilo(const float* __restrict__ in, u16* __restrict__ hi,
                         u16* __restrict__ lo, int n4)
{
    int i = blockIdx.x * 256 + threadIdx.x;
    if (i >= n4) return;
    float4 v = ((const float4*)in)[i];
    u16 h[4], l[4];
    float f[4] = {v.x, v.y, v.z, v.w};
#pragma unroll
    for (int j=0;j<4;j++){
        u16 hb = f2bu(f[j]);
        h[j] = hb;
        l[j] = f2bu(f[j] - b2f(hb));
    }
    *(ushort4*)&hi[i*4] = *(ushort4*)h;
    *(ushort4*)&lo[i*4] = *(ushort4*)l;
}

// im2col + bf16-split, READ-COALESCED (R17). One block per (channel, patch-row).
__global__ __launch_bounds__(256)
void xpb_build(const float* __restrict__ x, int base,
               u16* __restrict__ xh, u16* __restrict__ xl)
{
    __shared__ u16 lh[96*26], ll[96*26];
    const int c = blockIdx.x / 48;
    const int piL = blockIdx.x - c*48;
    const int pi = (base/96) + piL;
    const int tid = threadIdx.x;

    for (int e = tid; e < 600; e += 256){
        int r = e / 120, col4 = e - r*120;
        float4 v = *(const float4*)(x + (size_t)c*230400 + (size_t)(pi*5+r)*480 + col4*4);
        float f[4] = {v.x, v.y, v.z, v.w};
#pragma unroll
        for (int j=0;j<4;j++){
            int col = col4*4 + j;
            int pj = col / 5, jj = col - pj*5;
            u16 hb = f2bu(f[j]);
            int lo = pj*26 + r*5 + jj;
            lh[lo] = hb;
            ll[lo] = f2bu(f[j] - b2f(hb));
        }
    }
    __syncthreads();
    for (int e = tid; e < 2400; e += 256){
        int pj = e / 25, kk = e - pj*25;
        size_t go = (size_t)(piL*96 + pj)*6400 + c*25 + kk;
        xh[go] = lh[pj*26 + kk];
        xl[go] = ll[pj*26 + kk];
    }
}

// sum 4 K-split partials + bias + relu -> emb1 rows (one half = 294912 float4)
__global__ void conv_reduce2(const float* __restrict__ p, const float* __restrict__ bias,
                             float* __restrict__ o)
{
    int i = blockIdx.x * 256 + threadIdx.x;
    const float4* p4 = (const float4*)p;
    float4 s = p4[i];
#pragma unroll
    for (int j=1;j<4;j++){
        float4 v = p4[i + (size_t)j*294912];
        s.x += v.x; s.y += v.y; s.z += v.z; s.w += v.w;
    }
    float4 bb = ((const float4*)bias)[i & 63];
    float4 r;
    r.x = fmaxf(s.x+bb.x, 0.f);
    r.y = fmaxf(s.y+bb.y, 0.f);
    r.z = fmaxf(s.z+bb.z, 0.f);
    r.w = fmaxf(s.w+bb.w, 0.f);
    ((float4*)o)[i] = r;
}

// ---------------- generic fp32 GEMM (fc2) ------------------------------------------
template<int ACT>
__global__ __launch_bounds__(256)
void gemm_f32(const float* __restrict__ A1, int ldA1, int K1,
              const float* __restrict__ A2, int ldA2,
              const float* __restrict__ B, const float* __restrict__ bias,
              const float* __restrict__ add,
              float* __restrict__ C, int M, int N, int K)
{
    __shared__ __align__(16) float As[16][128];
    __shared__ __align__(16) float Bs[16][64];
    const int mb = blockIdx.x * 128, nb = blockIdx.y * 64;
    const int tid = threadIdx.x;
    const int tn = tid & 15, tm = tid >> 4;
    float acc[8][4];
#pragma unroll
    for (int i=0;i<8;i++){
#pragma unroll
        for (int j=0;j<4;j++) acc[i][j]=0.f;
    }
    const int am = tid >> 2;
    const int ak = (tid & 3) * 4;
    const int bk = tid >> 4;
    const int bn = (tid & 15) * 4;

    for (int k0 = 0; k0 < K; k0 += 16) {
        int kg = k0 + ak;
#pragma unroll
        for (int half = 0; half < 2; ++half) {
            int ml = am + half*64;
            int m = mb + ml;
            float4 v;
            if (kg < K1) v = *(const float4*)(A1 + (size_t)m*ldA1 + kg);
            else         v = *(const float4*)(A2 + (size_t)m*ldA2 + (kg - K1));
            As[ak+0][ml] = v.x; As[ak+1][ml] = v.y; As[ak+2][ml] = v.z; As[ak+3][ml] = v.w;
        }
        {
            float4 v = *(const float4*)(B + (size_t)(k0+bk)*N + nb + bn);
            *(float4*)&Bs[bk][bn] = v;
        }
        __syncthreads();
#pragma unroll
        for (int kk=0;kk<16;kk++){
            float a[8], b[4];
            *(float4*)&a[0] = *(const float4*)&As[kk][tm*8];
            *(float4*)&a[4] = *(const float4*)&As[kk][tm*8+4];
            *(float4*)&b[0] = *(const float4*)&Bs[kk][tn*4];
#pragma unroll
            for (int i=0;i<8;i++){
#pragma unroll
                for (int j=0;j<4;j++) acc[i][j] += a[i]*b[j];
            }
        }
        __syncthreads();
    }
#pragma unroll
    for (int i=0;i<8;i++){
        int m = mb + tm*8 + i;
        float ov[4];
#pragma unroll
        for (int j=0;j<4;j++){
            int n = nb + tn*4 + j;
            float v = acc[i][j] + bias[n];
            if (ACT == 1) v = v > 0.f ? v : 0.f;
            if (add) v += add[(size_t)m*N + n];
            ov[j] = v;
        }
        *(float4*)(C + (size_t)m*N + nb + tn*4) = *(float4*)ov;
    }
}

// fp32 [K][N] row-major -> bf16 out[N][K]
__global__ __launch_bounds__(256)
void transpose_cvt(const float* __restrict__ in, int K, int N, u16* __restrict__ out)
{
    __shared__ float t[32][33];
    const int kb = blockIdx.x * 32, nb = blockIdx.y * 32;
    const int tx = threadIdx.x & 31, ty = threadIdx.x >> 5;   // 32 x 8
#pragma unroll
    for (int r=0;r<4;r++)
        t[ty + r*8][tx] = in[(size_t)(kb + ty + r*8)*N + nb + tx];
    __syncthreads();
#pragma unroll
    for (int r=0;r<4;r++)
        out[(size_t)(nb + ty + r*8)*K + kb + tx] = f2bu(t[tx][ty + r*8]);
}

// ---------------- bf16 MFMA NT GEMM core: C[M][N] = A[M][K] @ B[N][K]^T ------------
// 128x128 tile, BK=32, global_load_lds staging, linear LDS [128][32].
// EPI 0: bf16 store via LDS-bounce. EPI 1: swapped-operand top-3 packed keys.
// EPI 2: conv K-split f32 partials. EPI 3 (R18): f32 out = relu(acc+bias0) + ADD
// (bias1 reinterpreted as the f32 add matrix, ld = ldc) — fc3 epilogue.
template<bool SPLIT, int EPI>
__device__ __forceinline__
void mm_core(const u16* __restrict__ Ah, const u16* __restrict__ Al, int lda,
             const u16* __restrict__ Bh, const u16* __restrict__ Bl, int ldb,
             const float* __restrict__ bias0, const float* __restrict__ bias1, int nHalf,
             void* __restrict__ Cout, int ldc, int K,
             u64* __restrict__ apk)
{
    constexpr int TSZ = 128 * 32;
    __shared__ u16 smem[(SPLIT ? 4 : 2) * TSZ];
    u16* AsH = smem;
    u16* BsH = smem + TSZ;
    u16* AsL = SPLIT ? smem + 2*TSZ : nullptr;
    u16* BsL = SPLIT ? smem + 3*TSZ : nullptr;

    const int tid = threadIdx.x;
    const int w = tid >> 6, ln = tid & 63;
    const int wr = w >> 1, wc = w & 1;
    const int fr = ln & 15, fq = ln >> 4;
    const int mb = blockIdx.x * 128, nb = blockIdx.y * 128;
    const int skk = (ln & 3) * 8;

    int kbeg = 0;
    if constexpr (EPI == 2) kbeg = blockIdx.z * K;
    const int kend = kbeg + K;

    f32x4 acc[4][4];
#pragma unroll
    for (int i=0;i<4;i++)
#pragma unroll
        for (int j=0;j<4;j++) acc[i][j] = (f32x4){0.f,0.f,0.f,0.f};

    for (int k0 = kbeg; k0 < kend; k0 += 32) {
#pragma unroll
        for (int t=0;t<2;t++){
            int rbase = w*32 + t*16;
            int r = rbase + (ln >> 2);
            size_t goA = (size_t)(mb + r)*lda + k0 + skk;
            size_t goB = (size_t)(nb + r)*ldb + k0 + skk;
            gload16(Ah + goA, AsH + rbase*32);
            gload16(Bh + goB, BsH + rbase*32);
            if constexpr (SPLIT){
                gload16(Al + goA, AsL + rbase*32);
                gload16(Bl + goB, BsL + rbase*32);
            }
        }
        __syncthreads();
        s16x8 ah[4], bh[4], al[4], bl[4];
#pragma unroll
        for (int mi=0;mi<4;mi++){
            int ro = (wr*64 + mi*16 + fr)*32 + fq*8;
            ah[mi] = *(const s16x8*)&AsH[ro];
            if constexpr (SPLIT) al[mi] = *(const s16x8*)&AsL[ro];
        }
#pragma unroll
        for (int nj=0;nj<4;nj++){
            int ro = (wc*64 + nj*16 + fr)*32 + fq*8;
            bh[nj] = *(const s16x8*)&BsH[ro];
            if constexpr (SPLIT) bl[nj] = *(const s16x8*)&BsL[ro];
        }
#pragma unroll
        for (int mi=0;mi<4;mi++)
#pragma unroll
            for (int nj=0;nj<4;nj++){
                acc[mi][nj] = mfma_bf16(ah[mi], bh[nj], acc[mi][nj]);
                if constexpr (SPLIT){
                    acc[mi][nj] = mfma_bf16(ah[mi], bl[nj], acc[mi][nj]);
                    acc[mi][nj] = mfma_bf16(al[mi], bh[nj], acc[mi][nj]);
                }
            }
        __syncthreads();
    }

    if constexpr (EPI == 0) {
        u16* ldsc = smem;
#pragma unroll
        for (int chunk=0; chunk<4; ++chunk){
            __syncthreads();
            if (wr == (chunk>>1)){
                int mi0 = (chunk&1)*2;
#pragma unroll
                for (int m2=0;m2<2;m2++){
                    int mi = mi0 + m2;
#pragma unroll
                    for (int nj=0;nj<4;nj++)
#pragma unroll
                    for (int t=0;t<4;t++){
                        int lr = m2*16 + fq*4 + t;
                        int lc = wc*64 + nj*16 + fr;
                        int col = nb + lc;
                        float v = acc[mi][nj][t];
                        if (bias0) v += (col < nHalf) ? bias0[col] : bias1[col - nHalf];
                        ldsc[lr*136 + lc] = f2bu(v);
                    }
                }
            }
            __syncthreads();
            int c0 = chunk*32;
#pragma unroll
            for (int q=0;q<2;q++){
                int e = q*256 + tid;
                int lr = e >> 4, c16 = e & 15;
                *(uint4*)((u16*)Cout + (size_t)(mb + c0 + lr)*ldc + nb + c16*8)
                    = *(const uint4*)&ldsc[lr*136 + c16*8];
            }
        }
    } else if constexpr (EPI == 2 || EPI == 3) {
        float* ldsf = (float*)smem;
        const int NC = (EPI == 3) ? ldc : 256;   // EPI3: N==ldc==256 tile width 128
#pragma unroll
        for (int chunk=0; chunk<8; ++chunk){
            __syncthreads();
            if (wr == (chunk>>2)){
                int mi = chunk & 3;
#pragma unroll
                for (int nj=0;nj<4;nj++)
#pragma unroll
                for (int t=0;t<4;t++){
                    int lr = fq*4 + t;
                    int lc = wc*64 + nj*16 + fr;
                    float v = acc[mi][nj][t];
                    if constexpr (EPI == 3){
                        v += bias0[nb + lc];
                        v = fmaxf(v, 0.f);
                    }
                    ldsf[lr*132 + lc] = v;
                }
            }
            __syncthreads();
            int c0 = chunk*16;
#pragma unroll
            for (int q=0;q<2;q++){
                int e = q*256 + tid;
                int lr = e >> 5, c4 = e & 31;
                if (c4 >= 32) continue;
                int row = mb + c0 + lr, col = nb + c4*4;
                if constexpr (EPI == 3){
                    float4 a = *(const float4*)(bias1 + (size_t)row*NC + col);
                    float4 v = *(const float4*)&ldsf[lr*132 + c4*4];
                    v.x += a.x; v.y += a.y; v.z += a.z; v.w += a.w;
                    *(float4*)((float*)Cout + (size_t)row*NC + col) = v;
                } else {
                    *(float4*)((float*)Cout + ((size_t)blockIdx.z*4608 + row)*256 + col)
                        = *(const float4*)&ldsf[lr*132 + c4*4];
                }
            }
        }
    } else {
        // swapped-selection: adj row = B-side (nb + wc*64 + nj*16 + fr); c = A-side.
        const int cbR = blockIdx.x * 2 + wr;
#pragma unroll
        for (int nj=0;nj<4;nj++){
            int row = nb + wc*64 + nj*16 + fr;
            float tv[3] = {NEG_INF, NEG_INF, NEG_INF};
            int   ti[3] = {0x7fffffff, 0x7fffffff, 0x7fffffff};
#pragma unroll
            for (int mi=0;mi<4;mi++)
#pragma unroll
                for (int t=0;t<4;t++)
                    tk_insert(acc[mi][nj][t], mb + wr*64 + mi*16 + fq*4 + t, tv, ti);
#pragma unroll
            for (int off=16; off<64; off<<=1){
                float ov[3]; int oi[3];
#pragma unroll
                for (int e=0;e<3;e++){ ov[e]=__shfl_xor(tv[e],off); oi[e]=__shfl_xor(ti[e],off); }
#pragma unroll
                for (int e=0;e<3;e++) tk_insert(ov[e], oi[e], tv, ti);
            }
            if (fq == 0){
#pragma unroll
                for (int e=0;e<3;e++)
                    apk[(size_t)row*432 + cbR*3 + e] = mkkey(tv[e], ti[e]);
            }
        }
    }
}

// named instantiations (distinct rocprof rows)
__global__ __launch_bounds__(256)
void mm_proj(const u16* Ah, int lda, const u16* Bh, int ldb,
             const float* bias0, const float* bias1, int nHalf,
             void* Cout, int ldc, int K)
{
    mm_core<false,0>(Ah, nullptr, lda, Bh, nullptr, ldb, bias0, bias1, nHalf,
                     Cout, ldc, K, nullptr);
}
__global__ __launch_bounds__(256)
void mm_adj(const u16* Ah, int lda, u64* apk)
{
    mm_core<false,1>(Ah, nullptr, lda, Ah, nullptr, lda, nullptr, nullptr, 0,
                     nullptr, 0, 256, apk);
}
__global__ __launch_bounds__(256)
void mm_conv(const u16* Ah, const u16* Al, int lda, const u16* Bh, const u16* Bl, int ldb,
             float* Cout, int K)
{
    mm_core<true,2>(Ah, Al, lda, Bh, Bl, ldb, nullptr, nullptr, 0,
                    Cout, 256, K, nullptr);
}
// fc3: out = relu(hcat @ WtF^T + bias) + add ; f32 out, ld 256
__global__ __launch_bounds__(256)
void mm_fc3(const u16* Ah, int lda, const u16* Bh, int ldb,
            const float* bias, const float* add, float* Cout)
{
    mm_core<false,3>(Ah, nullptr, lda, Bh, nullptr, ldb, bias, add, 0,
                     Cout, 256, 512, nullptr);
}

// merge: 432 packed keys per row -> top-8, ONE WAVE PER ROW (sort-network + head-pop).
__device__ __forceinline__ void ce_desc(u64& a, u64& b){
    u64 mx = a > b ? a : b; u64 mn = a > b ? b : a; a = mx; b = mn;
}
__global__ __launch_bounds__(256)
void adj_merge8(const u64* __restrict__ apk, int* __restrict__ c8i)
{
    int row = blockIdx.x * 4 + (threadIdx.x >> 6);
    int ln = threadIdx.x & 63;
    u64 k[7];
#pragma unroll
    for (int j=0;j<7;j++){
        int t = ln + 64*j;
        k[j] = (t < 432) ? apk[(size_t)row*432 + t] : 0ull;
    }
    ce_desc(k[0],k[6]); ce_desc(k[2],k[3]); ce_desc(k[4],k[5]);
    ce_desc(k[0],k[2]); ce_desc(k[1],k[4]); ce_desc(k[3],k[6]);
    ce_desc(k[0],k[1]); ce_desc(k[2],k[5]); ce_desc(k[3],k[4]);
    ce_desc(k[1],k[2]); ce_desc(k[4],k[6]);
    ce_desc(k[2],k[3]); ce_desc(k[4],k[5]);
    ce_desc(k[1],k[2]); ce_desc(k[3],k[4]); ce_desc(k[5],k[6]);
#pragma unroll
    for (int r=0;r<8;r++){
        u64 m = k[0];
#pragma unroll
        for (int off=1; off<64; off<<=1){
            u64 o = __shfl_xor((unsigned long long)m, off);
            m = o > m ? o : m;
        }
        if (k[0] == m){
            k[0]=k[1]; k[1]=k[2]; k[2]=k[3]; k[3]=k[4]; k[4]=k[5]; k[5]=k[6]; k[6]=0ull;
        }
        if (ln == 0) c8i[row*8 + r] = (int)(~(u32)(m & 0xFFFFFFFFull));
    }
}

// exact fp32 rescore of 8 candidates per row, final top-3 (lax.top_k semantics).
__global__ __launch_bounds__(256)
void rescore_select(const float* __restrict__ emb, const int* __restrict__ c8i,
                    float* __restrict__ vals, int* __restrict__ idx)
{
    int gid = blockIdx.x * 256 + threadIdx.x;
    int row = gid >> 6;
    int ln = threadIdx.x & 63;
    float a[4];
    *(float4*)a = *(const float4*)(emb + (size_t)row*256 + ln*4);
    float sc[8];
#pragma unroll
    for (int c=0;c<8;c++){
        int cand = c8i[row*8+c];
        float4 b = *(const float4*)(emb + (size_t)cand*256 + ln*4);
        float p = a[0]*b.x + a[1]*b.y + a[2]*b.z + a[3]*b.w;
#pragma unroll
        for (int off=1; off<64; off<<=1) p += __shfl_xor(p, off);
        sc[c] = p;
    }
    if (ln == 0){
        float tv[3]={NEG_INF,NEG_INF,NEG_INF};
        int   ti[3]={0x7fffffff,0x7fffffff,0x7fffffff};
#pragma unroll
        for (int c=0;c<8;c++) tk_insert(sc[c], c8i[row*8+c], tv, ti);
#pragma unroll
        for (int e=0;e<3;e++){ vals[row*3+e]=tv[e]; idx[row*3+e]=ti[e]; }
    }
}

// ---------------- GATv2 softmax + aggregate + bias + ELU, bf16 inputs --------------
// outp: bf16 dest (ld=ldo). out2: optional f32 dest (ld=ldo2), for g4's exact residual.
template<int H, int TPH, bool SPATIAL>
__global__ __launch_bounds__(H*TPH)
void gat_agg(const u16* __restrict__ xlxr, int ldx, int xrOff,
             const float* __restrict__ att, const float* __restrict__ bias,
             const float* __restrict__ vals, const int* __restrict__ idx,
             u16* __restrict__ outp, int ldo,
             float* __restrict__ out2, int ldo2)
{
    constexpr int D = 256;
    constexpr int DPT = D / TPH;
    const int n = blockIdx.x;
    const int tid = threadIdx.x;
    const int h = tid / TPH;
    const int l = tid % TPH;
    const int d0 = l * DPT;

    int srcs[4]; bool valid[4];
#pragma unroll
    for (int s=0;s<4;s++){ srcs[s]=n; valid[s]=(s==3); }
    if constexpr (SPATIAL) {
        int pi = n / 96, pj = n - (n/96)*96;
        int cand[4]; int nc=0;
        if (pi > 0)  cand[nc++] = n - 96;
        if (pj > 0)  cand[nc++] = n - 1;
        if (pj < 95) cand[nc++] = n + 1;
        if (pi < 95) cand[nc++] = n + 96;
        int s0 = cand[0], s1 = cand[1];
        if (s0 > n){ srcs[0]=s0; valid[0]=true; }
        if (s1 > n){ srcs[1]=s1; valid[1]=true; }
    } else {
#pragma unroll
        for (int t=0;t<3;t++){
            int s = idx[n*3+t];
            float v = vals[n*3+t];
            if (s > n && v != 0.0f){ srcs[t]=s; valid[t]=true; }
        }
    }

    float xrv[DPT], attv[DPT];
#pragma unroll
    for (int q=0;q<DPT/4;q++){
        ushort4 u = *(const ushort4*)(xlxr + (size_t)n*ldx + xrOff + h*D + d0 + q*4);
        xrv[q*4+0]=b2f(u.x); xrv[q*4+1]=b2f(u.y); xrv[q*4+2]=b2f(u.z); xrv[q*4+3]=b2f(u.w);
        *(float4*)&attv[q*4] = *(const float4*)(att + h*D + d0 + q*4);
    }

    float xs[4][DPT];
    float sc[4];
#pragma unroll
    for (int s=0;s<4;s++){
#pragma unroll
        for (int q=0;q<DPT/4;q++){
            ushort4 u = *(const ushort4*)(xlxr + (size_t)srcs[s]*ldx + h*D + d0 + q*4);
            xs[s][q*4+0]=b2f(u.x); xs[s][q*4+1]=b2f(u.y); xs[s][q*4+2]=b2f(u.z); xs[s][q*4+3]=b2f(u.w);
        }
        float p = 0.f;
#pragma unroll
        for (int d=0;d<DPT;d++){
            float e = xs[s][d] + xrv[d];
            e = (e > 0.f) ? e : 0.2f*e;
            p += attv[d]*e;
        }
#pragma unroll
        for (int off=1; off<TPH; off<<=1) p += __shfl_xor(p, off);
        sc[s] = p;
    }
    float m = NEG_INF;
#pragma unroll
    for (int s=0;s<4;s++) if (valid[s]) m = fmaxf(m, sc[s]);
    float al[4]; float denom = 0.f;
#pragma unroll
    for (int s=0;s<4;s++){ al[s] = valid[s] ? expf(sc[s]-m) : 0.f; denom += al[s]; }
    float inv = 1.f / denom;

    float o[DPT];
#pragma unroll
    for (int d=0;d<DPT;d++){
        float acc = al[0]*xs[0][d] + al[1]*xs[1][d] + al[2]*xs[2][d] + al[3]*xs[3][d];
        acc = acc*inv + bias[h*D + d0 + d];
        o[d] = (acc > 0.f) ? acc : (expf(acc) - 1.f);
    }
    // bf16 out
    u16 ov[DPT];
#pragma unroll
    for (int d=0;d<DPT;d++) ov[d] = f2bu(o[d]);
    if constexpr (DPT >= 8){
#pragma unroll
        for (int q=0;q<DPT/8;q++)
            *(uint4*)(outp + (size_t)n*ldo + h*D + d0 + q*8) = *(uint4*)&ov[q*8];
    } else {
        *(uint2*)(outp + (size_t)n*ldo + h*D + d0) = *(uint2*)ov;
    }
    // optional f32 out (exact residual path)
    if (out2){
#pragma unroll
        for (int q=0;q<DPT/4;q++)
            *(float4*)(out2 + (size_t)n*ldo2 + h*D + d0 + q*4) = *(float4*)&o[q*4];
    }
}

// ---------------------------------------------------------------------------
extern "C" void kernel_launch(void* const* d_in, const int* in_sizes, int n_in,
                              void* d_out, int out_size, void* d_ws, size_t ws_size,
                              hipStream_t stream)
{
    (void)in_sizes; (void)n_in;
    const float* x      = (const float*)d_in[0];
    const float* conv_w = (const float*)d_in[1];
    const float* conv_b = (const float*)d_in[2];
    const float* fc2_w  = (const float*)d_in[3];
    const float* fc2_b  = (const float*)d_in[4];
    const float* fc3_w  = (const float*)d_in[5];
    const float* fc3_b  = (const float*)d_in[6];
    const float* g_wl[4]   = {(const float*)d_in[7],  (const float*)d_in[13], (const float*)d_in[19], (const float*)d_in[25]};
    const float* g_bl[4]   = {(const float*)d_in[8],  (const float*)d_in[14], (const float*)d_in[20], (const float*)d_in[26]};
    const float* g_wr[4]   = {(const float*)d_in[9],  (const float*)d_in[15], (const float*)d_in[21], (const float*)d_in[27]};
    const float* g_br[4]   = {(const float*)d_in[10], (const float*)d_in[16], (const float*)d_in[22], (const float*)d_in[28]};
    const float* g_att[4]  = {(const float*)d_in[11], (const float*)d_in[17], (const float*)d_in[23], (const float*)d_in[29]};
    const float* g_bias[4] = {(const float*)d_in[12], (const float*)d_in[18], (const float*)d_in[24], (const float*)d_in[30]};

    float* ws = (float*)d_ws;
    size_t off = 0;
    float* emb1  = ws + off; off += 2359296;                  // [9216][256] f32 (persists)
    size_t emb_off = off;
    float* emb   = ws + off; off += 2359296;
    u16*   emb_h = (u16*)(ws + off); off += 1179648;          // [9216][256] bf16
    u16*   emb_l = (u16*)(ws + off); off += 1179648;
    u16*   Wt[4];
    Wt[0] = (u16*)(ws + off); off += 524288;                  // [4096][256] bf16
    Wt[1] = (u16*)(ws + off); off += 524288;                  // [512][2048] bf16
    Wt[2] = (u16*)(ws + off); off += 524288;
    Wt[3] = (u16*)(ws + off); off += 524288;
    u16*   WtF  = (u16*)(ws + off); off += 65536;             // [256][512] bf16 (fc3)
    u64*   apk  = (u64*)(ws + off); off += 7962624;           // [9216][432] u64 keys
    int*   c8i  = (int*)(ws + off); off += 73728;             // [9216][8]
    float* vals = ws + off; off += 27648;
    int*   idx  = (int*)(ws + off); off += 27648;
    u16*   hcat = (u16*)(ws + off); off += 2359296;           // [9216][512] bf16 (g2|g4)
    float* h4   = ws + off; off += 2359296;                   // [9216][256] f32 (residual)
    u16*   xlxr = (u16*)(ws + off); off += 18874368;          // [9216][4096] u16
    u16*   hbig = (u16*)(ws + off); off += 9437184;           // [9216][2048] u16
    u16*   WbH  = (u16*)(ws + off); off += 851968;            // [256][6400] bf16 (conv W split)
    u16*   WbL  = (u16*)(ws + off); off += 851968;
    // conv-phase scratch, aliased onto post-conv region starting at emb
    u16*   xp_h = (u16*)(ws + emb_off);                          // [4608][6400] u16
    u16*   xp_l = (u16*)(ws + emb_off + 14745600);
    float* cpart = ws + emb_off + 29491200;                      // [4][4608][256] f32
    size_t need = off * sizeof(float);
    if (ws_size < need) {
        hipMemsetAsync(d_out, 0, (size_t)out_size*sizeof(float), stream);
        return;
    }
    float* out = (float*)d_out;

    // conv1 = bf16-split-3-term NT GEMM over im2col'd x (two row-halves, K-split x4).
    cvt_hilo<<<1600,256,0,stream>>>(conv_w, WbH, WbL, 409600);
    for (int half = 0; half < 2; ++half) {
        xpb_build<<<12288,256,0,stream>>>(x, half*4608, xp_h, xp_l);
        mm_conv<<<dim3(36,2,4),256,0,stream>>>(xp_h, xp_l, 6400, WbH, WbL, 6400, cpart, 1600);
        conv_reduce2<<<1152,256,0,stream>>>(cpart, conv_b, emb1 + (size_t)half*4608*256);
    }
    // fc2 fp32 -> emb (exact; feeds graph + rescore)
    gemm_f32<1><<<dim3(72,4),256,0,stream>>>(emb1,256,256, emb1,256, fc2_w, fc2_b, nullptr, emb, 9216,256,256);

    // conversions: emb -> hi/lo ; weights -> transposed bf16
    cvt_hilo<<<2304,256,0,stream>>>(emb, emb_h, emb_l, 589824);
    transpose_cvt<<<dim3(8,64),256,0,stream>>>(g_wl[0], 256, 2048, Wt[0]);
    transpose_cvt<<<dim3(8,64),256,0,stream>>>(g_wr[0], 256, 2048, Wt[0] + (size_t)2048*256);
    transpose_cvt<<<dim3(64,8),256,0,stream>>>(g_wl[1], 2048, 256, Wt[1]);
    transpose_cvt<<<dim3(64,8),256,0,stream>>>(g_wr[1], 2048, 256, Wt[1] + (size_t)256*2048);
    transpose_cvt<<<dim3(8,64),256,0,stream>>>(g_wl[2], 256, 2048, Wt[2]);
    transpose_cvt<<<dim3(8,64),256,0,stream>>>(g_wr[2], 256, 2048, Wt[2] + (size_t)2048*256);
    transpose_cvt<<<dim3(64,8),256,0,stream>>>(g_wl[3], 2048, 256, Wt[3]);
    transpose_cvt<<<dim3(64,8),256,0,stream>>>(g_wr[3], 2048, 256, Wt[3] + (size_t)256*2048);
    transpose_cvt<<<dim3(16,8),256,0,stream>>>(fc3_w, 512, 256, WtF);

    // similarity kNN: 1-term bf16 candidates -> packed-key merge -> exact rescore.
    mm_adj<<<dim3(72,72),256,0,stream>>>(emb_h, 256, apk);
    adj_merge8<<<2304,256,0,stream>>>(apk, c8i);
    rescore_select<<<2304,256,0,stream>>>(emb, c8i, vals, idx);

    // g1 (H=8, similarity graph)
    mm_proj<<<dim3(72,32),256,0,stream>>>(emb_h, 256, Wt[0], 256, g_bl[0], g_br[0], 2048,
                                          xlxr, 4096, 256);
    gat_agg<8,32,false><<<9216,256,0,stream>>>(xlxr, 4096, 2048, g_att[0], g_bias[0], vals, idx,
                                               hbig, 2048, nullptr, 0);
    // g2 (H=1) -> hcat cols 0..255 (bf16 only)
    mm_proj<<<dim3(72,4),256,0,stream>>>(hbig, 2048, Wt[1], 2048, g_bl[1], g_br[1], 256,
                                         xlxr, 512, 2048);
    gat_agg<1,64,false><<<9216,64,0,stream>>>(xlxr, 512, 256, g_att[1], g_bias[1], vals, idx,
                                              hcat, 512, nullptr, 0);
    // g3 (H=8, spatial graph)
    mm_proj<<<dim3(72,32),256,0,stream>>>(emb_h, 256, Wt[2], 256, g_bl[2], g_br[2], 2048,
                                          xlxr, 4096, 256);
    gat_agg<8,32,true><<<9216,256,0,stream>>>(xlxr, 4096, 2048, g_att[2], g_bias[2], nullptr, nullptr,
                                              hbig, 2048, nullptr, 0);
    // g4 (H=1) -> hcat cols 256..511 (bf16) + h4 f32 (exact residual)
    mm_proj<<<dim3(72,4),256,0,stream>>>(hbig, 2048, Wt[3], 2048, g_bl[3], g_br[3], 256,
                                         xlxr, 512, 2048);
    gat_agg<1,64,true><<<9216,64,0,stream>>>(xlxr, 512, 256, g_att[3], g_bias[3], nullptr, nullptr,
                                             hcat + 256, 512, h4, 256);

    // fc3 via bf16 MFMA: out = relu(hcat @ WtF^T + b) + h4
    mm_fc3<<<dim3(72,2),256,0,stream>>>(hcat, 512, WtF, 512, fc3_b, h4, out);
}

// Round 19
// 804.496 us; speedup vs baseline: 1.5409x; 1.0079x over previous
//
#include <hip/hip_runtime.h>
#include <cstdint>
#include <cstddef>

#define NEG_INF (-3.402823466e38f)
typedef unsigned short u16;
typedef unsigned int u32;
typedef unsigned long long u64;

typedef short s16x8 __attribute__((ext_vector_type(8)));
typedef __bf16 bf16x8_t __attribute__((ext_vector_type(8)));
typedef float f32x4 __attribute__((ext_vector_type(4)));

__device__ __forceinline__ f32x4 mfma_bf16(s16x8 a, s16x8 b, f32x4 c){
    return __builtin_amdgcn_mfma_f32_16x16x32_bf16(
        __builtin_bit_cast(bf16x8_t, a), __builtin_bit_cast(bf16x8_t, b), c, 0, 0, 0);
}
__device__ __forceinline__ float b2f(u16 u){ return __uint_as_float(((u32)u) << 16); }
__device__ __forceinline__ u16 f2bu(float f){           // RNE fp32 -> bf16 bits
    u32 u = __float_as_uint(f);
    return (u16)((u + 0x7fffu + ((u >> 16) & 1u)) >> 16);
}
// async global->LDS, 16B/lane; LDS dest = wave-uniform base + lane*16 (m97 pattern)
__device__ __forceinline__ void gload16(const u16* __restrict__ g, u16* l){
    __builtin_amdgcn_global_load_lds(
        (const __attribute__((address_space(1))) u32*)g,
        (__attribute__((address_space(3))) u32*)l, 16, 0, 0);
}
// monotone (val desc, idx asc) <-> u64 key desc ; keys unique (idx unique), > 0
__device__ __forceinline__ u64 mkkey(float v, int id){
    u32 s = __float_as_uint(v);
    s ^= (u32)(((int)s >> 31)) | 0x80000000u;
    return ((u64)s << 32) | (u32)(~(u32)id);
}

// ---------------- top-k helpers (JAX lax.top_k stable: val desc, idx asc on ties) ----
__device__ __forceinline__ bool tk_gt(float v, int i, float w, int j){
    return (v > w) || (v == w && i < j);
}
__device__ __forceinline__ void tk_insert(float v, int id, float tv[3], int ti[3]){
    if (!tk_gt(v, id, tv[2], ti[2])) return;
    if (tk_gt(v, id, tv[1], ti[1])) {
        tv[2]=tv[1]; ti[2]=ti[1];
        if (tk_gt(v, id, tv[0], ti[0])) { tv[1]=tv[0]; ti[1]=ti[0]; tv[0]=v; ti[0]=id; }
        else { tv[1]=v; ti[1]=id; }
    } else { tv[2]=v; ti[2]=id; }
}

// ---------------- conversion pre-passes --------------------------------------------
__global__ void cvt_hi(const float* __restrict__ in, u16* __restrict__ hi, int n4)
{
    int i = blockIdx.x * 256 + threadIdx.x;
    if (i >= n4) return;
    float4 v = ((const float4*)in)[i];
    u16 h[4] = {f2bu(v.x), f2bu(v.y), f2bu(v.z), f2bu(v.w)};
    *(ushort4*)&hi[i*4] = *(ushort4*)h;
}
__global__ void cvt_hilo(const float* __restrict__ in, u16* __restrict__ hi,
                         u16* __restrict__ lo, int n4)
{
    int i = blockIdx.x * 256 + threadIdx.x;
    if (i >= n4) return;
    float4 v = ((const float4*)in)[i];
    u16 h[4], l[4];
    float f[4] = {v.x, v.y, v.z, v.w};
#pragma unroll
    for (int j=0;j<4;j++){
        u16 hb = f2bu(f[j]);
        h[j] = hb;
        l[j] = f2bu(f[j] - b2f(hb));
    }
    *(ushort4*)&hi[i*4] = *(ushort4*)h;
    *(ushort4*)&lo[i*4] = *(ushort4*)l;
}

// im2col + bf16-split, READ-COALESCED (R17). One block per (channel, patch-row).
__global__ __launch_bounds__(256)
void xpb_build(const float* __restrict__ x, int base,
               u16* __restrict__ xh, u16* __restrict__ xl)
{
    __shared__ u16 lh[96*26], ll[96*26];
    const int c = blockIdx.x / 48;
    const int piL = blockIdx.x - c*48;
    const int pi = (base/96) + piL;
    const int tid = threadIdx.x;

    for (int e = tid; e < 600; e += 256){
        int r = e / 120, col4 = e - r*120;
        float4 v = *(const float4*)(x + (size_t)c*230400 + (size_t)(pi*5+r)*480 + col4*4);
        float f[4] = {v.x, v.y, v.z, v.w};
#pragma unroll
        for (int j=0;j<4;j++){
            int col = col4*4 + j;
            int pj = col / 5, jj = col - pj*5;
            u16 hb = f2bu(f[j]);
            int lo = pj*26 + r*5 + jj;
            lh[lo] = hb;
            ll[lo] = f2bu(f[j] - b2f(hb));
        }
    }
    __syncthreads();
    for (int e = tid; e < 2400; e += 256){
        int pj = e / 25, kk = e - pj*25;
        size_t go = (size_t)(piL*96 + pj)*6400 + c*25 + kk;
        xh[go] = lh[pj*26 + kk];
        xl[go] = ll[pj*26 + kk];
    }
}

// sum 4 K-split partials + bias + relu -> emb1 as bf16 hi/lo (R19: feeds fc2 MFMA)
__global__ void conv_reduce2(const float* __restrict__ p, const float* __restrict__ bias,
                             u16* __restrict__ oh, u16* __restrict__ ol)
{
    int i = blockIdx.x * 256 + threadIdx.x;
    const float4* p4 = (const float4*)p;
    float4 s = p4[i];
#pragma unroll
    for (int j=1;j<4;j++){
        float4 v = p4[i + (size_t)j*294912];
        s.x += v.x; s.y += v.y; s.z += v.z; s.w += v.w;
    }
    float4 bb = ((const float4*)bias)[i & 63];
    float f[4] = {fmaxf(s.x+bb.x,0.f), fmaxf(s.y+bb.y,0.f),
                  fmaxf(s.z+bb.z,0.f), fmaxf(s.w+bb.w,0.f)};
    u16 h[4], l[4];
#pragma unroll
    for (int j=0;j<4;j++){
        u16 hb = f2bu(f[j]);
        h[j] = hb;
        l[j] = f2bu(f[j] - b2f(hb));
    }
    *(ushort4*)&oh[i*4] = *(ushort4*)h;
    *(ushort4*)&ol[i*4] = *(ushort4*)l;
}

// fp32 [K][N] row-major -> bf16 out[N][K]
__global__ __launch_bounds__(256)
void transpose_cvt(const float* __restrict__ in, int K, int N, u16* __restrict__ out)
{
    __shared__ float t[32][33];
    const int kb = blockIdx.x * 32, nb = blockIdx.y * 32;
    const int tx = threadIdx.x & 31, ty = threadIdx.x >> 5;   // 32 x 8
#pragma unroll
    for (int r=0;r<4;r++)
        t[ty + r*8][tx] = in[(size_t)(kb + ty + r*8)*N + nb + tx];
    __syncthreads();
#pragma unroll
    for (int r=0;r<4;r++)
        out[(size_t)(nb + ty + r*8)*K + kb + tx] = f2bu(t[tx][ty + r*8]);
}
// fp32 [K][N] -> bf16 hi/lo [N][K] (fc2 weights)
__global__ __launch_bounds__(256)
void transpose_cvt_hilo(const float* __restrict__ in, int K, int N,
                        u16* __restrict__ outh, u16* __restrict__ outl)
{
    __shared__ float t[32][33];
    const int kb = blockIdx.x * 32, nb = blockIdx.y * 32;
    const int tx = threadIdx.x & 31, ty = threadIdx.x >> 5;
#pragma unroll
    for (int r=0;r<4;r++)
        t[ty + r*8][tx] = in[(size_t)(kb + ty + r*8)*N + nb + tx];
    __syncthreads();
#pragma unroll
    for (int r=0;r<4;r++){
        float v = t[tx][ty + r*8];
        u16 hb = f2bu(v);
        outh[(size_t)(nb + ty + r*8)*K + kb + tx] = hb;
        outl[(size_t)(nb + ty + r*8)*K + kb + tx] = f2bu(v - b2f(hb));
    }
}

// ---------------- bf16 MFMA NT GEMM core: C[M][N] = A[M][K] @ B[N][K]^T ------------
// 128x128 tile, BK=32, global_load_lds staging, linear LDS [128][32].
// EPI 0: bf16 store. EPI 1: swapped-operand top-3 packed keys. EPI 2: conv K-split
// f32 partials. EPI 3: f32 relu(acc+bias)+add (fc3). EPI 4: f32 relu(acc+bias) (fc2).
// SWAPG: n-tile on blockIdx.x (consecutive blocks share the A slab via L2).
template<bool SPLIT, int EPI, bool SWAPG>
__device__ __forceinline__
void mm_core(const u16* __restrict__ Ah, const u16* __restrict__ Al, int lda,
             const u16* __restrict__ Bh, const u16* __restrict__ Bl, int ldb,
             const float* __restrict__ bias0, const float* __restrict__ bias1, int nHalf,
             void* __restrict__ Cout, int ldc, int K,
             u64* __restrict__ apk)
{
    constexpr int TSZ = 128 * 32;
    __shared__ u16 smem[(SPLIT ? 4 : 2) * TSZ];
    u16* AsH = smem;
    u16* BsH = smem + TSZ;
    u16* AsL = SPLIT ? smem + 2*TSZ : nullptr;
    u16* BsL = SPLIT ? smem + 3*TSZ : nullptr;

    const int tid = threadIdx.x;
    const int w = tid >> 6, ln = tid & 63;
    const int wr = w >> 1, wc = w & 1;
    const int fr = ln & 15, fq = ln >> 4;
    const int mb = (SWAPG ? blockIdx.y : blockIdx.x) * 128;
    const int nb = (SWAPG ? blockIdx.x : blockIdx.y) * 128;
    const int skk = (ln & 3) * 8;

    int kbeg = 0;
    if constexpr (EPI == 2) kbeg = blockIdx.z * K;
    const int kend = kbeg + K;

    f32x4 acc[4][4];
#pragma unroll
    for (int i=0;i<4;i++)
#pragma unroll
        for (int j=0;j<4;j++) acc[i][j] = (f32x4){0.f,0.f,0.f,0.f};

    for (int k0 = kbeg; k0 < kend; k0 += 32) {
#pragma unroll
        for (int t=0;t<2;t++){
            int rbase = w*32 + t*16;
            int r = rbase + (ln >> 2);
            size_t goA = (size_t)(mb + r)*lda + k0 + skk;
            size_t goB = (size_t)(nb + r)*ldb + k0 + skk;
            gload16(Ah + goA, AsH + rbase*32);
            gload16(Bh + goB, BsH + rbase*32);
            if constexpr (SPLIT){
                gload16(Al + goA, AsL + rbase*32);
                gload16(Bl + goB, BsL + rbase*32);
            }
        }
        __syncthreads();
        s16x8 ah[4], bh[4], al[4], bl[4];
#pragma unroll
        for (int mi=0;mi<4;mi++){
            int ro = (wr*64 + mi*16 + fr)*32 + fq*8;
            ah[mi] = *(const s16x8*)&AsH[ro];
            if constexpr (SPLIT) al[mi] = *(const s16x8*)&AsL[ro];
        }
#pragma unroll
        for (int nj=0;nj<4;nj++){
            int ro = (wc*64 + nj*16 + fr)*32 + fq*8;
            bh[nj] = *(const s16x8*)&BsH[ro];
            if constexpr (SPLIT) bl[nj] = *(const s16x8*)&BsL[ro];
        }
#pragma unroll
        for (int mi=0;mi<4;mi++)
#pragma unroll
            for (int nj=0;nj<4;nj++){
                acc[mi][nj] = mfma_bf16(ah[mi], bh[nj], acc[mi][nj]);
                if constexpr (SPLIT){
                    acc[mi][nj] = mfma_bf16(ah[mi], bl[nj], acc[mi][nj]);
                    acc[mi][nj] = mfma_bf16(al[mi], bh[nj], acc[mi][nj]);
                }
            }
        __syncthreads();
    }

    if constexpr (EPI == 0) {
        u16* ldsc = smem;
#pragma unroll
        for (int chunk=0; chunk<4; ++chunk){
            __syncthreads();
            if (wr == (chunk>>1)){
                int mi0 = (chunk&1)*2;
#pragma unroll
                for (int m2=0;m2<2;m2++){
                    int mi = mi0 + m2;
#pragma unroll
                    for (int nj=0;nj<4;nj++)
#pragma unroll
                    for (int t=0;t<4;t++){
                        int lr = m2*16 + fq*4 + t;
                        int lc = wc*64 + nj*16 + fr;
                        int col = nb + lc;
                        float v = acc[mi][nj][t];
                        if (bias0) v += (col < nHalf) ? bias0[col] : bias1[col - nHalf];
                        ldsc[lr*136 + lc] = f2bu(v);
                    }
                }
            }
            __syncthreads();
            int c0 = chunk*32;
#pragma unroll
            for (int q=0;q<2;q++){
                int e = q*256 + tid;
                int lr = e >> 4, c16 = e & 15;
                *(uint4*)((u16*)Cout + (size_t)(mb + c0 + lr)*ldc + nb + c16*8)
                    = *(const uint4*)&ldsc[lr*136 + c16*8];
            }
        }
    } else if constexpr (EPI == 2 || EPI == 3 || EPI == 4) {
        float* ldsf = (float*)smem;
        const int NC = (EPI == 2) ? 256 : ldc;
#pragma unroll
        for (int chunk=0; chunk<8; ++chunk){
            __syncthreads();
            if (wr == (chunk>>2)){
                int mi = chunk & 3;
#pragma unroll
                for (int nj=0;nj<4;nj++)
#pragma unroll
                for (int t=0;t<4;t++){
                    int lr = fq*4 + t;
                    int lc = wc*64 + nj*16 + fr;
                    float v = acc[mi][nj][t];
                    if constexpr (EPI == 3 || EPI == 4){
                        v += bias0[nb + lc];
                        v = fmaxf(v, 0.f);
                    }
                    ldsf[lr*132 + lc] = v;
                }
            }
            __syncthreads();
            int c0 = chunk*16;
#pragma unroll
            for (int q=0;q<2;q++){
                int e = q*256 + tid;
                int lr = e >> 5, c4 = e & 31;
                int row = mb + c0 + lr, col = nb + c4*4;
                if constexpr (EPI == 3){
                    float4 a = *(const float4*)(bias1 + (size_t)row*NC + col);
                    float4 v = *(const float4*)&ldsf[lr*132 + c4*4];
                    v.x += a.x; v.y += a.y; v.z += a.z; v.w += a.w;
                    *(float4*)((float*)Cout + (size_t)row*NC + col) = v;
                } else if constexpr (EPI == 4){
                    *(float4*)((float*)Cout + (size_t)row*NC + col)
                        = *(const float4*)&ldsf[lr*132 + c4*4];
                } else {
                    *(float4*)((float*)Cout + ((size_t)blockIdx.z*4608 + row)*256 + col)
                        = *(const float4*)&ldsf[lr*132 + c4*4];
                }
            }
        }
    } else {
        // swapped-selection: adj row = B-side (nb + wc*64 + nj*16 + fr); c = A-side.
        const int cbR = blockIdx.x * 2 + wr;
#pragma unroll
        for (int nj=0;nj<4;nj++){
            int row = nb + wc*64 + nj*16 + fr;
            float tv[3] = {NEG_INF, NEG_INF, NEG_INF};
            int   ti[3] = {0x7fffffff, 0x7fffffff, 0x7fffffff};
#pragma unroll
            for (int mi=0;mi<4;mi++)
#pragma unroll
                for (int t=0;t<4;t++)
                    tk_insert(acc[mi][nj][t], mb + wr*64 + mi*16 + fq*4 + t, tv, ti);
#pragma unroll
            for (int off=16; off<64; off<<=1){
                float ov[3]; int oi[3];
#pragma unroll
                for (int e=0;e<3;e++){ ov[e]=__shfl_xor(tv[e],off); oi[e]=__shfl_xor(ti[e],off); }
#pragma unroll
                for (int e=0;e<3;e++) tk_insert(ov[e], oi[e], tv, ti);
            }
            if (fq == 0){
#pragma unroll
                for (int e=0;e<3;e++)
                    apk[(size_t)row*432 + cbR*3 + e] = mkkey(tv[e], ti[e]);
            }
        }
    }
}

// named instantiations (distinct rocprof rows)
__global__ __launch_bounds__(256)
void mm_proj(const u16* Ah, int lda, const u16* Bh, int ldb,
             const float* bias0, const float* bias1, int nHalf,
             void* Cout, int ldc, int K)
{
    mm_core<false,0,false>(Ah, nullptr, lda, Bh, nullptr, ldb, bias0, bias1, nHalf,
                           Cout, ldc, K, nullptr);
}
__global__ __launch_bounds__(256)
void mm_projT(const u16* Ah, int lda, const u16* Bh, int ldb,
              const float* bias0, const float* bias1, int nHalf,
              void* Cout, int ldc, int K)
{
    mm_core<false,0,true>(Ah, nullptr, lda, Bh, nullptr, ldb, bias0, bias1, nHalf,
                          Cout, ldc, K, nullptr);
}
__global__ __launch_bounds__(256)
void mm_adj(const u16* Ah, int lda, u64* apk)
{
    mm_core<false,1,false>(Ah, nullptr, lda, Ah, nullptr, lda, nullptr, nullptr, 0,
                           nullptr, 0, 256, apk);
}
__global__ __launch_bounds__(256)
void mm_conv(const u16* Ah, const u16* Al, int lda, const u16* Bh, const u16* Bl, int ldb,
             float* Cout, int K)
{
    mm_core<true,2,false>(Ah, Al, lda, Bh, Bl, ldb, nullptr, nullptr, 0,
                          Cout, 256, K, nullptr);
}
// fc2: emb = relu(emb1 @ W2t^T + b), split-bf16 3-term, f32 out ld 256
__global__ __launch_bounds__(256)
void mm_fc2(const u16* Ah, const u16* Al, const u16* Bh, const u16* Bl,
            const float* bias, float* Cout)
{
    mm_core<true,4,false>(Ah, Al, 256, Bh, Bl, 256, bias, nullptr, 0,
                          Cout, 256, 256, nullptr);
}
// fc3: out = relu(hcat @ WtF^T + bias) + add ; f32 out, ld 256
__global__ __launch_bounds__(256)
void mm_fc3(const u16* Ah, int lda, const u16* Bh, int ldb,
            const float* bias, const float* add, float* Cout)
{
    mm_core<false,3,false>(Ah, nullptr, lda, Bh, nullptr, ldb, bias, add, 0,
                           Cout, 256, 512, nullptr);
}

// merge: 432 packed keys per row -> top-8, ONE WAVE PER ROW (sort-network + head-pop).
__device__ __forceinline__ void ce_desc(u64& a, u64& b){
    u64 mx = a > b ? a : b; u64 mn = a > b ? b : a; a = mx; b = mn;
}
__global__ __launch_bounds__(256)
void adj_merge8(const u64* __restrict__ apk, int* __restrict__ c8i)
{
    int row = blockIdx.x * 4 + (threadIdx.x >> 6);
    int ln = threadIdx.x & 63;
    u64 k[7];
#pragma unroll
    for (int j=0;j<7;j++){
        int t = ln + 64*j;
        k[j] = (t < 432) ? apk[(size_t)row*432 + t] : 0ull;
    }
    ce_desc(k[0],k[6]); ce_desc(k[2],k[3]); ce_desc(k[4],k[5]);
    ce_desc(k[0],k[2]); ce_desc(k[1],k[4]); ce_desc(k[3],k[6]);
    ce_desc(k[0],k[1]); ce_desc(k[2],k[5]); ce_desc(k[3],k[4]);
    ce_desc(k[1],k[2]); ce_desc(k[4],k[6]);
    ce_desc(k[2],k[3]); ce_desc(k[4],k[5]);
    ce_desc(k[1],k[2]); ce_desc(k[3],k[4]); ce_desc(k[5],k[6]);
#pragma unroll
    for (int r=0;r<8;r++){
        u64 m = k[0];
#pragma unroll
        for (int off=1; off<64; off<<=1){
            u64 o = __shfl_xor((unsigned long long)m, off);
            m = o > m ? o : m;
        }
        if (k[0] == m){
            k[0]=k[1]; k[1]=k[2]; k[2]=k[3]; k[3]=k[4]; k[4]=k[5]; k[5]=k[6]; k[6]=0ull;
        }
        if (ln == 0) c8i[row*8 + r] = (int)(~(u32)(m & 0xFFFFFFFFull));
    }
}

// exact fp32 rescore of 8 candidates per row, final top-3 (lax.top_k semantics).
__global__ __launch_bounds__(256)
void rescore_select(const float* __restrict__ emb, const int* __restrict__ c8i,
                    float* __restrict__ vals, int* __restrict__ idx)
{
    int gid = blockIdx.x * 256 + threadIdx.x;
    int row = gid >> 6;
    int ln = threadIdx.x & 63;
    float a[4];
    *(float4*)a = *(const float4*)(emb + (size_t)row*256 + ln*4);
    float sc[8];
#pragma unroll
    for (int c=0;c<8;c++){
        int cand = c8i[row*8+c];
        float4 b = *(const float4*)(emb + (size_t)cand*256 + ln*4);
        float p = a[0]*b.x + a[1]*b.y + a[2]*b.z + a[3]*b.w;
#pragma unroll
        for (int off=1; off<64; off<<=1) p += __shfl_xor(p, off);
        sc[c] = p;
    }
    if (ln == 0){
        float tv[3]={NEG_INF,NEG_INF,NEG_INF};
        int   ti[3]={0x7fffffff,0x7fffffff,0x7fffffff};
#pragma unroll
        for (int c=0;c<8;c++) tk_insert(sc[c], c8i[row*8+c], tv, ti);
#pragma unroll
        for (int e=0;e<3;e++){ vals[row*3+e]=tv[e]; idx[row*3+e]=ti[e]; }
    }
}

// ---------------- GATv2 softmax + aggregate + bias + ELU, bf16 inputs --------------
template<int H, int TPH, bool SPATIAL>
__global__ __launch_bounds__(H*TPH)
void gat_agg(const u16* __restrict__ xlxr, int ldx, int xrOff,
             const float* __restrict__ att, const float* __restrict__ bias,
             const float* __restrict__ vals, const int* __restrict__ idx,
             u16* __restrict__ outp, int ldo,
             float* __restrict__ out2, int ldo2)
{
    constexpr int D = 256;
    constexpr int DPT = D / TPH;
    const int n = blockIdx.x;
    const int tid = threadIdx.x;
    const int h = tid / TPH;
    const int l = tid % TPH;
    const int d0 = l * DPT;

    int srcs[4]; bool valid[4];
#pragma unroll
    for (int s=0;s<4;s++){ srcs[s]=n; valid[s]=(s==3); }
    if constexpr (SPATIAL) {
        int pi = n / 96, pj = n - (n/96)*96;
        int cand[4]; int nc=0;
        if (pi > 0)  cand[nc++] = n - 96;
        if (pj > 0)  cand[nc++] = n - 1;
        if (pj < 95) cand[nc++] = n + 1;
        if (pi < 95) cand[nc++] = n + 96;
        int s0 = cand[0], s1 = cand[1];
        if (s0 > n){ srcs[0]=s0; valid[0]=true; }
        if (s1 > n){ srcs[1]=s1; valid[1]=true; }
    } else {
#pragma unroll
        for (int t=0;t<3;t++){
            int s = idx[n*3+t];
            float v = vals[n*3+t];
            if (s > n && v != 0.0f){ srcs[t]=s; valid[t]=true; }
        }
    }

    float xrv[DPT], attv[DPT];
#pragma unroll
    for (int q=0;q<DPT/4;q++){
        ushort4 u = *(const ushort4*)(xlxr + (size_t)n*ldx + xrOff + h*D + d0 + q*4);
        xrv[q*4+0]=b2f(u.x); xrv[q*4+1]=b2f(u.y); xrv[q*4+2]=b2f(u.z); xrv[q*4+3]=b2f(u.w);
        *(float4*)&attv[q*4] = *(const float4*)(att + h*D + d0 + q*4);
    }

    float xs[4][DPT];
    float sc[4];
#pragma unroll
    for (int s=0;s<4;s++){
#pragma unroll
        for (int q=0;q<DPT/4;q++){
            ushort4 u = *(const ushort4*)(xlxr + (size_t)srcs[s]*ldx + h*D + d0 + q*4);
            xs[s][q*4+0]=b2f(u.x); xs[s][q*4+1]=b2f(u.y); xs[s][q*4+2]=b2f(u.z); xs[s][q*4+3]=b2f(u.w);
        }
        float p = 0.f;
#pragma unroll
        for (int d=0;d<DPT;d++){
            float e = xs[s][d] + xrv[d];
            e = (e > 0.f) ? e : 0.2f*e;
            p += attv[d]*e;
        }
#pragma unroll
        for (int off=1; off<TPH; off<<=1) p += __shfl_xor(p, off);
        sc[s] = p;
    }
    float m = NEG_INF;
#pragma unroll
    for (int s=0;s<4;s++) if (valid[s]) m = fmaxf(m, sc[s]);
    float al[4]; float denom = 0.f;
#pragma unroll
    for (int s=0;s<4;s++){ al[s] = valid[s] ? expf(sc[s]-m) : 0.f; denom += al[s]; }
    float inv = 1.f / denom;

    float o[DPT];
#pragma unroll
    for (int d=0;d<DPT;d++){
        float acc = al[0]*xs[0][d] + al[1]*xs[1][d] + al[2]*xs[2][d] + al[3]*xs[3][d];
        acc = acc*inv + bias[h*D + d0 + d];
        o[d] = (acc > 0.f) ? acc : (expf(acc) - 1.f);
    }
    u16 ov[DPT];
#pragma unroll
    for (int d=0;d<DPT;d++) ov[d] = f2bu(o[d]);
    if constexpr (DPT >= 8){
#pragma unroll
        for (int q=0;q<DPT/8;q++)
            *(uint4*)(outp + (size_t)n*ldo + h*D + d0 + q*8) = *(uint4*)&ov[q*8];
    } else {
        *(uint2*)(outp + (size_t)n*ldo + h*D + d0) = *(uint2*)ov;
    }
    if (out2){
#pragma unroll
        for (int q=0;q<DPT/4;q++)
            *(float4*)(out2 + (size_t)n*ldo2 + h*D + d0 + q*4) = *(float4*)&o[q*4];
    }
}

// ---------------------------------------------------------------------------
extern "C" void kernel_launch(void* const* d_in, const int* in_sizes, int n_in,
                              void* d_out, int out_size, void* d_ws, size_t ws_size,
                              hipStream_t stream)
{
    (void)in_sizes; (void)n_in;
    const float* x      = (const float*)d_in[0];
    const float* conv_w = (const float*)d_in[1];
    const float* conv_b = (const float*)d_in[2];
    const float* fc2_w  = (const float*)d_in[3];
    const float* fc2_b  = (const float*)d_in[4];
    const float* fc3_w  = (const float*)d_in[5];
    const float* fc3_b  = (const float*)d_in[6];
    const float* g_wl[4]   = {(const float*)d_in[7],  (const float*)d_in[13], (const float*)d_in[19], (const float*)d_in[25]};
    const float* g_bl[4]   = {(const float*)d_in[8],  (const float*)d_in[14], (const float*)d_in[20], (const float*)d_in[26]};
    const float* g_wr[4]   = {(const float*)d_in[9],  (const float*)d_in[15], (const float*)d_in[21], (const float*)d_in[27]};
    const float* g_br[4]   = {(const float*)d_in[10], (const float*)d_in[16], (const float*)d_in[22], (const float*)d_in[28]};
    const float* g_att[4]  = {(const float*)d_in[11], (const float*)d_in[17], (const float*)d_in[23], (const float*)d_in[29]};
    const float* g_bias[4] = {(const float*)d_in[12], (const float*)d_in[18], (const float*)d_in[24], (const float*)d_in[30]};

    float* ws = (float*)d_ws;
    size_t off = 0;
    u16*   e1h  = (u16*)(ws + off); off += 1179648;           // [9216][256] bf16 hi (persists)
    u16*   e1l  = (u16*)(ws + off); off += 1179648;           // [9216][256] bf16 lo
    size_t emb_off = off;
    float* emb   = ws + off; off += 2359296;
    u16*   emb_h = (u16*)(ws + off); off += 1179648;          // [9216][256] bf16
    u16*   Wt[4];
    Wt[0] = (u16*)(ws + off); off += 524288;                  // [4096][256] bf16
    Wt[1] = (u16*)(ws + off); off += 524288;                  // [512][2048] bf16
    Wt[2] = (u16*)(ws + off); off += 524288;
    Wt[3] = (u16*)(ws + off); off += 524288;
    u16*   WtF  = (u16*)(ws + off); off += 65536;             // [256][512] bf16 (fc3)
    u16*   W2h  = (u16*)(ws + off); off += 32768;             // [256][256] bf16 (fc2 hi)
    u16*   W2l  = (u16*)(ws + off); off += 32768;             // [256][256] bf16 (fc2 lo)
    u64*   apk  = (u64*)(ws + off); off += 7962624;           // [9216][432] u64 keys
    int*   c8i  = (int*)(ws + off); off += 73728;             // [9216][8]
    float* vals = ws + off; off += 27648;
    int*   idx  = (int*)(ws + off); off += 27648;
    u16*   hcat = (u16*)(ws + off); off += 2359296;           // [9216][512] bf16 (g2|g4)
    float* h4   = ws + off; off += 2359296;                   // [9216][256] f32 (residual)
    u16*   xlxr = (u16*)(ws + off); off += 18874368;          // [9216][4096] u16
    u16*   hbig = (u16*)(ws + off); off += 9437184;           // [9216][2048] u16
    u16*   WbH  = (u16*)(ws + off); off += 851968;            // [256][6400] bf16 (conv W split)
    u16*   WbL  = (u16*)(ws + off); off += 851968;
    // conv-phase scratch, aliased onto post-conv region starting at emb
    u16*   xp_h = (u16*)(ws + emb_off);                          // [4608][6400] u16
    u16*   xp_l = (u16*)(ws + emb_off + 14745600);
    float* cpart = ws + emb_off + 29491200;                      // [4][4608][256] f32
    size_t need = off * sizeof(float);
    if (ws_size < need) {
        hipMemsetAsync(d_out, 0, (size_t)out_size*sizeof(float), stream);
        return;
    }
    float* out = (float*)d_out;

    // conv1 = bf16-split-3-term NT GEMM over im2col'd x (two row-halves, K-split x4);
    // reduce emits emb1 directly as bf16 hi/lo (feeds fc2 MFMA).
    cvt_hilo<<<1600,256,0,stream>>>(conv_w, WbH, WbL, 409600);
    for (int half = 0; half < 2; ++half) {
        xpb_build<<<12288,256,0,stream>>>(x, half*4608, xp_h, xp_l);
        mm_conv<<<dim3(36,2,4),256,0,stream>>>(xp_h, xp_l, 6400, WbH, WbL, 6400, cpart, 1600);
        conv_reduce2<<<1152,256,0,stream>>>(cpart, conv_b,
                                            e1h + (size_t)half*4608*256,
                                            e1l + (size_t)half*4608*256);
    }
    // fc2 via split-bf16 MFMA (err ~2e-5 rel, same pedigree as conv) -> emb f32
    transpose_cvt_hilo<<<dim3(8,8),256,0,stream>>>(fc2_w, 256, 256, W2h, W2l);
    mm_fc2<<<dim3(72,2),256,0,stream>>>(e1h, e1l, W2h, W2l, fc2_b, emb);

    // conversions: emb -> hi ; weights -> transposed bf16
    cvt_hi<<<2304,256,0,stream>>>(emb, emb_h, 589824);
    transpose_cvt<<<dim3(8,64),256,0,stream>>>(g_wl[0], 256, 2048, Wt[0]);
    transpose_cvt<<<dim3(8,64),256,0,stream>>>(g_wr[0], 256, 2048, Wt[0] + (size_t)2048*256);
    transpose_cvt<<<dim3(64,8),256,0,stream>>>(g_wl[1], 2048, 256, Wt[1]);
    transpose_cvt<<<dim3(64,8),256,0,stream>>>(g_wr[1], 2048, 256, Wt[1] + (size_t)256*2048);
    transpose_cvt<<<dim3(8,64),256,0,stream>>>(g_wl[2], 256, 2048, Wt[2]);
    transpose_cvt<<<dim3(8,64),256,0,stream>>>(g_wr[2], 256, 2048, Wt[2] + (size_t)2048*256);
    transpose_cvt<<<dim3(64,8),256,0,stream>>>(g_wl[3], 2048, 256, Wt[3]);
    transpose_cvt<<<dim3(64,8),256,0,stream>>>(g_wr[3], 2048, 256, Wt[3] + (size_t)256*2048);
    transpose_cvt<<<dim3(16,8),256,0,stream>>>(fc3_w, 512, 256, WtF);

    // similarity kNN: 1-term bf16 candidates -> packed-key merge -> exact rescore.
    mm_adj<<<dim3(72,72),256,0,stream>>>(emb_h, 256, apk);
    adj_merge8<<<2304,256,0,stream>>>(apk, c8i);
    rescore_select<<<2304,256,0,stream>>>(emb, c8i, vals, idx);

    // g1 (H=8, similarity graph)
    mm_proj<<<dim3(72,32),256,0,stream>>>(emb_h, 256, Wt[0], 256, g_bl[0], g_br[0], 2048,
                                          xlxr, 4096, 256);
    gat_agg<8,32,false><<<9216,256,0,stream>>>(xlxr, 4096, 2048, g_att[0], g_bias[0], vals, idx,
                                               hbig, 2048, nullptr, 0);
    // g2 (H=1) -> hcat cols 0..255 ; n-fastest grid so hbig slab L2-reuses
    mm_projT<<<dim3(4,72),256,0,stream>>>(hbig, 2048, Wt[1], 2048, g_bl[1], g_br[1], 256,
                                          xlxr, 512, 2048);
    gat_agg<1,64,false><<<9216,64,0,stream>>>(xlxr, 512, 256, g_att[1], g_bias[1], vals, idx,
                                              hcat, 512, nullptr, 0);
    // g3 (H=8, spatial graph)
    mm_proj<<<dim3(72,32),256,0,stream>>>(emb_h, 256, Wt[2], 256, g_bl[2], g_br[2], 2048,
                                          xlxr, 4096, 256);
    gat_agg<8,32,true><<<9216,256,0,stream>>>(xlxr, 4096, 2048, g_att[2], g_bias[2], nullptr, nullptr,
                                              hbig, 2048, nullptr, 0);
    // g4 (H=1) -> hcat cols 256..511 + h4 f32 (exact residual)
    mm_projT<<<dim3(4,72),256,0,stream>>>(hbig, 2048, Wt[3], 2048, g_bl[3], g_br[3], 256,
                                          xlxr, 512, 2048);
    gat_agg<1,64,true><<<9216,64,0,stream>>>(xlxr, 512, 256, g_att[3], g_bias[3], nullptr, nullptr,
                                             hcat + 256, 512, h4, 256);

    // fc3 via bf16 MFMA: out = relu(hcat @ WtF^T + b) + h4
    mm_fc3<<<dim3(72,2),256,0,stream>>>(hcat, 512, WtF, 512, fc3_b, h4, out);
}

// Round 21
// 802.099 us; speedup vs baseline: 1.5456x; 1.0030x over previous
//
#include <hip/hip_runtime.h>
#include <cstdint>
#include <cstddef>

#define NEG_INF (-3.402823466e38f)
typedef unsigned short u16;
typedef unsigned int u32;
typedef unsigned long long u64;

typedef short s16x8 __attribute__((ext_vector_type(8)));
typedef __bf16 bf16x8_t __attribute__((ext_vector_type(8)));
typedef float f32x4 __attribute__((ext_vector_type(4)));

__device__ __forceinline__ f32x4 mfma_bf16(s16x8 a, s16x8 b, f32x4 c){
    return __builtin_amdgcn_mfma_f32_16x16x32_bf16(
        __builtin_bit_cast(bf16x8_t, a), __builtin_bit_cast(bf16x8_t, b), c, 0, 0, 0);
}
__device__ __forceinline__ float b2f(u16 u){ return __uint_as_float(((u32)u) << 16); }
__device__ __forceinline__ u16 f2bu(float f){           // RNE fp32 -> bf16 bits
    u32 u = __float_as_uint(f);
    return (u16)((u + 0x7fffu + ((u >> 16) & 1u)) >> 16);
}
// async global->LDS, 16B/lane; LDS dest = wave-uniform base + lane*16 (m97 pattern)
__device__ __forceinline__ void gload16(const u16* __restrict__ g, u16* l){
    __builtin_amdgcn_global_load_lds(
        (const __attribute__((address_space(1))) u32*)g,
        (__attribute__((address_space(3))) u32*)l, 16, 0, 0);
}
// monotone (val desc, idx asc) <-> u64 key desc ; keys unique (idx unique), > 0
__device__ __forceinline__ u64 mkkey(float v, int id){
    u32 s = __float_as_uint(v);
    s ^= (u32)(((int)s >> 31)) | 0x80000000u;
    return ((u64)s << 32) | (u32)(~(u32)id);
}

// ---------------- top-k helpers (JAX lax.top_k stable: val desc, idx asc on ties) ----
__device__ __forceinline__ bool tk_gt(float v, int i, float w, int j){
    return (v > w) || (v == w && i < j);
}
__device__ __forceinline__ void tk_insert(float v, int id, float tv[3], int ti[3]){
    if (!tk_gt(v, id, tv[2], ti[2])) return;
    if (tk_gt(v, id, tv[1], ti[1])) {
        tv[2]=tv[1]; ti[2]=ti[1];
        if (tk_gt(v, id, tv[0], ti[0])) { tv[1]=tv[0]; ti[1]=ti[0]; tv[0]=v; ti[0]=id; }
        else { tv[1]=v; ti[1]=id; }
    } else { tv[2]=v; ti[2]=id; }
}

// ---------------- prep_all: all weight conversions in ONE launch --------------------
// block ranges: [0,1600) conv_w hilo split (flat); [1600,5696) 8 projection
// transposes (512 tiles each); [5696,5824) fc3 transpose; [5824,5888) fc2 hilo.
__device__ __forceinline__ void tc_tile(const float* in, int K, int N, u16* out,
                                        int bx, int by, int tid, float (*t)[33])
{
    const int kb = bx*32, nb = by*32;
    const int tx = tid & 31, ty = tid >> 5;
#pragma unroll
    for (int r=0;r<4;r++)
        t[ty + r*8][tx] = in[(size_t)(kb + ty + r*8)*N + nb + tx];
    __syncthreads();
#pragma unroll
    for (int r=0;r<4;r++)
        out[(size_t)(nb + ty + r*8)*K + kb + tx] = f2bu(t[tx][ty + r*8]);
}
__global__ __launch_bounds__(256)
void prep_all(const float* conv_w, u16* WbH, u16* WbL,
              const float* wl0, const float* wr0, const float* wl1, const float* wr1,
              const float* wl2, const float* wr2, const float* wl3, const float* wr3,
              u16* Wt0, u16* Wt1, u16* Wt2, u16* Wt3,
              const float* fc3_w, u16* WtF,
              const float* fc2_w, u16* W2h, u16* W2l)
{
    __shared__ float t[32][33];
    int b = blockIdx.x, tid = threadIdx.x;
    if (b < 1600) {                                   // conv_w split, flat float4
        int i = b*256 + tid;
        float4 v = ((const float4*)conv_w)[i];
        float f[4] = {v.x, v.y, v.z, v.w};
        u16 h[4], l[4];
#pragma unroll
        for (int j=0;j<4;j++){
            u16 hb = f2bu(f[j]);
            h[j] = hb;
            l[j] = f2bu(f[j] - b2f(hb));
        }
        *(ushort4*)&WbH[i*4] = *(ushort4*)h;
        *(ushort4*)&WbL[i*4] = *(ushort4*)l;
        return;
    }
    b -= 1600;
    if (b < 4096) {                                   // 8 projection transposes
        int m = b >> 9, tt = b & 511;                 // m: wl0,wr0,wl1,wr1,wl2,wr2,wl3,wr3
        const float* src[8] = {wl0, wr0, wl1, wr1, wl2, wr2, wl3, wr3};
        u16* Wt[4] = {Wt0, Wt1, Wt2, Wt3};
        int layer = m >> 1, half = m & 1;
        u16* dst = Wt[layer] + (size_t)half * 2048 * 256;
        if ((layer & 1) == 0)                          // (K=256, N=2048): 8 x 64 tiles
            tc_tile(src[m], 256, 2048, dst, tt & 7, tt >> 3, tid, t);
        else                                           // (K=2048, N=256): 64 x 8 tiles
            tc_tile(src[m], 2048, 256, dst, tt & 63, tt >> 6, tid, t);
        return;
    }
    b -= 4096;
    if (b < 128) {                                    // fc3 (K=512, N=256): 16 x 8
        tc_tile(fc3_w, 512, 256, WtF, b & 15, b >> 4, tid, t);
        return;
    }
    b -= 128;                                         // fc2 hilo (K=256,N=256): 8 x 8
    {
        const int kb = (b & 7)*32, nb = (b >> 3)*32;
        const int tx = tid & 31, ty = tid >> 5;
#pragma unroll
        for (int r=0;r<4;r++)
            t[ty + r*8][tx] = fc2_w[(size_t)(kb + ty + r*8)*256 + nb + tx];
        __syncthreads();
#pragma unroll
        for (int r=0;r<4;r++){
            float v = t[tx][ty + r*8];
            u16 hb = f2bu(v);
            W2h[(size_t)(nb + ty + r*8)*256 + kb + tx] = hb;
            W2l[(size_t)(nb + ty + r*8)*256 + kb + tx] = f2bu(v - b2f(hb));
        }
    }
}

// im2col + bf16-split, READ-COALESCED (R17). One block per (channel, patch-row).
__global__ __launch_bounds__(256)
void xpb_build(const float* __restrict__ x, int base,
               u16* __restrict__ xh, u16* __restrict__ xl)
{
    __shared__ u16 lh[96*26], ll[96*26];
    const int c = blockIdx.x / 48;
    const int piL = blockIdx.x - c*48;
    const int pi = (base/96) + piL;
    const int tid = threadIdx.x;

    for (int e = tid; e < 600; e += 256){
        int r = e / 120, col4 = e - r*120;
        float4 v = *(const float4*)(x + (size_t)c*230400 + (size_t)(pi*5+r)*480 + col4*4);
        float f[4] = {v.x, v.y, v.z, v.w};
#pragma unroll
        for (int j=0;j<4;j++){
            int col = col4*4 + j;
            int pj = col / 5, jj = col - pj*5;
            u16 hb = f2bu(f[j]);
            int lo = pj*26 + r*5 + jj;
            lh[lo] = hb;
            ll[lo] = f2bu(f[j] - b2f(hb));
        }
    }
    __syncthreads();
    for (int e = tid; e < 2400; e += 256){
        int pj = e / 25, kk = e - pj*25;
        size_t go = (size_t)(piL*96 + pj)*6400 + c*25 + kk;
        xh[go] = lh[pj*26 + kk];
        xl[go] = ll[pj*26 + kk];
    }
}

// sum 4 K-split partials + bias + relu -> emb1 as bf16 hi/lo (feeds fc2 MFMA)
__global__ void conv_reduce2(const float* __restrict__ p, const float* __restrict__ bias,
                             u16* __restrict__ oh, u16* __restrict__ ol)
{
    int i = blockIdx.x * 256 + threadIdx.x;
    const float4* p4 = (const float4*)p;
    float4 s = p4[i];
#pragma unroll
    for (int j=1;j<4;j++){
        float4 v = p4[i + (size_t)j*294912];
        s.x += v.x; s.y += v.y; s.z += v.z; s.w += v.w;
    }
    float4 bb = ((const float4*)bias)[i & 63];
    float f[4] = {fmaxf(s.x+bb.x,0.f), fmaxf(s.y+bb.y,0.f),
                  fmaxf(s.z+bb.z,0.f), fmaxf(s.w+bb.w,0.f)};
    u16 h[4], l[4];
#pragma unroll
    for (int j=0;j<4;j++){
        u16 hb = f2bu(f[j]);
        h[j] = hb;
        l[j] = f2bu(f[j] - b2f(hb));
    }
    *(ushort4*)&oh[i*4] = *(ushort4*)h;
    *(ushort4*)&ol[i*4] = *(ushort4*)l;
}

// ---------------- bf16 MFMA NT GEMM core: C[M][N] = A[M][K] @ B[N][K]^T ------------
// 128x128 tile, BK=32, global_load_lds staging, linear LDS [128][32].
// EPI 0: bf16 store. EPI 1: swapped-operand top-3 packed keys. EPI 2: conv K-split
// f32 partials. EPI 3: f32 relu(acc+bias)+add (fc3). EPI 4: f32 relu(acc+bias) and
// bf16 dual-store (fc2). SWAPG: n-tile fast (A-slab L2 reuse).
template<bool SPLIT, int EPI, bool SWAPG>
__device__ __forceinline__
void mm_core(const u16* __restrict__ Ah, const u16* __restrict__ Al, int lda,
             const u16* __restrict__ Bh, const u16* __restrict__ Bl, int ldb,
             const float* __restrict__ bias0, const float* __restrict__ bias1, int nHalf,
             void* __restrict__ Cout, int ldc, int K,
             u64* __restrict__ apk, u16* __restrict__ Cout2)
{
    constexpr int TSZ = 128 * 32;
    __shared__ u16 smem[(SPLIT ? 4 : 2) * TSZ];
    u16* AsH = smem;
    u16* BsH = smem + TSZ;
    u16* AsL = SPLIT ? smem + 2*TSZ : nullptr;
    u16* BsL = SPLIT ? smem + 3*TSZ : nullptr;

    const int tid = threadIdx.x;
    const int w = tid >> 6, ln = tid & 63;
    const int wr = w >> 1, wc = w & 1;
    const int fr = ln & 15, fq = ln >> 4;
    const int mb = (SWAPG ? blockIdx.y : blockIdx.x) * 128;
    const int nb = (SWAPG ? blockIdx.x : blockIdx.y) * 128;
    const int skk = (ln & 3) * 8;

    int kbeg = 0;
    if constexpr (EPI == 2) kbeg = blockIdx.z * K;
    const int kend = kbeg + K;

    f32x4 acc[4][4];
#pragma unroll
    for (int i=0;i<4;i++)
#pragma unroll
        for (int j=0;j<4;j++) acc[i][j] = (f32x4){0.f,0.f,0.f,0.f};

    for (int k0 = kbeg; k0 < kend; k0 += 32) {
#pragma unroll
        for (int t=0;t<2;t++){
            int rbase = w*32 + t*16;
            int r = rbase + (ln >> 2);
            size_t goA = (size_t)(mb + r)*lda + k0 + skk;
            size_t goB = (size_t)(nb + r)*ldb + k0 + skk;
            gload16(Ah + goA, AsH + rbase*32);
            gload16(Bh + goB, BsH + rbase*32);
            if constexpr (SPLIT){
                gload16(Al + goA, AsL + rbase*32);
                gload16(Bl + goB, BsL + rbase*32);
            }
        }
        __syncthreads();
        s16x8 ah[4], bh[4], al[4], bl[4];
#pragma unroll
        for (int mi=0;mi<4;mi++){
            int ro = (wr*64 + mi*16 + fr)*32 + fq*8;
            ah[mi] = *(const s16x8*)&AsH[ro];
            if constexpr (SPLIT) al[mi] = *(const s16x8*)&AsL[ro];
        }
#pragma unroll
        for (int nj=0;nj<4;nj++){
            int ro = (wc*64 + nj*16 + fr)*32 + fq*8;
            bh[nj] = *(const s16x8*)&BsH[ro];
            if constexpr (SPLIT) bl[nj] = *(const s16x8*)&BsL[ro];
        }
#pragma unroll
        for (int mi=0;mi<4;mi++)
#pragma unroll
            for (int nj=0;nj<4;nj++){
                acc[mi][nj] = mfma_bf16(ah[mi], bh[nj], acc[mi][nj]);
                if constexpr (SPLIT){
                    acc[mi][nj] = mfma_bf16(ah[mi], bl[nj], acc[mi][nj]);
                    acc[mi][nj] = mfma_bf16(al[mi], bh[nj], acc[mi][nj]);
                }
            }
        __syncthreads();
    }

    if constexpr (EPI == 0) {
        u16* ldsc = smem;
#pragma unroll
        for (int chunk=0; chunk<4; ++chunk){
            __syncthreads();
            if (wr == (chunk>>1)){
                int mi0 = (chunk&1)*2;
#pragma unroll
                for (int m2=0;m2<2;m2++){
                    int mi = mi0 + m2;
#pragma unroll
                    for (int nj=0;nj<4;nj++)
#pragma unroll
                    for (int t=0;t<4;t++){
                        int lr = m2*16 + fq*4 + t;
                        int lc = wc*64 + nj*16 + fr;
                        int col = nb + lc;
                        float v = acc[mi][nj][t];
                        if (bias0) v += (col < nHalf) ? bias0[col] : bias1[col - nHalf];
                        ldsc[lr*136 + lc] = f2bu(v);
                    }
                }
            }
            __syncthreads();
            int c0 = chunk*32;
#pragma unroll
            for (int q=0;q<2;q++){
                int e = q*256 + tid;
                int lr = e >> 4, c16 = e & 15;
                *(uint4*)((u16*)Cout + (size_t)(mb + c0 + lr)*ldc + nb + c16*8)
                    = *(const uint4*)&ldsc[lr*136 + c16*8];
            }
        }
    } else if constexpr (EPI == 2 || EPI == 3 || EPI == 4) {
        float* ldsf = (float*)smem;
        const int NC = (EPI == 2) ? 256 : ldc;
#pragma unroll
        for (int chunk=0; chunk<8; ++chunk){
            __syncthreads();
            if (wr == (chunk>>2)){
                int mi = chunk & 3;
#pragma unroll
                for (int nj=0;nj<4;nj++)
#pragma unroll
                for (int t=0;t<4;t++){
                    int lr = fq*4 + t;
                    int lc = wc*64 + nj*16 + fr;
                    float v = acc[mi][nj][t];
                    if constexpr (EPI == 3 || EPI == 4){
                        v += bias0[nb + lc];
                        v = fmaxf(v, 0.f);
                    }
                    ldsf[lr*132 + lc] = v;
                }
            }
            __syncthreads();
            int c0 = chunk*16;
#pragma unroll
            for (int q=0;q<2;q++){
                int e = q*256 + tid;
                int lr = e >> 5, c4 = e & 31;
                int row = mb + c0 + lr, col = nb + c4*4;
                if constexpr (EPI == 3){
                    float4 a = *(const float4*)(bias1 + (size_t)row*NC + col);
                    float4 v = *(const float4*)&ldsf[lr*132 + c4*4];
                    v.x += a.x; v.y += a.y; v.z += a.z; v.w += a.w;
                    *(float4*)((float*)Cout + (size_t)row*NC + col) = v;
                } else if constexpr (EPI == 4){
                    float4 v = *(const float4*)&ldsf[lr*132 + c4*4];
                    *(float4*)((float*)Cout + (size_t)row*NC + col) = v;
                    u16 hh[4] = {f2bu(v.x), f2bu(v.y), f2bu(v.z), f2bu(v.w)};
                    *(uint2*)(Cout2 + (size_t)row*NC + col) = *(uint2*)hh;
                } else {
                    *(float4*)((float*)Cout + ((size_t)blockIdx.z*4608 + row)*256 + col)
                        = *(const float4*)&ldsf[lr*132 + c4*4];
                }
            }
        }
    } else {
        // swapped-selection: adj row = B-side (nb + wc*64 + nj*16 + fr); c = A-side.
        const int cbR = blockIdx.x * 2 + wr;
#pragma unroll
        for (int nj=0;nj<4;nj++){
            int row = nb + wc*64 + nj*16 + fr;
            float tv[3] = {NEG_INF, NEG_INF, NEG_INF};
            int   ti[3] = {0x7fffffff, 0x7fffffff, 0x7fffffff};
#pragma unroll
            for (int mi=0;mi<4;mi++)
#pragma unroll
                for (int t=0;t<4;t++)
                    tk_insert(acc[mi][nj][t], mb + wr*64 + mi*16 + fq*4 + t, tv, ti);
#pragma unroll
            for (int off=16; off<64; off<<=1){
                float ov[3]; int oi[3];
#pragma unroll
                for (int e=0;e<3;e++){ ov[e]=__shfl_xor(tv[e],off); oi[e]=__shfl_xor(ti[e],off); }
#pragma unroll
                for (int e=0;e<3;e++) tk_insert(ov[e], oi[e], tv, ti);
            }
            if (fq == 0){
#pragma unroll
                for (int e=0;e<3;e++)
                    apk[(size_t)row*432 + cbR*3 + e] = mkkey(tv[e], ti[e]);
            }
        }
    }
}

// named instantiations (distinct rocprof rows)
__global__ __launch_bounds__(256)
void mm_proj(const u16* Ah, int lda, const u16* Bh, int ldb,
             const float* bias0, const float* bias1, int nHalf,
             void* Cout, int ldc, int K)
{
    mm_core<false,0,false>(Ah, nullptr, lda, Bh, nullptr, ldb, bias0, bias1, nHalf,
                           Cout, ldc, K, nullptr, nullptr);
}
__global__ __launch_bounds__(256)
void mm_projT(const u16* Ah, int lda, const u16* Bh, int ldb,
              const float* bias0, const float* bias1, int nHalf,
              void* Cout, int ldc, int K)
{
    mm_core<false,0,true>(Ah, nullptr, lda, Bh, nullptr, ldb, bias0, bias1, nHalf,
                          Cout, ldc, K, nullptr, nullptr);
}
__global__ __launch_bounds__(256)
void mm_adj(const u16* Ah, int lda, u64* apk)
{
    mm_core<false,1,false>(Ah, nullptr, lda, Ah, nullptr, lda, nullptr, nullptr, 0,
                           nullptr, 0, 256, apk, nullptr);
}
__global__ __launch_bounds__(256)
void mm_conv(const u16* Ah, const u16* Al, int lda, const u16* Bh, const u16* Bl, int ldb,
             float* Cout, int K)
{
    mm_core<true,2,false>(Ah, Al, lda, Bh, Bl, ldb, nullptr, nullptr, 0,
                          Cout, 256, K, nullptr, nullptr);
}
// fc2: emb = relu(emb1 @ W2t^T + b), split-bf16 3-term; dual out f32 + bf16
__global__ __launch_bounds__(256)
void mm_fc2(const u16* Ah, const u16* Al, const u16* Bh, const u16* Bl,
            const float* bias, float* Cout, u16* Cout2)
{
    mm_core<true,4,false>(Ah, Al, 256, Bh, Bl, 256, bias, nullptr, 0,
                          Cout, 256, 256, nullptr, Cout2);
}
// fc3: out = relu(hcat @ WtF^T + bias) + add ; f32 out, ld 256
__global__ __launch_bounds__(256)
void mm_fc3(const u16* Ah, int lda, const u16* Bh, int ldb,
            const float* bias, const float* add, float* Cout)
{
    mm_core<false,3,false>(Ah, nullptr, lda, Bh, nullptr, ldb, bias, add, 0,
                           Cout, 256, 512, nullptr, nullptr);
}

// fused merge+rescore: 432 packed keys/row -> top-8 (wave head-pop, candidates
// wave-visible) -> exact fp32 rescore -> final top-3. ONE WAVE PER ROW.
__device__ __forceinline__ void ce_desc(u64& a, u64& b){
    u64 mx = a > b ? a : b; u64 mn = a > b ? b : a; a = mx; b = mn;
}
__global__ __launch_bounds__(256)
void adj_select(const u64* __restrict__ apk, const float* __restrict__ emb,
                float* __restrict__ vals, int* __restrict__ idx)
{
    int row = blockIdx.x * 4 + (threadIdx.x >> 6);
    int ln = threadIdx.x & 63;
    u64 k[7];
#pragma unroll
    for (int j=0;j<7;j++){
        int t = ln + 64*j;
        k[j] = (t < 432) ? apk[(size_t)row*432 + t] : 0ull;
    }
    ce_desc(k[0],k[6]); ce_desc(k[2],k[3]); ce_desc(k[4],k[5]);
    ce_desc(k[0],k[2]); ce_desc(k[1],k[4]); ce_desc(k[3],k[6]);
    ce_desc(k[0],k[1]); ce_desc(k[2],k[5]); ce_desc(k[3],k[4]);
    ce_desc(k[1],k[2]); ce_desc(k[4],k[6]);
    ce_desc(k[2],k[3]); ce_desc(k[4],k[5]);
    ce_desc(k[1],k[2]); ce_desc(k[3],k[4]); ce_desc(k[5],k[6]);
    int cand[8];
#pragma unroll
    for (int r=0;r<8;r++){
        u64 m = k[0];
#pragma unroll
        for (int off=1; off<64; off<<=1){
            u64 o = __shfl_xor((unsigned long long)m, off);
            m = o > m ? o : m;
        }
        if (k[0] == m){               // unique keys -> exactly one winner pops
            k[0]=k[1]; k[1]=k[2]; k[2]=k[3]; k[3]=k[4]; k[4]=k[5]; k[5]=k[6]; k[6]=0ull;
        }
        cand[r] = (int)(~(u32)(m & 0xFFFFFFFFull));   // wave-visible in ALL lanes
    }
    float a[4];
    *(float4*)a = *(const float4*)(emb + (size_t)row*256 + ln*4);
    float sc[8];
#pragma unroll
    for (int c=0;c<8;c++){
        float4 bb = *(const float4*)(emb + (size_t)cand[c]*256 + ln*4);
        float p = a[0]*bb.x + a[1]*bb.y + a[2]*bb.z + a[3]*bb.w;
#pragma unroll
        for (int off=1; off<64; off<<=1) p += __shfl_xor(p, off);
        sc[c] = p;
    }
    if (ln == 0){
        float tv[3]={NEG_INF,NEG_INF,NEG_INF};
        int   ti[3]={0x7fffffff,0x7fffffff,0x7fffffff};
#pragma unroll
        for (int c=0;c<8;c++) tk_insert(sc[c], cand[c], tv, ti);
#pragma unroll
        for (int e=0;e<3;e++){ vals[row*3+e]=tv[e]; idx[row*3+e]=ti[e]; }
    }
}

// ---------------- GATv2 softmax + aggregate + bias + ELU, bf16 inputs --------------
template<int H, int TPH, bool SPATIAL>
__global__ __launch_bounds__(H*TPH)
void gat_agg(const u16* __restrict__ xlxr, int ldx, int xrOff,
             const float* __restrict__ att, const float* __restrict__ bias,
             const float* __restrict__ vals, const int* __restrict__ idx,
             u16* __restrict__ outp, int ldo,
             float* __restrict__ out2, int ldo2)
{
    constexpr int D = 256;
    constexpr int DPT = D / TPH;
    const int n = blockIdx.x;
    const int tid = threadIdx.x;
    const int h = tid / TPH;
    const int l = tid % TPH;
    const int d0 = l * DPT;

    int srcs[4]; bool valid[4];
#pragma unroll
    for (int s=0;s<4;s++){ srcs[s]=n; valid[s]=(s==3); }
    if constexpr (SPATIAL) {
        int pi = n / 96, pj = n - (n/96)*96;
        int cand[4]; int nc=0;
        if (pi > 0)  cand[nc++] = n - 96;
        if (pj > 0)  cand[nc++] = n - 1;
        if (pj < 95) cand[nc++] = n + 1;
        if (pi < 95) cand[nc++] = n + 96;
        int s0 = cand[0], s1 = cand[1];
        if (s0 > n){ srcs[0]=s0; valid[0]=true; }
        if (s1 > n){ srcs[1]=s1; valid[1]=true; }
    } else {
#pragma unroll
        for (int t=0;t<3;t++){
            int s = idx[n*3+t];
            float v = vals[n*3+t];
            if (s > n && v != 0.0f){ srcs[t]=s; valid[t]=true; }
        }
    }

    float xrv[DPT], attv[DPT];
#pragma unroll
    for (int q=0;q<DPT/4;q++){
        ushort4 u = *(const ushort4*)(xlxr + (size_t)n*ldx + xrOff + h*D + d0 + q*4);
        xrv[q*4+0]=b2f(u.x); xrv[q*4+1]=b2f(u.y); xrv[q*4+2]=b2f(u.z); xrv[q*4+3]=b2f(u.w);
        *(float4*)&attv[q*4] = *(const float4*)(att + h*D + d0 + q*4);
    }

    float xs[4][DPT];
    float sc[4];
#pragma unroll
    for (int s=0;s<4;s++){
#pragma unroll
        for (int q=0;q<DPT/4;q++){
            ushort4 u = *(const ushort4*)(xlxr + (size_t)srcs[s]*ldx + h*D + d0 + q*4);
            xs[s][q*4+0]=b2f(u.x); xs[s][q*4+1]=b2f(u.y); xs[s][q*4+2]=b2f(u.z); xs[s][q*4+3]=b2f(u.w);
        }
        float p = 0.f;
#pragma unroll
        for (int d=0;d<DPT;d++){
            float e = xs[s][d] + xrv[d];
            e = (e > 0.f) ? e : 0.2f*e;
            p += attv[d]*e;
        }
#pragma unroll
        for (int off=1; off<TPH; off<<=1) p += __shfl_xor(p, off);
        sc[s] = p;
    }
    float m = NEG_INF;
#pragma unroll
    for (int s=0;s<4;s++) if (valid[s]) m = fmaxf(m, sc[s]);
    float al[4]; float denom = 0.f;
#pragma unroll
    for (int s=0;s<4;s++){ al[s] = valid[s] ? expf(sc[s]-m) : 0.f; denom += al[s]; }
    float inv = 1.f / denom;

    float o[DPT];
#pragma unroll
    for (int d=0;d<DPT;d++){
        float acc = al[0]*xs[0][d] + al[1]*xs[1][d] + al[2]*xs[2][d] + al[3]*xs[3][d];
        acc = acc*inv + bias[h*D + d0 + d];
        o[d] = (acc > 0.f) ? acc : (expf(acc) - 1.f);
    }
    u16 ov[DPT];
#pragma unroll
    for (int d=0;d<DPT;d++) ov[d] = f2bu(o[d]);
    if constexpr (DPT >= 8){
#pragma unroll
        for (int q=0;q<DPT/8;q++)
            *(uint4*)(outp + (size_t)n*ldo + h*D + d0 + q*8) = *(uint4*)&ov[q*8];
    } else {
        *(uint2*)(outp + (size_t)n*ldo + h*D + d0) = *(uint2*)ov;
    }
    if (out2){
#pragma unroll
        for (int q=0;q<DPT/4;q++)
            *(float4*)(out2 + (size_t)n*ldo2 + h*D + d0 + q*4) = *(float4*)&o[q*4];
    }
}

// ---------------------------------------------------------------------------
extern "C" void kernel_launch(void* const* d_in, const int* in_sizes, int n_in,
                              void* d_out, int out_size, void* d_ws, size_t ws_size,
                              hipStream_t stream)
{
    (void)in_sizes; (void)n_in;
    const float* x      = (const float*)d_in[0];
    const float* conv_w = (const float*)d_in[1];
    const float* conv_b = (const float*)d_in[2];
    const float* fc2_w  = (const float*)d_in[3];
    const float* fc2_b  = (const float*)d_in[4];
    const float* fc3_w  = (const float*)d_in[5];
    const float* fc3_b  = (const float*)d_in[6];
    const float* g_wl[4]   = {(const float*)d_in[7],  (const float*)d_in[13], (const float*)d_in[19], (const float*)d_in[25]};
    const float* g_bl[4]   = {(const float*)d_in[8],  (const float*)d_in[14], (const float*)d_in[20], (const float*)d_in[26]};
    const float* g_wr[4]   = {(const float*)d_in[9],  (const float*)d_in[15], (const float*)d_in[21], (const float*)d_in[27]};
    const float* g_br[4]   = {(const float*)d_in[10], (const float*)d_in[16], (const float*)d_in[22], (const float*)d_in[28]};
    const float* g_att[4]  = {(const float*)d_in[11], (const float*)d_in[17], (const float*)d_in[23], (const float*)d_in[29]};
    const float* g_bias[4] = {(const float*)d_in[12], (const float*)d_in[18], (const float*)d_in[24], (const float*)d_in[30]};

    float* ws = (float*)d_ws;
    size_t off = 0;
    // persistent (never aliased): e1h/e1l
    u16*   e1h  = (u16*)(ws + off); off += 1179648;           // [9216][256] bf16 hi
    u16*   e1l  = (u16*)(ws + off); off += 1179648;           // [9216][256] bf16 lo
    // ALIASED REGION (conv scratch lives here; all these buffers written POST-conv)
    size_t emb_off = off;
    float* emb   = ws + off; off += 2359296;                  // written by fc2
    u16*   emb_h = (u16*)(ws + off); off += 1179648;          // written by fc2
    u64*   apk  = (u64*)(ws + off); off += 7962624;           // written by mm_adj
    float* vals = ws + off; off += 27648;                     // written by adj_select
    int*   idx  = (int*)(ws + off); off += 27648;
    u16*   hcat = (u16*)(ws + off); off += 2359296;           // written by gat_agg g2/g4
    float* h4   = ws + off; off += 2359296;                   // written by gat_agg g4
    u16*   xlxr = (u16*)(ws + off); off += 18874368;          // written by mm_proj
    u16*   hbig = (u16*)(ws + off); off += 9437184;           // written by gat_agg g1/g3
    // TAIL (never aliased): all weight buffers — prep_all runs BEFORE conv (R20 fix)
    u16*   Wt[4];
    Wt[0] = (u16*)(ws + off); off += 524288;                  // [4096][256] bf16
    Wt[1] = (u16*)(ws + off); off += 524288;                  // [512][2048] bf16
    Wt[2] = (u16*)(ws + off); off += 524288;
    Wt[3] = (u16*)(ws + off); off += 524288;
    u16*   WtF  = (u16*)(ws + off); off += 65536;             // [256][512] bf16 (fc3)
    u16*   W2h  = (u16*)(ws + off); off += 32768;             // [256][256] bf16 (fc2 hi)
    u16*   W2l  = (u16*)(ws + off); off += 32768;             // [256][256] bf16 (fc2 lo)
    u16*   WbH  = (u16*)(ws + off); off += 851968;            // [256][6400] bf16 (conv W)
    u16*   WbL  = (u16*)(ws + off); off += 851968;
    // conv-phase scratch aliased onto [emb_off, emb_off+34,209,792) — fits within
    // the aliased region (44,587,008 floats), touches NO weight buffer.
    u16*   xp_h = (u16*)(ws + emb_off);                          // [4608][6400] u16
    u16*   xp_l = (u16*)(ws + emb_off + 14745600);
    float* cpart = ws + emb_off + 29491200;                      // [4][4608][256] f32
    size_t need = off * sizeof(float);
    if (ws_size < need) {
        hipMemsetAsync(d_out, 0, (size_t)out_size*sizeof(float), stream);
        return;
    }
    float* out = (float*)d_out;

    // all weight prep in one launch (targets tail buffers only — safe before conv)
    prep_all<<<5888,256,0,stream>>>(conv_w, WbH, WbL,
                                    g_wl[0], g_wr[0], g_wl[1], g_wr[1],
                                    g_wl[2], g_wr[2], g_wl[3], g_wr[3],
                                    Wt[0], Wt[1], Wt[2], Wt[3],
                                    fc3_w, WtF, fc2_w, W2h, W2l);
    // conv1 = bf16-split-3-term NT GEMM over im2col'd x (two row-halves, K-split x4)
    for (int half = 0; half < 2; ++half) {
        xpb_build<<<12288,256,0,stream>>>(x, half*4608, xp_h, xp_l);
        mm_conv<<<dim3(36,2,4),256,0,stream>>>(xp_h, xp_l, 6400, WbH, WbL, 6400, cpart, 1600);
        conv_reduce2<<<1152,256,0,stream>>>(cpart, conv_b,
                                            e1h + (size_t)half*4608*256,
                                            e1l + (size_t)half*4608*256);
    }
    // fc2 via split-bf16 MFMA -> emb f32 + emb_h bf16 (dual out)
    mm_fc2<<<dim3(72,2),256,0,stream>>>(e1h, e1l, W2h, W2l, fc2_b, emb, emb_h);

    // similarity kNN: candidates -> fused merge+rescore -> top-3
    mm_adj<<<dim3(72,72),256,0,stream>>>(emb_h, 256, apk);
    adj_select<<<2304,256,0,stream>>>(apk, emb, vals, idx);

    // g1 (H=8, similarity graph)
    mm_proj<<<dim3(72,32),256,0,stream>>>(emb_h, 256, Wt[0], 256, g_bl[0], g_br[0], 2048,
                                          xlxr, 4096, 256);
    gat_agg<8,32,false><<<9216,256,0,stream>>>(xlxr, 4096, 2048, g_att[0], g_bias[0], vals, idx,
                                               hbig, 2048, nullptr, 0);
    // g2 (H=1) -> hcat cols 0..255 ; n-fastest grid (hbig slab L2 reuse)
    mm_projT<<<dim3(4,72),256,0,stream>>>(hbig, 2048, Wt[1], 2048, g_bl[1], g_br[1], 256,
                                          xlxr, 512, 2048);
    gat_agg<1,64,false><<<9216,64,0,stream>>>(xlxr, 512, 256, g_att[1], g_bias[1], vals, idx,
                                              hcat, 512, nullptr, 0);
    // g3 (H=8, spatial graph)
    mm_proj<<<dim3(72,32),256,0,stream>>>(emb_h, 256, Wt[2], 256, g_bl[2], g_br[2], 2048,
                                          xlxr, 4096, 256);
    gat_agg<8,32,true><<<9216,256,0,stream>>>(xlxr, 4096, 2048, g_att[2], g_bias[2], nullptr, nullptr,
                                              hbig, 2048, nullptr, 0);
    // g4 (H=1) -> hcat cols 256..511 + h4 f32 (exact residual)
    mm_projT<<<dim3(4,72),256,0,stream>>>(hbig, 2048, Wt[3], 2048, g_bl[3], g_br[3], 256,
                                          xlxr, 512, 2048);
    gat_agg<1,64,true><<<9216,64,0,stream>>>(xlxr, 512, 256, g_att[3], g_bias[3], nullptr, nullptr,
                                             hcat + 256, 512, h4, 256);

    // fc3 via bf16 MFMA: out = relu(hcat @ WtF^T + b) + h4
    mm_fc3<<<dim3(72,2),256,0,stream>>>(hcat, 512, WtF, 512, fc3_b, h4, out);
}